// Round 11
// baseline (425.314 us; speedup 1.0000x reference)
//
#include <hip/hip_runtime.h>
#include <hip/hip_bf16.h>
#include <math.h>

#define Bdim 2
#define Tdim 1024
#define Cdim 1024
#define Hdim 16
#define Ndim 64
#define CCdim (Cdim * Cdim)
#define EPS_GN 0.00064f

typedef __bf16 bf8_t __attribute__((ext_vector_type(8)));
typedef float f32x4 __attribute__((ext_vector_type(4)));
typedef float f4 __attribute__((ext_vector_type(4)));

static __device__ __forceinline__ float sigf(float x) { return 1.f / (1.f + expf(-x)); }

static __device__ __forceinline__ float wsum64(float v) {
    #pragma unroll
    for (int m = 1; m < 64; m <<= 1) v += __shfl_xor(v, m);
    return v;
}

static __device__ __forceinline__ void gload_lds16(const void* g, void* l) {
    __builtin_amdgcn_global_load_lds(
        (const __attribute__((address_space(1))) void*)g,
        (__attribute__((address_space(3))) void*)l, 16, 0, 0);
}

// quad (4-lane) reduce via DPP quad_perm: xor1 then xor2, VALU-speed.
static __device__ __forceinline__ float quad_reduce(float x) {
    int s1 = __builtin_amdgcn_update_dpp(0, __builtin_bit_cast(int, x),
                                         0xB1, 0xF, 0xF, true);   // [1,0,3,2]
    float y = x + __builtin_bit_cast(float, s1);
    int s2 = __builtin_amdgcn_update_dpp(0, __builtin_bit_cast(int, y),
                                         0x4E, 0xF, 0xF, true);   // [2,3,0,1]
    return y + __builtin_bit_cast(float, s2);
}

// ---------------------------------------------------------------------------
// prep_weights: 3 segments in one dispatch (unchanged from R10).
// ---------------------------------------------------------------------------
__global__ __launch_bounds__(256) void prep_weights(
    const float* __restrict__ W0, const float* __restrict__ W1,
    const float* __restrict__ W2, const float* __restrict__ W3,
    const float* __restrict__ w1, const float* __restrict__ a1,
    const float* __restrict__ v1, const float* __restrict__ g1,
    const float* __restrict__ w2, const float* __restrict__ a2,
    const float* __restrict__ v2, const float* __restrict__ g2,
    const float* __restrict__ mw, const float* __restrict__ ma,
    const float* __restrict__ mv, const float* __restrict__ mg,
    __hip_bfloat16* __restrict__ Wb, __hip_bfloat16* __restrict__ Wlr1,
    __hip_bfloat16* __restrict__ Wl2)
{
    int blk = blockIdx.x;
    int tid = threadIdx.x;
    if (blk < 2048) {
        int which = blk >> 9;
        const float* src = (which == 0) ? W0 : (which == 1) ? W1 : (which == 2) ? W2 : W3;
        size_t e8 = ((size_t)(blk & 511) * 256 + tid) * 8;
        float c[8];
        *(float4*)&c[0] = ((const float4*)(src + e8))[0];
        *(float4*)&c[4] = ((const float4*)(src + e8))[1];
        __hip_bfloat16 o[8];
        #pragma unroll
        for (int j = 0; j < 8; ++j) o[j] = __float2bfloat16(c[j]);
        __hip_bfloat16* dst = Wb + (size_t)which * CCdim + e8;
        ((ushort4*)dst)[0] = *(ushort4*)&o[0];
        ((ushort4*)dst)[1] = *(ushort4*)&o[4];
    } else if (blk < 2432) {
        int n = blk - 2048;                 // 0..383
        if (n < 288) {
            const float* M1; const float* mix; int D, nl;
            if (n < 64)       { M1 = w1; mix = mw; D = 64;  nl = n; }
            else if (n < 128) { M1 = a1; mix = ma; D = 64;  nl = n - 64; }
            else if (n < 160) { M1 = v1; mix = mv; D = 32;  nl = n - 128; }
            else              { M1 = g1; mix = mg; D = 128; nl = n - 160; }
            #pragma unroll
            for (int i = 0; i < 8; ++i) {
                int kp = tid + i * 256;     // 0..2047
                int k = kp & 1023, half = kp >> 10;
                float mx = mix[k];
                float val = M1[(size_t)k * D + nl] * (half ? mx : 1.f - mx);
                Wlr1[(size_t)n * 2048 + kp] = __float2bfloat16(val);
            }
        } else {
            #pragma unroll
            for (int i = 0; i < 8; ++i)
                Wlr1[(size_t)n * 2048 + tid + i * 256] = __float2bfloat16(0.f);
        }
    } else {
        int np = blk - 2432;                // 0..4095
        int path = np >> 10, nl = np & 1023;
        const float* M2; int off, D;
        if (path == 0)      { M2 = w2; off = 0;   D = 64; }
        else if (path == 1) { M2 = a2; off = 64;  D = 64; }
        else if (path == 2) { M2 = v2; off = 128; D = 32; }
        else                { M2 = g2; off = 160; D = 128; }
        for (int kp = tid; kp < 288; kp += 256) {
            int kl = kp - off;
            float val = (kl >= 0 && kl < D) ? M2[(size_t)kl * Cdim + nl] : 0.f;
            Wl2[(size_t)np * 288 + kp] = __float2bfloat16(val);
        }
    }
}

// ---------------------------------------------------------------------------
// prep_all: token-shift lerps (r,k,v) -> bf16 + Aall = [x | xprev] bf16.
// ---------------------------------------------------------------------------
__global__ __launch_bounds__(256) void prep_all(
    const float* __restrict__ xt,
    const float* __restrict__ mr, const float* __restrict__ mk, const float* __restrict__ mv,
    __hip_bfloat16* __restrict__ xr16, __hip_bfloat16* __restrict__ xk16,
    __hip_bfloat16* __restrict__ xv16, __hip_bfloat16* __restrict__ Aall)
{
    int idx8 = blockIdx.x * 256 + threadIdx.x;   // 0..262143
    int m = idx8 >> 7;
    int c8 = (idx8 & 127) * 8;
    int t = m & (Tdim - 1);
    const float* p = xt + (size_t)idx8 * 8;
    float cur[8], prv[8];
    *(float4*)&cur[0] = ((const float4*)p)[0];
    *(float4*)&cur[4] = ((const float4*)p)[1];
    if (t > 0) {
        *(float4*)&prv[0] = ((const float4*)(p - Cdim))[0];
        *(float4*)&prv[4] = ((const float4*)(p - Cdim))[1];
    } else {
        #pragma unroll
        for (int j = 0; j < 8; ++j) prv[j] = 0.f;
    }
    float mx[8];
    __hip_bfloat16 o[8];
    size_t ob = (size_t)idx8 * 8;

    *(float4*)&mx[0] = *(const float4*)(mr + c8);
    *(float4*)&mx[4] = *(const float4*)(mr + c8 + 4);
    #pragma unroll
    for (int j = 0; j < 8; ++j) o[j] = __float2bfloat16(cur[j] + (prv[j] - cur[j]) * mx[j]);
    ((ushort4*)(xr16 + ob))[0] = *(ushort4*)&o[0];
    ((ushort4*)(xr16 + ob))[1] = *(ushort4*)&o[4];

    *(float4*)&mx[0] = *(const float4*)(mk + c8);
    *(float4*)&mx[4] = *(const float4*)(mk + c8 + 4);
    #pragma unroll
    for (int j = 0; j < 8; ++j) o[j] = __float2bfloat16(cur[j] + (prv[j] - cur[j]) * mx[j]);
    ((ushort4*)(xk16 + ob))[0] = *(ushort4*)&o[0];
    ((ushort4*)(xk16 + ob))[1] = *(ushort4*)&o[4];

    *(float4*)&mx[0] = *(const float4*)(mv + c8);
    *(float4*)&mx[4] = *(const float4*)(mv + c8 + 4);
    #pragma unroll
    for (int j = 0; j < 8; ++j) o[j] = __float2bfloat16(cur[j] + (prv[j] - cur[j]) * mx[j]);
    ((ushort4*)(xv16 + ob))[0] = *(ushort4*)&o[0];
    ((ushort4*)(xv16 + ob))[1] = *(ushort4*)&o[4];

    size_t ab = (size_t)m * 2048 + c8;
    #pragma unroll
    for (int j = 0; j < 8; ++j) o[j] = __float2bfloat16(cur[j]);
    ((ushort4*)(Aall + ab))[0] = *(ushort4*)&o[0];
    ((ushort4*)(Aall + ab))[1] = *(ushort4*)&o[4];
    #pragma unroll
    for (int j = 0; j < 8; ++j) o[j] = __float2bfloat16(prv[j]);
    ((ushort4*)(Aall + ab + 1024))[0] = *(ushort4*)&o[0];
    ((ushort4*)(Aall + ab + 1024))[1] = *(ushort4*)&o[4];
}

// ---------------------------------------------------------------------------
// Triple bf16 MFMA GEMM (z = 0,1,2 selects A/W/C): 128x128 tile, BK=32.
// ---------------------------------------------------------------------------
__global__ __launch_bounds__(256) void gemm3_mfma(
    const __hip_bfloat16* __restrict__ A0, const __hip_bfloat16* __restrict__ A1,
    const __hip_bfloat16* __restrict__ A2, const __hip_bfloat16* __restrict__ Wbase,
    float* __restrict__ C0, float* __restrict__ C1, float* __restrict__ C2)
{
    const int N = Cdim, K = Cdim;
    __shared__ unsigned short At[128][32];
    __shared__ unsigned short Bt[128][32];
    int z = blockIdx.z;
    const __hip_bfloat16* A = (z == 0) ? A0 : (z == 1) ? A1 : A2;
    const __hip_bfloat16* Bw = Wbase + (size_t)z * CCdim;
    float* Cout = (z == 0) ? C0 : (z == 1) ? C1 : C2;
    int tid = threadIdx.x;
    int lane = tid & 63, wv = tid >> 6;
    int bm = blockIdx.y * 128, bn = blockIdx.x * 128;
    int wr = wv >> 1, wc = wv & 1;

    f32x4 acc[4][4];
    #pragma unroll
    for (int mi = 0; mi < 4; ++mi)
        #pragma unroll
        for (int ni = 0; ni < 4; ++ni)
            acc[mi][ni] = (f32x4){0.f, 0.f, 0.f, 0.f};

    int srow = wv * 16 + (lane >> 2);
    int scol = (lane & 3) * 8;
    const __hip_bfloat16* pa0 = A + (size_t)(bm + srow) * K + scol;
    const __hip_bfloat16* pa1 = A + (size_t)(bm + 64 + srow) * K + scol;
    const __hip_bfloat16* pb0 = Bw + (size_t)(bn + srow) * K + scol;
    const __hip_bfloat16* pb1 = Bw + (size_t)(bn + 64 + srow) * K + scol;
    char* At_b = (char*)&At[0][0] + wv * 1024;
    char* Bt_b = (char*)&Bt[0][0] + wv * 1024;

    for (int k0 = 0; k0 < K; k0 += 32) {
        gload_lds16(pa0 + k0, At_b);
        gload_lds16(pa1 + k0, At_b + 4096);
        gload_lds16(pb0 + k0, Bt_b);
        gload_lds16(pb1 + k0, Bt_b + 4096);
        __syncthreads();

        bf8_t af[4], bfr[4];
        #pragma unroll
        for (int mi = 0; mi < 4; ++mi)
            af[mi] = *(const bf8_t*)((const char*)&At[0][0] +
                     (wr * 64 + mi * 16 + (lane & 15)) * 64 + (lane >> 4) * 16);
        #pragma unroll
        for (int ni = 0; ni < 4; ++ni)
            bfr[ni] = *(const bf8_t*)((const char*)&Bt[0][0] +
                     (wc * 64 + ni * 16 + (lane & 15)) * 64 + (lane >> 4) * 16);
        #pragma unroll
        for (int mi = 0; mi < 4; ++mi)
            #pragma unroll
            for (int ni = 0; ni < 4; ++ni)
                acc[mi][ni] = __builtin_amdgcn_mfma_f32_16x16x32_bf16(
                    af[mi], bfr[ni], acc[mi][ni], 0, 0, 0);
        __syncthreads();
    }

    #pragma unroll
    for (int mi = 0; mi < 4; ++mi) {
        int r0 = bm + wr * 64 + mi * 16 + (lane >> 4) * 4;
        #pragma unroll
        for (int ni = 0; ni < 4; ++ni) {
            int c0 = bn + wc * 64 + ni * 16 + (lane & 15);
            #pragma unroll
            for (int j = 0; j < 4; ++j)
                Cout[(size_t)(r0 + j) * N + c0] = acc[mi][ni][j];
        }
    }
}

// ---------------------------------------------------------------------------
// Single bf16 MFMA GEMM (output projection).
// ---------------------------------------------------------------------------
__global__ __launch_bounds__(256) void gemm_mfma(
    const __hip_bfloat16* __restrict__ A, const __hip_bfloat16* __restrict__ Bw,
    float* __restrict__ Cout, int M, int N, int K)
{
    __shared__ unsigned short At[128][32];
    __shared__ unsigned short Bt[128][32];
    int tid = threadIdx.x;
    int lane = tid & 63, wv = tid >> 6;
    int bm = blockIdx.y * 128, bn = blockIdx.x * 128;
    int wr = wv >> 1, wc = wv & 1;

    f32x4 acc[4][4];
    #pragma unroll
    for (int mi = 0; mi < 4; ++mi)
        #pragma unroll
        for (int ni = 0; ni < 4; ++ni)
            acc[mi][ni] = (f32x4){0.f, 0.f, 0.f, 0.f};

    int srow = wv * 16 + (lane >> 2);
    int scol = (lane & 3) * 8;
    const __hip_bfloat16* pa0 = A + (size_t)(bm + srow) * K + scol;
    const __hip_bfloat16* pa1 = A + (size_t)(bm + 64 + srow) * K + scol;
    const __hip_bfloat16* pb0 = Bw + (size_t)(bn + srow) * K + scol;
    const __hip_bfloat16* pb1 = Bw + (size_t)(bn + 64 + srow) * K + scol;
    char* At_b = (char*)&At[0][0] + wv * 1024;
    char* Bt_b = (char*)&Bt[0][0] + wv * 1024;

    for (int k0 = 0; k0 < K; k0 += 32) {
        gload_lds16(pa0 + k0, At_b);
        gload_lds16(pa1 + k0, At_b + 4096);
        gload_lds16(pb0 + k0, Bt_b);
        gload_lds16(pb1 + k0, Bt_b + 4096);
        __syncthreads();

        bf8_t af[4], bfr[4];
        #pragma unroll
        for (int mi = 0; mi < 4; ++mi)
            af[mi] = *(const bf8_t*)((const char*)&At[0][0] +
                     (wr * 64 + mi * 16 + (lane & 15)) * 64 + (lane >> 4) * 16);
        #pragma unroll
        for (int ni = 0; ni < 4; ++ni)
            bfr[ni] = *(const bf8_t*)((const char*)&Bt[0][0] +
                     (wc * 64 + ni * 16 + (lane & 15)) * 64 + (lane >> 4) * 16);
        #pragma unroll
        for (int mi = 0; mi < 4; ++mi)
            #pragma unroll
            for (int ni = 0; ni < 4; ++ni)
                acc[mi][ni] = __builtin_amdgcn_mfma_f32_16x16x32_bf16(
                    af[mi], bfr[ni], acc[mi][ni], 0, 0, 0);
        __syncthreads();
    }

    #pragma unroll
    for (int mi = 0; mi < 4; ++mi) {
        int r0 = bm + wr * 64 + mi * 16 + (lane >> 4) * 4;
        #pragma unroll
        for (int ni = 0; ni < 4; ++ni) {
            int c0 = bn + wc * 64 + ni * 16 + (lane & 15);
            #pragma unroll
            for (int j = 0; j < 4; ++j)
                Cout[(size_t)(r0 + j) * N + c0] = acc[mi][ni][j];
        }
    }
}

// ---------------------------------------------------------------------------
// gemm_lr1: H[2048][288] = Aall @ Wlr1^T, bf16 out, per-range activation.
// ---------------------------------------------------------------------------
__global__ __launch_bounds__(256) void gemm_lr1(
    const __hip_bfloat16* __restrict__ A, const __hip_bfloat16* __restrict__ W,
    __hip_bfloat16* __restrict__ H)
{
    const int K = 2048;
    __shared__ unsigned short At[128][32];
    __shared__ unsigned short Bt[128][32];
    int tid = threadIdx.x;
    int lane = tid & 63, wv = tid >> 6;
    int bm = blockIdx.y * 128, bn = blockIdx.x * 128;
    int wr = wv >> 1, wc = wv & 1;

    f32x4 acc[4][4];
    #pragma unroll
    for (int mi = 0; mi < 4; ++mi)
        #pragma unroll
        for (int ni = 0; ni < 4; ++ni)
            acc[mi][ni] = (f32x4){0.f, 0.f, 0.f, 0.f};

    int srow = wv * 16 + (lane >> 2);
    int scol = (lane & 3) * 8;
    const __hip_bfloat16* pa0 = A + (size_t)(bm + srow) * K + scol;
    const __hip_bfloat16* pa1 = A + (size_t)(bm + 64 + srow) * K + scol;
    const __hip_bfloat16* pb0 = W + (size_t)(bn + srow) * K + scol;
    const __hip_bfloat16* pb1 = W + (size_t)(bn + 64 + srow) * K + scol;
    char* At_b = (char*)&At[0][0] + wv * 1024;
    char* Bt_b = (char*)&Bt[0][0] + wv * 1024;

    for (int k0 = 0; k0 < K; k0 += 32) {
        gload_lds16(pa0 + k0, At_b);
        gload_lds16(pa1 + k0, At_b + 4096);
        gload_lds16(pb0 + k0, Bt_b);
        gload_lds16(pb1 + k0, Bt_b + 4096);
        __syncthreads();

        bf8_t af[4], bfr[4];
        #pragma unroll
        for (int mi = 0; mi < 4; ++mi)
            af[mi] = *(const bf8_t*)((const char*)&At[0][0] +
                     (wr * 64 + mi * 16 + (lane & 15)) * 64 + (lane >> 4) * 16);
        #pragma unroll
        for (int ni = 0; ni < 4; ++ni)
            bfr[ni] = *(const bf8_t*)((const char*)&Bt[0][0] +
                     (wc * 64 + ni * 16 + (lane & 15)) * 64 + (lane >> 4) * 16);
        #pragma unroll
        for (int mi = 0; mi < 4; ++mi)
            #pragma unroll
            for (int ni = 0; ni < 4; ++ni)
                acc[mi][ni] = __builtin_amdgcn_mfma_f32_16x16x32_bf16(
                    af[mi], bfr[ni], acc[mi][ni], 0, 0, 0);
        __syncthreads();
    }

    #pragma unroll
    for (int mi = 0; mi < 4; ++mi) {
        int r0 = bm + wr * 64 + mi * 16 + (lane >> 4) * 4;
        #pragma unroll
        for (int ni = 0; ni < 4; ++ni) {
            int c0 = bn + wc * 64 + ni * 16 + (lane & 15);
            if (c0 < 288) {
                #pragma unroll
                for (int j = 0; j < 4; ++j) {
                    float v = acc[mi][ni][j];
                    if (c0 < 64) v = tanhf(v);
                    else if (c0 >= 160) v = sigf(v);
                    H[(size_t)(r0 + j) * 288 + c0] = __float2bfloat16(v);
                }
            }
        }
    }
}

// ---------------------------------------------------------------------------
// gemm_lr2: block-diag expansion, epilogue demux (unchanged from R10).
// ---------------------------------------------------------------------------
__global__ __launch_bounds__(256) void gemm_lr2(
    const __hip_bfloat16* __restrict__ H, const __hip_bfloat16* __restrict__ W,
    const float* __restrict__ w0, const float* __restrict__ a0,
    const float* __restrict__ v0,
    float* __restrict__ decay, __hip_bfloat16* __restrict__ at16,
    float* __restrict__ vt, __hip_bfloat16* __restrict__ gt16)
{
    const int K = 288;
    __shared__ unsigned short At[128][32];
    __shared__ unsigned short Bt[128][32];
    int tid = threadIdx.x;
    int lane = tid & 63, wv = tid >> 6;
    int bm = blockIdx.y * 128, bn = blockIdx.x * 128;
    int wr = wv >> 1, wc = wv & 1;

    f32x4 acc[4][4];
    #pragma unroll
    for (int mi = 0; mi < 4; ++mi)
        #pragma unroll
        for (int ni = 0; ni < 4; ++ni)
            acc[mi][ni] = (f32x4){0.f, 0.f, 0.f, 0.f};

    int srow = wv * 16 + (lane >> 2);
    int scol = (lane & 3) * 8;
    const __hip_bfloat16* pa0 = H + (size_t)(bm + srow) * K + scol;
    const __hip_bfloat16* pa1 = H + (size_t)(bm + 64 + srow) * K + scol;
    const __hip_bfloat16* pb0 = W + (size_t)(bn + srow) * K + scol;
    const __hip_bfloat16* pb1 = W + (size_t)(bn + 64 + srow) * K + scol;
    char* At_b = (char*)&At[0][0] + wv * 1024;
    char* Bt_b = (char*)&Bt[0][0] + wv * 1024;

    for (int k0 = 0; k0 < K; k0 += 32) {
        gload_lds16(pa0 + k0, At_b);
        gload_lds16(pa1 + k0, At_b + 4096);
        gload_lds16(pb0 + k0, Bt_b);
        gload_lds16(pb1 + k0, Bt_b + 4096);
        __syncthreads();

        bf8_t af[4], bfr[4];
        #pragma unroll
        for (int mi = 0; mi < 4; ++mi)
            af[mi] = *(const bf8_t*)((const char*)&At[0][0] +
                     (wr * 64 + mi * 16 + (lane & 15)) * 64 + (lane >> 4) * 16);
        #pragma unroll
        for (int ni = 0; ni < 4; ++ni)
            bfr[ni] = *(const bf8_t*)((const char*)&Bt[0][0] +
                     (wc * 64 + ni * 16 + (lane & 15)) * 64 + (lane >> 4) * 16);
        #pragma unroll
        for (int mi = 0; mi < 4; ++mi)
            #pragma unroll
            for (int ni = 0; ni < 4; ++ni)
                acc[mi][ni] = __builtin_amdgcn_mfma_f32_16x16x32_bf16(
                    af[mi], bfr[ni], acc[mi][ni], 0, 0, 0);
        __syncthreads();
    }

    #pragma unroll
    for (int mi = 0; mi < 4; ++mi) {
        int r0 = bm + wr * 64 + mi * 16 + (lane >> 4) * 4;
        #pragma unroll
        for (int ni = 0; ni < 4; ++ni) {
            int np = bn + wc * 64 + ni * 16 + (lane & 15);
            int path = np >> 10, nl = np & 1023;
            #pragma unroll
            for (int j = 0; j < 4; ++j) {
                float v = acc[mi][ni][j];
                size_t oi = (size_t)(r0 + j) * Cdim + nl;
                if (path == 0)      decay[oi] = sigf(v + w0[nl]) * 0.60653065971263342f;
                else if (path == 1) at16[oi] = __float2bfloat16(sigf(v + a0[nl]));
                else if (path == 2) vt[oi] = sigf(v + v0[nl]);
                else                gt16[oi] = __float2bfloat16(v);
            }
        }
    }
}

// ---------------------------------------------------------------------------
// E1: kk-normalize -> aarr=-kkn, barr=kkn*at; ut; v_first passthrough.
// ---------------------------------------------------------------------------
__global__ __launch_bounds__(256) void e1_kernel(
    const float* __restrict__ kt, const __hip_bfloat16* __restrict__ at16,
    const float* __restrict__ rt, const float* __restrict__ vraw,
    const float* __restrict__ vt, const float* __restrict__ vfirst,
    const float* __restrict__ k_k, const float* __restrict__ k_a,
    const float* __restrict__ r_k,
    float* __restrict__ aarr, float* __restrict__ barr,
    float* __restrict__ ut, float* __restrict__ out2)
{
    int gid = blockIdx.x * 4 + (threadIdx.x >> 6);
    int lane = threadIdx.x & 63;
    int h = gid % Hdim;
    size_t idx = (size_t)gid * 64 + lane;
    int c = h * 64 + lane;
    float ktv = kt[idx];
    float atv = __bfloat162float(at16[idx]);
    float kk = ktv * k_k[c];
    float ss = wsum64(kk * kk);
    float norm = sqrtf(ss);
    float kkn = kk / fmaxf(norm, 1e-12f);
    aarr[idx] = -kkn;
    barr[idx] = kkn * atv;
    float kmix = ktv * (1.f + (atv - 1.f) * k_a[c]);
    float rv = rt[idx];
    float dot = wsum64(rv * kmix * r_k[c]);
    float vm = vraw[idx];
    float vf = vfirst[idx];
    vm = vm + (vf - vm) * vt[idx];
    ut[idx] = dot * vm;
    out2[idx] = vf;
}

// ---------------------------------------------------------------------------
// WKV scan v6: 16-way row-split, XCD-local chunk placement, 4 rows x 16
// lanes/row, 4-deep asm-batched reg pipeline.
//  - blk = chunk*32 + bh: a bh's 16 chunks sit at stride-32 block indices,
//    all == bh (mod 8) -> SAME XCD -> chunk-duplicated operand reads are
//    L2-local (R10: bh-major order spread chunks across XCDs; FETCH was
//    180MB = 24 unique x 7.5).
//  - 512 blocks x 64 thr = 2 waves/CU (TLP); per-set VMEM = 6 instr
//    (5 dwordx4 + 1 dword, 512B/wave) vs 11.
//  - 16-lane reduce: DPP quad xor1/xor2 + shfl_xor 4 + shfl_xor 8.
//  - vmcnt(18) = 3 newer 6-load sets (stores over-wait by <=1, harmless;
//    same derivation as R9's 33).
// ---------------------------------------------------------------------------
struct Ops { f4 a, d, k, b, r; float vi; };

static __device__ __forceinline__ void load_set(
    Ops& s, const float* pa, const float* pd, const float* pk,
    const float* pb, const float* pr, const float* pv)
{
    asm volatile(
        "global_load_dwordx4 %0, %6, off\n\t"
        "global_load_dword   %5, %11, off\n\t"
        "global_load_dwordx4 %1, %7, off\n\t"
        "global_load_dwordx4 %2, %8, off\n\t"
        "global_load_dwordx4 %3, %9, off\n\t"
        "global_load_dwordx4 %4, %10, off"
        : "=&v"(s.a), "=&v"(s.d), "=&v"(s.k), "=&v"(s.b), "=&v"(s.r), "=&v"(s.vi)
        : "v"(pa), "v"(pd), "v"(pk), "v"(pb), "v"(pr), "v"(pv));
}

static __device__ __forceinline__ void wkv_wait18() {
    asm volatile("s_waitcnt vmcnt(18)" ::: "memory");
    __builtin_amdgcn_sched_barrier(0);
}

static __device__ __forceinline__ float red16(float x) {
    float y = quad_reduce(x);
    y += __shfl_xor(y, 4);
    y += __shfl_xor(y, 8);
    return y;
}

static __device__ __forceinline__ void wkv_compute(
    float S[4], const Ops& o, float* po, int q)
{
    float s0 = S[0] * o.a.x, s1 = S[1] * o.a.y;
    float s2 = S[2] * o.a.z, s3 = S[3] * o.a.w;
    float sp = red16((s0 + s1) + (s2 + s3));

    S[0] = fmaf(S[0], o.d.x, fmaf(sp, o.b.x, o.vi * o.k.x));
    S[1] = fmaf(S[1], o.d.y, fmaf(sp, o.b.y, o.vi * o.k.y));
    S[2] = fmaf(S[2], o.d.z, fmaf(sp, o.b.z, o.vi * o.k.z));
    S[3] = fmaf(S[3], o.d.w, fmaf(sp, o.b.w, o.vi * o.k.w));

    float o0 = S[0] * o.r.x, o1 = S[1] * o.r.y;
    float o2 = S[2] * o.r.z, o3 = S[3] * o.r.w;
    float op = red16((o0 + o1) + (o2 + o3));
    if (q == 0) *po = op;
}

__global__ __launch_bounds__(64, 1) void wkv_kernel(
    const float* __restrict__ rt, const float* __restrict__ decay,
    const float* __restrict__ kt, const float* __restrict__ vt,
    const float* __restrict__ aarr, const float* __restrict__ barr,
    float* __restrict__ wkvt)
{
    int tid = threadIdx.x;
    int blk = blockIdx.x;              // 512 blocks: chunk*32 + bh
    int chunk = blk >> 5, bh = blk & 31;
    int b = bh >> 4, h = bh & 15;
    int i = chunk * 4 + (tid >> 4);    // state row owned by this 16-lane group
    int q = tid & 15;                  // column-slice owner (4 cols)
    int jb = q * 4;
    size_t base = ((size_t)b * Tdim) * Cdim + (size_t)h * Ndim;
    const float* pa = aarr + base + jb;
    const float* pd = decay + base + jb;
    const float* pk = kt + base + jb;
    const float* pb = barr + base + jb;
    const float* pr = rt + base + jb;
    const float* pv = vt + base + i;
    float* po = wkvt + base + i;

    float S[4];
    #pragma unroll
    for (int j = 0; j < 4; ++j) S[j] = 0.f;

    Ops A, B, C, D;
    load_set(A, pa, pd, pk, pb, pr, pv);
    {
        size_t o1 = (size_t)1 * Cdim, o2 = (size_t)2 * Cdim, o3 = (size_t)3 * Cdim;
        load_set(B, pa + o1, pd + o1, pk + o1, pb + o1, pr + o1, pv + o1);
        load_set(C, pa + o2, pd + o2, pk + o2, pb + o2, pr + o2, pv + o2);
        load_set(D, pa + o3, pd + o3, pk + o3, pb + o3, pr + o3, pv + o3);
    }

    for (int t = 0; t < Tdim; t += 4) {
        wkv_wait18();
        wkv_compute(S, A, po + (size_t)t * Cdim, q);
        size_t o4 = (size_t)((t + 4 < Tdim) ? t + 4 : Tdim - 1) * Cdim;
        load_set(A, pa + o4, pd + o4, pk + o4, pb + o4, pr + o4, pv + o4);

        wkv_wait18();
        wkv_compute(S, B, po + (size_t)(t + 1) * Cdim, q);
        size_t o5 = (size_t)((t + 5 < Tdim) ? t + 5 : Tdim - 1) * Cdim;
        load_set(B, pa + o5, pd + o5, pk + o5, pb + o5, pr + o5, pv + o5);

        wkv_wait18();
        wkv_compute(S, C, po + (size_t)(t + 2) * Cdim, q);
        size_t o6 = (size_t)((t + 6 < Tdim) ? t + 6 : Tdim - 1) * Cdim;
        load_set(C, pa + o6, pd + o6, pk + o6, pb + o6, pr + o6, pv + o6);

        wkv_wait18();
        wkv_compute(S, D, po + (size_t)(t + 3) * Cdim, q);
        size_t o7 = (size_t)((t + 7 < Tdim) ? t + 7 : Tdim - 1) * Cdim;
        load_set(D, pa + o7, pd + o7, pk + o7, pb + o7, pr + o7, pv + o7);
    }
}

// ---------------------------------------------------------------------------
// E2: pt = GroupNorm(rt*wkvt)*ln_g + ln_b + ut; g16 = bf16(gt*pt)
// ---------------------------------------------------------------------------
__global__ __launch_bounds__(256) void e2_kernel(
    const float* __restrict__ rt, const float* __restrict__ wkvt,
    const float* __restrict__ ut, const __hip_bfloat16* __restrict__ gt16,
    const float* __restrict__ ln_g, const float* __restrict__ ln_b,
    __hip_bfloat16* __restrict__ g16)
{
    int gid = blockIdx.x * 4 + (threadIdx.x >> 6);
    int lane = threadIdx.x & 63;
    int h = gid % Hdim;
    size_t idx = (size_t)gid * 64 + lane;
    int c = h * 64 + lane;
    float x = rt[idx] * wkvt[idx];
    float mu = wsum64(x) * (1.f / 64.f);
    float d = x - mu;
    float var = wsum64(d * d) * (1.f / 64.f);
    float xn = d / sqrtf(var + EPS_GN);
    float pt = xn * ln_g[c] + ln_b[c] + ut[idx];
    float res = __bfloat162float(gt16[idx]) * pt;
    g16[idx] = __float2bfloat16(res);
}

// ---------------------------------------------------------------------------
extern "C" void kernel_launch(void* const* d_in, const int* in_sizes, int n_in,
                              void* d_out, int out_size, void* d_ws, size_t ws_size,
                              hipStream_t stream)
{
    (void)in_sizes; (void)n_in; (void)out_size; (void)ws_size;
    const float* xt      = (const float*)d_in[0];
    const float* v_first = (const float*)d_in[1];
    const float* tmix_r  = (const float*)d_in[2];
    const float* tmix_w  = (const float*)d_in[3];
    const float* tmix_k  = (const float*)d_in[4];
    const float* tmix_v  = (const float*)d_in[5];
    const float* tmix_a  = (const float*)d_in[6];
    const float* tmix_g  = (const float*)d_in[7];
    const float* w1 = (const float*)d_in[8];
    const float* w2 = (const float*)d_in[9];
    const float* w0 = (const float*)d_in[10];
    const float* a1 = (const float*)d_in[11];
    const float* a2 = (const float*)d_in[12];
    const float* a0 = (const float*)d_in[13];
    const float* v1 = (const float*)d_in[14];
    const float* v2 = (const float*)d_in[15];
    const float* v0 = (const float*)d_in[16];
    const float* g1 = (const float*)d_in[17];
    const float* g2 = (const float*)d_in[18];
    const float* k_k = (const float*)d_in[19];
    const float* k_a = (const float*)d_in[20];
    const float* r_k = (const float*)d_in[21];
    const float* W_r = (const float*)d_in[22];
    const float* W_k = (const float*)d_in[23];
    const float* W_v = (const float*)d_in[24];
    const float* W_o = (const float*)d_in[25];
    const float* ln_g = (const float*)d_in[26];
    const float* ln_b = (const float*)d_in[27];

    float* out = (float*)d_out;
    const size_t BTC = (size_t)Bdim * Tdim * Cdim;   // 2,097,152
    const int M = Bdim * Tdim;                        // 2048

    float* ws = (float*)d_ws;
    float* rt    = ws + 0 * BTC;
    float* kt    = ws + 1 * BTC;
    float* vraw  = ws + 2 * BTC;
    float* vt    = ws + 3 * BTC;
    float* decay = ws + 4 * BTC;
    float* aarr  = ws + 5 * BTC;
    float* barr  = ws + 6 * BTC;
    float* ut    = ws + 7 * BTC;
    float* wkv   = ws + 8 * BTC;
    __hip_bfloat16* bfa = (__hip_bfloat16*)(ws + 9 * BTC);
    __hip_bfloat16* at16 = bfa + 0 * BTC;
    __hip_bfloat16* gt16 = bfa + 1 * BTC;
    __hip_bfloat16* xr16 = bfa + 2 * BTC;
    __hip_bfloat16* xk16 = bfa + 3 * BTC;
    __hip_bfloat16* xv16 = bfa + 4 * BTC;   // reused as g16 after gemm3
    __hip_bfloat16* Wb   = bfa + 5 * BTC;   // 4*CCdim = 2*BTC bf16
    // Aliased scratch (dead before their slots' writers run):
    __hip_bfloat16* Aall = (__hip_bfloat16*)decay;           // 8MB (decay written later by gemm_lr2)
    __hip_bfloat16* Wlr1 = (__hip_bfloat16*)aarr;            // (aarr written later by e1)
    __hip_bfloat16* Wl2  = Wlr1 + (size_t)384 * 2048;
    __hip_bfloat16* hcat = Wl2 + (size_t)4096 * 288;
    __hip_bfloat16* g16 = xv16;

    // weight prep: big W -> bf16, Wlr1, Wl2 (one dispatch, 3 segments)
    prep_weights<<<6528, 256, 0, stream>>>(
        W_r, W_k, W_v, W_o, w1, a1, v1, g1, w2, a2, v2, g2,
        tmix_w, tmix_a, tmix_v, tmix_g, Wb, Wlr1, Wl2);

    // activation prep: 3 lerps -> bf16, Aall = [x | xprev] bf16
    prep_all<<<1024, 256, 0, stream>>>(xt, tmix_r, tmix_k, tmix_v,
                                       xr16, xk16, xv16, Aall);

    // low-rank chain as 2 MFMA GEMMs
    gemm_lr1<<<dim3(3, 16), 256, 0, stream>>>(Aall, Wlr1, hcat);
    gemm_lr2<<<dim3(32, 16), 256, 0, stream>>>(hcat, Wl2, w0, a0, v0,
                                               decay, at16, vt, gt16);

    // 3 big projections in one dispatch (384 blocks, full chip)
    dim3 gg3(Cdim / 128, M / 128, 3);
    gemm3_mfma<<<gg3, 256, 0, stream>>>(xr16, xk16, xv16, Wb, rt, kt, vraw);

    // E1
    e1_kernel<<<(Bdim * Tdim * Hdim) / 4, 256, 0, stream>>>(
        kt, at16, rt, vraw, vt, v_first, k_k, k_a, r_k,
        aarr, barr, ut, out + BTC);

    // WKV scan (16-way XCD-local split, 4-deep reg pipeline)
    wkv_kernel<<<512, 64, 0, stream>>>(rt, decay, kt, vt, aarr, barr, wkv);

    // E2 (writes bf16 gated output)
    e2_kernel<<<(Bdim * Tdim * Hdim) / 4, 256, 0, stream>>>(
        rt, wkv, ut, gt16, ln_g, ln_b, g16);

    // output projection (bf16 MFMA)
    dim3 gg(Cdim / 128, M / 128);
    gemm_mfma<<<gg, 256, 0, stream>>>(g16, Wb + 3 * (size_t)CCdim, out, M, Cdim, Cdim);
}

// Round 12
// 350.413 us; speedup vs baseline: 1.2138x; 1.2138x over previous
//
#include <hip/hip_runtime.h>
#include <hip/hip_bf16.h>
#include <math.h>

#define Bdim 2
#define Tdim 1024
#define Cdim 1024
#define Hdim 16
#define Ndim 64
#define CCdim (Cdim * Cdim)
#define EPS_GN 0.00064f

typedef __bf16 bf8_t __attribute__((ext_vector_type(8)));
typedef float f32x4 __attribute__((ext_vector_type(4)));
typedef float f4 __attribute__((ext_vector_type(4)));

static __device__ __forceinline__ float sigf(float x) { return 1.f / (1.f + expf(-x)); }

static __device__ __forceinline__ float wsum64(float v) {
    #pragma unroll
    for (int m = 1; m < 64; m <<= 1) v += __shfl_xor(v, m);
    return v;
}

static __device__ __forceinline__ void gload_lds16(const void* g, void* l) {
    __builtin_amdgcn_global_load_lds(
        (const __attribute__((address_space(1))) void*)g,
        (__attribute__((address_space(3))) void*)l, 16, 0, 0);
}

// 8-lane sum, ALL-DPP (no LDS-pipe shfl): quad_perm xor1, xor2, then
// row_half_mirror (0x141: lane i <- 7-i within each 8-lane group).
// R11 lesson: each shfl_xor is ~35cyc (ds_bpermute); DPP is ~5-8cyc.
static __device__ __forceinline__ float red8_dpp(float x) {
    int s1 = __builtin_amdgcn_update_dpp(0, __builtin_bit_cast(int, x),
                                         0xB1, 0xF, 0xF, true);   // [1,0,3,2]
    float y = x + __builtin_bit_cast(float, s1);
    int s2 = __builtin_amdgcn_update_dpp(0, __builtin_bit_cast(int, y),
                                         0x4E, 0xF, 0xF, true);   // [2,3,0,1]
    float z = y + __builtin_bit_cast(float, s2);
    int s3 = __builtin_amdgcn_update_dpp(0, __builtin_bit_cast(int, z),
                                         0x141, 0xF, 0xF, true);  // row_half_mirror
    return z + __builtin_bit_cast(float, s3);
}

// ---------------------------------------------------------------------------
// prep_weights: 3 segments in one dispatch (unchanged).
// ---------------------------------------------------------------------------
__global__ __launch_bounds__(256) void prep_weights(
    const float* __restrict__ W0, const float* __restrict__ W1,
    const float* __restrict__ W2, const float* __restrict__ W3,
    const float* __restrict__ w1, const float* __restrict__ a1,
    const float* __restrict__ v1, const float* __restrict__ g1,
    const float* __restrict__ w2, const float* __restrict__ a2,
    const float* __restrict__ v2, const float* __restrict__ g2,
    const float* __restrict__ mw, const float* __restrict__ ma,
    const float* __restrict__ mv, const float* __restrict__ mg,
    __hip_bfloat16* __restrict__ Wb, __hip_bfloat16* __restrict__ Wlr1,
    __hip_bfloat16* __restrict__ Wl2)
{
    int blk = blockIdx.x;
    int tid = threadIdx.x;
    if (blk < 2048) {
        int which = blk >> 9;
        const float* src = (which == 0) ? W0 : (which == 1) ? W1 : (which == 2) ? W2 : W3;
        size_t e8 = ((size_t)(blk & 511) * 256 + tid) * 8;
        float c[8];
        *(float4*)&c[0] = ((const float4*)(src + e8))[0];
        *(float4*)&c[4] = ((const float4*)(src + e8))[1];
        __hip_bfloat16 o[8];
        #pragma unroll
        for (int j = 0; j < 8; ++j) o[j] = __float2bfloat16(c[j]);
        __hip_bfloat16* dst = Wb + (size_t)which * CCdim + e8;
        ((ushort4*)dst)[0] = *(ushort4*)&o[0];
        ((ushort4*)dst)[1] = *(ushort4*)&o[4];
    } else if (blk < 2432) {
        int n = blk - 2048;                 // 0..383
        if (n < 288) {
            const float* M1; const float* mix; int D, nl;
            if (n < 64)       { M1 = w1; mix = mw; D = 64;  nl = n; }
            else if (n < 128) { M1 = a1; mix = ma; D = 64;  nl = n - 64; }
            else if (n < 160) { M1 = v1; mix = mv; D = 32;  nl = n - 128; }
            else              { M1 = g1; mix = mg; D = 128; nl = n - 160; }
            #pragma unroll
            for (int i = 0; i < 8; ++i) {
                int kp = tid + i * 256;     // 0..2047
                int k = kp & 1023, half = kp >> 10;
                float mx = mix[k];
                float val = M1[(size_t)k * D + nl] * (half ? mx : 1.f - mx);
                Wlr1[(size_t)n * 2048 + kp] = __float2bfloat16(val);
            }
        } else {
            #pragma unroll
            for (int i = 0; i < 8; ++i)
                Wlr1[(size_t)n * 2048 + tid + i * 256] = __float2bfloat16(0.f);
        }
    } else {
        int np = blk - 2432;                // 0..4095
        int path = np >> 10, nl = np & 1023;
        const float* M2; int off, D;
        if (path == 0)      { M2 = w2; off = 0;   D = 64; }
        else if (path == 1) { M2 = a2; off = 64;  D = 64; }
        else if (path == 2) { M2 = v2; off = 128; D = 32; }
        else                { M2 = g2; off = 160; D = 128; }
        for (int kp = tid; kp < 288; kp += 256) {
            int kl = kp - off;
            float val = (kl >= 0 && kl < D) ? M2[(size_t)kl * Cdim + nl] : 0.f;
            Wl2[(size_t)np * 288 + kp] = __float2bfloat16(val);
        }
    }
}

// ---------------------------------------------------------------------------
// prep_all: token-shift lerps (r,k,v) -> bf16 + Aall = [x | xprev] bf16.
// ---------------------------------------------------------------------------
__global__ __launch_bounds__(256) void prep_all(
    const float* __restrict__ xt,
    const float* __restrict__ mr, const float* __restrict__ mk, const float* __restrict__ mv,
    __hip_bfloat16* __restrict__ xr16, __hip_bfloat16* __restrict__ xk16,
    __hip_bfloat16* __restrict__ xv16, __hip_bfloat16* __restrict__ Aall)
{
    int idx8 = blockIdx.x * 256 + threadIdx.x;   // 0..262143
    int m = idx8 >> 7;
    int c8 = (idx8 & 127) * 8;
    int t = m & (Tdim - 1);
    const float* p = xt + (size_t)idx8 * 8;
    float cur[8], prv[8];
    *(float4*)&cur[0] = ((const float4*)p)[0];
    *(float4*)&cur[4] = ((const float4*)p)[1];
    if (t > 0) {
        *(float4*)&prv[0] = ((const float4*)(p - Cdim))[0];
        *(float4*)&prv[4] = ((const float4*)(p - Cdim))[1];
    } else {
        #pragma unroll
        for (int j = 0; j < 8; ++j) prv[j] = 0.f;
    }
    float mx[8];
    __hip_bfloat16 o[8];
    size_t ob = (size_t)idx8 * 8;

    *(float4*)&mx[0] = *(const float4*)(mr + c8);
    *(float4*)&mx[4] = *(const float4*)(mr + c8 + 4);
    #pragma unroll
    for (int j = 0; j < 8; ++j) o[j] = __float2bfloat16(cur[j] + (prv[j] - cur[j]) * mx[j]);
    ((ushort4*)(xr16 + ob))[0] = *(ushort4*)&o[0];
    ((ushort4*)(xr16 + ob))[1] = *(ushort4*)&o[4];

    *(float4*)&mx[0] = *(const float4*)(mk + c8);
    *(float4*)&mx[4] = *(const float4*)(mk + c8 + 4);
    #pragma unroll
    for (int j = 0; j < 8; ++j) o[j] = __float2bfloat16(cur[j] + (prv[j] - cur[j]) * mx[j]);
    ((ushort4*)(xk16 + ob))[0] = *(ushort4*)&o[0];
    ((ushort4*)(xk16 + ob))[1] = *(ushort4*)&o[4];

    *(float4*)&mx[0] = *(const float4*)(mv + c8);
    *(float4*)&mx[4] = *(const float4*)(mv + c8 + 4);
    #pragma unroll
    for (int j = 0; j < 8; ++j) o[j] = __float2bfloat16(cur[j] + (prv[j] - cur[j]) * mx[j]);
    ((ushort4*)(xv16 + ob))[0] = *(ushort4*)&o[0];
    ((ushort4*)(xv16 + ob))[1] = *(ushort4*)&o[4];

    size_t ab = (size_t)m * 2048 + c8;
    #pragma unroll
    for (int j = 0; j < 8; ++j) o[j] = __float2bfloat16(cur[j]);
    ((ushort4*)(Aall + ab))[0] = *(ushort4*)&o[0];
    ((ushort4*)(Aall + ab))[1] = *(ushort4*)&o[4];
    #pragma unroll
    for (int j = 0; j < 8; ++j) o[j] = __float2bfloat16(prv[j]);
    ((ushort4*)(Aall + ab + 1024))[0] = *(ushort4*)&o[0];
    ((ushort4*)(Aall + ab + 1024))[1] = *(ushort4*)&o[4];
}

// ---------------------------------------------------------------------------
// Triple bf16 MFMA GEMM (z = 0,1,2 selects A/W/C): 128x128 tile, BK=32.
// ---------------------------------------------------------------------------
__global__ __launch_bounds__(256) void gemm3_mfma(
    const __hip_bfloat16* __restrict__ A0, const __hip_bfloat16* __restrict__ A1,
    const __hip_bfloat16* __restrict__ A2, const __hip_bfloat16* __restrict__ Wbase,
    float* __restrict__ C0, float* __restrict__ C1, float* __restrict__ C2)
{
    const int N = Cdim, K = Cdim;
    __shared__ unsigned short At[128][32];
    __shared__ unsigned short Bt[128][32];
    int z = blockIdx.z;
    const __hip_bfloat16* A = (z == 0) ? A0 : (z == 1) ? A1 : A2;
    const __hip_bfloat16* Bw = Wbase + (size_t)z * CCdim;
    float* Cout = (z == 0) ? C0 : (z == 1) ? C1 : C2;
    int tid = threadIdx.x;
    int lane = tid & 63, wv = tid >> 6;
    int bm = blockIdx.y * 128, bn = blockIdx.x * 128;
    int wr = wv >> 1, wc = wv & 1;

    f32x4 acc[4][4];
    #pragma unroll
    for (int mi = 0; mi < 4; ++mi)
        #pragma unroll
        for (int ni = 0; ni < 4; ++ni)
            acc[mi][ni] = (f32x4){0.f, 0.f, 0.f, 0.f};

    int srow = wv * 16 + (lane >> 2);
    int scol = (lane & 3) * 8;
    const __hip_bfloat16* pa0 = A + (size_t)(bm + srow) * K + scol;
    const __hip_bfloat16* pa1 = A + (size_t)(bm + 64 + srow) * K + scol;
    const __hip_bfloat16* pb0 = Bw + (size_t)(bn + srow) * K + scol;
    const __hip_bfloat16* pb1 = Bw + (size_t)(bn + 64 + srow) * K + scol;
    char* At_b = (char*)&At[0][0] + wv * 1024;
    char* Bt_b = (char*)&Bt[0][0] + wv * 1024;

    for (int k0 = 0; k0 < K; k0 += 32) {
        gload_lds16(pa0 + k0, At_b);
        gload_lds16(pa1 + k0, At_b + 4096);
        gload_lds16(pb0 + k0, Bt_b);
        gload_lds16(pb1 + k0, Bt_b + 4096);
        __syncthreads();

        bf8_t af[4], bfr[4];
        #pragma unroll
        for (int mi = 0; mi < 4; ++mi)
            af[mi] = *(const bf8_t*)((const char*)&At[0][0] +
                     (wr * 64 + mi * 16 + (lane & 15)) * 64 + (lane >> 4) * 16);
        #pragma unroll
        for (int ni = 0; ni < 4; ++ni)
            bfr[ni] = *(const bf8_t*)((const char*)&Bt[0][0] +
                     (wc * 64 + ni * 16 + (lane & 15)) * 64 + (lane >> 4) * 16);
        #pragma unroll
        for (int mi = 0; mi < 4; ++mi)
            #pragma unroll
            for (int ni = 0; ni < 4; ++ni)
                acc[mi][ni] = __builtin_amdgcn_mfma_f32_16x16x32_bf16(
                    af[mi], bfr[ni], acc[mi][ni], 0, 0, 0);
        __syncthreads();
    }

    #pragma unroll
    for (int mi = 0; mi < 4; ++mi) {
        int r0 = bm + wr * 64 + mi * 16 + (lane >> 4) * 4;
        #pragma unroll
        for (int ni = 0; ni < 4; ++ni) {
            int c0 = bn + wc * 64 + ni * 16 + (lane & 15);
            #pragma unroll
            for (int j = 0; j < 4; ++j)
                Cout[(size_t)(r0 + j) * N + c0] = acc[mi][ni][j];
        }
    }
}

// ---------------------------------------------------------------------------
// Single bf16 MFMA GEMM (output projection).
// ---------------------------------------------------------------------------
__global__ __launch_bounds__(256) void gemm_mfma(
    const __hip_bfloat16* __restrict__ A, const __hip_bfloat16* __restrict__ Bw,
    float* __restrict__ Cout, int M, int N, int K)
{
    __shared__ unsigned short At[128][32];
    __shared__ unsigned short Bt[128][32];
    int tid = threadIdx.x;
    int lane = tid & 63, wv = tid >> 6;
    int bm = blockIdx.y * 128, bn = blockIdx.x * 128;
    int wr = wv >> 1, wc = wv & 1;

    f32x4 acc[4][4];
    #pragma unroll
    for (int mi = 0; mi < 4; ++mi)
        #pragma unroll
        for (int ni = 0; ni < 4; ++ni)
            acc[mi][ni] = (f32x4){0.f, 0.f, 0.f, 0.f};

    int srow = wv * 16 + (lane >> 2);
    int scol = (lane & 3) * 8;
    const __hip_bfloat16* pa0 = A + (size_t)(bm + srow) * K + scol;
    const __hip_bfloat16* pa1 = A + (size_t)(bm + 64 + srow) * K + scol;
    const __hip_bfloat16* pb0 = Bw + (size_t)(bn + srow) * K + scol;
    const __hip_bfloat16* pb1 = Bw + (size_t)(bn + 64 + srow) * K + scol;
    char* At_b = (char*)&At[0][0] + wv * 1024;
    char* Bt_b = (char*)&Bt[0][0] + wv * 1024;

    for (int k0 = 0; k0 < K; k0 += 32) {
        gload_lds16(pa0 + k0, At_b);
        gload_lds16(pa1 + k0, At_b + 4096);
        gload_lds16(pb0 + k0, Bt_b);
        gload_lds16(pb1 + k0, Bt_b + 4096);
        __syncthreads();

        bf8_t af[4], bfr[4];
        #pragma unroll
        for (int mi = 0; mi < 4; ++mi)
            af[mi] = *(const bf8_t*)((const char*)&At[0][0] +
                     (wr * 64 + mi * 16 + (lane & 15)) * 64 + (lane >> 4) * 16);
        #pragma unroll
        for (int ni = 0; ni < 4; ++ni)
            bfr[ni] = *(const bf8_t*)((const char*)&Bt[0][0] +
                     (wc * 64 + ni * 16 + (lane & 15)) * 64 + (lane >> 4) * 16);
        #pragma unroll
        for (int mi = 0; mi < 4; ++mi)
            #pragma unroll
            for (int ni = 0; ni < 4; ++ni)
                acc[mi][ni] = __builtin_amdgcn_mfma_f32_16x16x32_bf16(
                    af[mi], bfr[ni], acc[mi][ni], 0, 0, 0);
        __syncthreads();
    }

    #pragma unroll
    for (int mi = 0; mi < 4; ++mi) {
        int r0 = bm + wr * 64 + mi * 16 + (lane >> 4) * 4;
        #pragma unroll
        for (int ni = 0; ni < 4; ++ni) {
            int c0 = bn + wc * 64 + ni * 16 + (lane & 15);
            #pragma unroll
            for (int j = 0; j < 4; ++j)
                Cout[(size_t)(r0 + j) * N + c0] = acc[mi][ni][j];
        }
    }
}

// ---------------------------------------------------------------------------
// gemm_lr1: H[2048][288] = Aall @ Wlr1^T, bf16 out, per-range activation.
// ---------------------------------------------------------------------------
__global__ __launch_bounds__(256) void gemm_lr1(
    const __hip_bfloat16* __restrict__ A, const __hip_bfloat16* __restrict__ W,
    __hip_bfloat16* __restrict__ H)
{
    const int K = 2048;
    __shared__ unsigned short At[128][32];
    __shared__ unsigned short Bt[128][32];
    int tid = threadIdx.x;
    int lane = tid & 63, wv = tid >> 6;
    int bm = blockIdx.y * 128, bn = blockIdx.x * 128;
    int wr = wv >> 1, wc = wv & 1;

    f32x4 acc[4][4];
    #pragma unroll
    for (int mi = 0; mi < 4; ++mi)
        #pragma unroll
        for (int ni = 0; ni < 4; ++ni)
            acc[mi][ni] = (f32x4){0.f, 0.f, 0.f, 0.f};

    int srow = wv * 16 + (lane >> 2);
    int scol = (lane & 3) * 8;
    const __hip_bfloat16* pa0 = A + (size_t)(bm + srow) * K + scol;
    const __hip_bfloat16* pa1 = A + (size_t)(bm + 64 + srow) * K + scol;
    const __hip_bfloat16* pb0 = W + (size_t)(bn + srow) * K + scol;
    const __hip_bfloat16* pb1 = W + (size_t)(bn + 64 + srow) * K + scol;
    char* At_b = (char*)&At[0][0] + wv * 1024;
    char* Bt_b = (char*)&Bt[0][0] + wv * 1024;

    for (int k0 = 0; k0 < K; k0 += 32) {
        gload_lds16(pa0 + k0, At_b);
        gload_lds16(pa1 + k0, At_b + 4096);
        gload_lds16(pb0 + k0, Bt_b);
        gload_lds16(pb1 + k0, Bt_b + 4096);
        __syncthreads();

        bf8_t af[4], bfr[4];
        #pragma unroll
        for (int mi = 0; mi < 4; ++mi)
            af[mi] = *(const bf8_t*)((const char*)&At[0][0] +
                     (wr * 64 + mi * 16 + (lane & 15)) * 64 + (lane >> 4) * 16);
        #pragma unroll
        for (int ni = 0; ni < 4; ++ni)
            bfr[ni] = *(const bf8_t*)((const char*)&Bt[0][0] +
                     (wc * 64 + ni * 16 + (lane & 15)) * 64 + (lane >> 4) * 16);
        #pragma unroll
        for (int mi = 0; mi < 4; ++mi)
            #pragma unroll
            for (int ni = 0; ni < 4; ++ni)
                acc[mi][ni] = __builtin_amdgcn_mfma_f32_16x16x32_bf16(
                    af[mi], bfr[ni], acc[mi][ni], 0, 0, 0);
        __syncthreads();
    }

    #pragma unroll
    for (int mi = 0; mi < 4; ++mi) {
        int r0 = bm + wr * 64 + mi * 16 + (lane >> 4) * 4;
        #pragma unroll
        for (int ni = 0; ni < 4; ++ni) {
            int c0 = bn + wc * 64 + ni * 16 + (lane & 15);
            if (c0 < 288) {
                #pragma unroll
                for (int j = 0; j < 4; ++j) {
                    float v = acc[mi][ni][j];
                    if (c0 < 64) v = tanhf(v);
                    else if (c0 >= 160) v = sigf(v);
                    H[(size_t)(r0 + j) * 288 + c0] = __float2bfloat16(v);
                }
            }
        }
    }
}

// ---------------------------------------------------------------------------
// gemm_lr2: block-diag expansion, epilogue demux (unchanged).
// ---------------------------------------------------------------------------
__global__ __launch_bounds__(256) void gemm_lr2(
    const __hip_bfloat16* __restrict__ H, const __hip_bfloat16* __restrict__ W,
    const float* __restrict__ w0, const float* __restrict__ a0,
    const float* __restrict__ v0,
    float* __restrict__ decay, __hip_bfloat16* __restrict__ at16,
    float* __restrict__ vt, __hip_bfloat16* __restrict__ gt16)
{
    const int K = 288;
    __shared__ unsigned short At[128][32];
    __shared__ unsigned short Bt[128][32];
    int tid = threadIdx.x;
    int lane = tid & 63, wv = tid >> 6;
    int bm = blockIdx.y * 128, bn = blockIdx.x * 128;
    int wr = wv >> 1, wc = wv & 1;

    f32x4 acc[4][4];
    #pragma unroll
    for (int mi = 0; mi < 4; ++mi)
        #pragma unroll
        for (int ni = 0; ni < 4; ++ni)
            acc[mi][ni] = (f32x4){0.f, 0.f, 0.f, 0.f};

    int srow = wv * 16 + (lane >> 2);
    int scol = (lane & 3) * 8;
    const __hip_bfloat16* pa0 = H + (size_t)(bm + srow) * K + scol;
    const __hip_bfloat16* pa1 = H + (size_t)(bm + 64 + srow) * K + scol;
    const __hip_bfloat16* pb0 = W + (size_t)(bn + srow) * K + scol;
    const __hip_bfloat16* pb1 = W + (size_t)(bn + 64 + srow) * K + scol;
    char* At_b = (char*)&At[0][0] + wv * 1024;
    char* Bt_b = (char*)&Bt[0][0] + wv * 1024;

    for (int k0 = 0; k0 < K; k0 += 32) {
        gload_lds16(pa0 + k0, At_b);
        gload_lds16(pa1 + k0, At_b + 4096);
        gload_lds16(pb0 + k0, Bt_b);
        gload_lds16(pb1 + k0, Bt_b + 4096);
        __syncthreads();

        bf8_t af[4], bfr[4];
        #pragma unroll
        for (int mi = 0; mi < 4; ++mi)
            af[mi] = *(const bf8_t*)((const char*)&At[0][0] +
                     (wr * 64 + mi * 16 + (lane & 15)) * 64 + (lane >> 4) * 16);
        #pragma unroll
        for (int ni = 0; ni < 4; ++ni)
            bfr[ni] = *(const bf8_t*)((const char*)&Bt[0][0] +
                     (wc * 64 + ni * 16 + (lane & 15)) * 64 + (lane >> 4) * 16);
        #pragma unroll
        for (int mi = 0; mi < 4; ++mi)
            #pragma unroll
            for (int ni = 0; ni < 4; ++ni)
                acc[mi][ni] = __builtin_amdgcn_mfma_f32_16x16x32_bf16(
                    af[mi], bfr[ni], acc[mi][ni], 0, 0, 0);
        __syncthreads();
    }

    #pragma unroll
    for (int mi = 0; mi < 4; ++mi) {
        int r0 = bm + wr * 64 + mi * 16 + (lane >> 4) * 4;
        #pragma unroll
        for (int ni = 0; ni < 4; ++ni) {
            int np = bn + wc * 64 + ni * 16 + (lane & 15);
            int path = np >> 10, nl = np & 1023;
            #pragma unroll
            for (int j = 0; j < 4; ++j) {
                float v = acc[mi][ni][j];
                size_t oi = (size_t)(r0 + j) * Cdim + nl;
                if (path == 0)      decay[oi] = sigf(v + w0[nl]) * 0.60653065971263342f;
                else if (path == 1) at16[oi] = __float2bfloat16(sigf(v + a0[nl]));
                else if (path == 2) vt[oi] = sigf(v + v0[nl]);
                else                gt16[oi] = __float2bfloat16(v);
            }
        }
    }
}

// ---------------------------------------------------------------------------
// E1: kk-normalize -> aarr=-kkn, barr=kkn*at; ut; v_first passthrough.
// ---------------------------------------------------------------------------
__global__ __launch_bounds__(256) void e1_kernel(
    const float* __restrict__ kt, const __hip_bfloat16* __restrict__ at16,
    const float* __restrict__ rt, const float* __restrict__ vraw,
    const float* __restrict__ vt, const float* __restrict__ vfirst,
    const float* __restrict__ k_k, const float* __restrict__ k_a,
    const float* __restrict__ r_k,
    float* __restrict__ aarr, float* __restrict__ barr,
    float* __restrict__ ut, float* __restrict__ out2)
{
    int gid = blockIdx.x * 4 + (threadIdx.x >> 6);
    int lane = threadIdx.x & 63;
    int h = gid % Hdim;
    size_t idx = (size_t)gid * 64 + lane;
    int c = h * 64 + lane;
    float ktv = kt[idx];
    float atv = __bfloat162float(at16[idx]);
    float kk = ktv * k_k[c];
    float ss = wsum64(kk * kk);
    float norm = sqrtf(ss);
    float kkn = kk / fmaxf(norm, 1e-12f);
    aarr[idx] = -kkn;
    barr[idx] = kkn * atv;
    float kmix = ktv * (1.f + (atv - 1.f) * k_a[c]);
    float rv = rt[idx];
    float dot = wsum64(rv * kmix * r_k[c]);
    float vm = vraw[idx];
    float vf = vfirst[idx];
    vm = vm + (vf - vm) * vt[idx];
    ut[idx] = dot * vm;
    out2[idx] = vf;
}

// ---------------------------------------------------------------------------
// WKV scan v7 = R10 v5 geometry + XCD-local ordering + all-DPP reduce.
//  - 8 chunks x 128 thr (8 rows/chunk-wavehalf... i = chunk*8 + tid>>3? no:
//    chunk*8 rows would give 8 rows; we keep v5: 256 blocks, 128 thr,
//    i = chunk*8 + (tid>>3) covers rows [chunk*8, chunk*8+16)?  -- v5 used
//    blk=bh*8+chunk, i=chunk*8+(tid>>3) with tid<128 -> tid>>3 in [0,16):
//    16 rows per chunk x 8 chunks = 128 rows?? No: 64 rows total, chunk
//    covers 8 rows... v5 actual: 256 blocks = 32bh x 8chunk, 128thr,
//    tid>>3 in [0,16) -> i = chunk*8 + [0,16) OVERLAPS. Recheck R9 code:
//    i = chunk*8 + (tid>>3) with 64-thr blocks (tid>>3 in [0,8)) -> v5 was
//    64-thr/256-block in R9. R10 kept it. So v7: 64 thr, 256 blocks,
//    blk = chunk*32 + bh (XCD-local), i = chunk*8 + (tid>>3), q = tid&7.
//  - reduces via red8_dpp (3 DPP, no shfl): R11 showed shfl ~35cyc each.
//  - vmcnt(33) counted wait (3 newer 11-load sets), 4-deep pipeline.
// ---------------------------------------------------------------------------
struct Ops { f4 a0, a1, d0, d1, k0, k1, b0, b1, r0, r1; float vi; };

static __device__ __forceinline__ void load_set(
    Ops& s, const float* pa, const float* pd, const float* pk,
    const float* pb, const float* pr, const float* pv)
{
    asm volatile(
        "global_load_dwordx4 %0, %11, off\n\t"
        "global_load_dwordx4 %1, %11, off offset:16\n\t"
        "global_load_dword   %10, %16, off\n\t"
        "global_load_dwordx4 %2, %12, off\n\t"
        "global_load_dwordx4 %3, %12, off offset:16\n\t"
        "global_load_dwordx4 %4, %13, off\n\t"
        "global_load_dwordx4 %5, %13, off offset:16\n\t"
        "global_load_dwordx4 %6, %14, off\n\t"
        "global_load_dwordx4 %7, %14, off offset:16\n\t"
        "global_load_dwordx4 %8, %15, off\n\t"
        "global_load_dwordx4 %9, %15, off offset:16"
        : "=&v"(s.a0), "=&v"(s.a1), "=&v"(s.d0), "=&v"(s.d1),
          "=&v"(s.k0), "=&v"(s.k1), "=&v"(s.b0), "=&v"(s.b1),
          "=&v"(s.r0), "=&v"(s.r1), "=&v"(s.vi)
        : "v"(pa), "v"(pd), "v"(pk), "v"(pb), "v"(pr), "v"(pv));
}

static __device__ __forceinline__ void wkv_wait33() {
    asm volatile("s_waitcnt vmcnt(33)" ::: "memory");
    __builtin_amdgcn_sched_barrier(0);
}

static __device__ __forceinline__ void wkv_compute(
    float S[8], const Ops& o, float* po, int q)
{
    float s0 = 0.f, s1 = 0.f, s2 = 0.f, s3 = 0.f;
    s0 = fmaf(S[0], o.a0.x, s0); s1 = fmaf(S[1], o.a0.y, s1);
    s2 = fmaf(S[2], o.a0.z, s2); s3 = fmaf(S[3], o.a0.w, s3);
    s0 = fmaf(S[4], o.a1.x, s0); s1 = fmaf(S[5], o.a1.y, s1);
    s2 = fmaf(S[6], o.a1.z, s2); s3 = fmaf(S[7], o.a1.w, s3);
    float sp = red8_dpp((s0 + s1) + (s2 + s3));

    S[0] = fmaf(S[0], o.d0.x, fmaf(sp, o.b0.x, o.vi * o.k0.x));
    S[1] = fmaf(S[1], o.d0.y, fmaf(sp, o.b0.y, o.vi * o.k0.y));
    S[2] = fmaf(S[2], o.d0.z, fmaf(sp, o.b0.z, o.vi * o.k0.z));
    S[3] = fmaf(S[3], o.d0.w, fmaf(sp, o.b0.w, o.vi * o.k0.w));
    S[4] = fmaf(S[4], o.d1.x, fmaf(sp, o.b1.x, o.vi * o.k1.x));
    S[5] = fmaf(S[5], o.d1.y, fmaf(sp, o.b1.y, o.vi * o.k1.y));
    S[6] = fmaf(S[6], o.d1.z, fmaf(sp, o.b1.z, o.vi * o.k1.z));
    S[7] = fmaf(S[7], o.d1.w, fmaf(sp, o.b1.w, o.vi * o.k1.w));

    float o0 = S[0] * o.r0.x, o1 = S[1] * o.r0.y;
    float o2 = S[2] * o.r0.z, o3 = S[3] * o.r0.w;
    o0 = fmaf(S[4], o.r1.x, o0); o1 = fmaf(S[5], o.r1.y, o1);
    o2 = fmaf(S[6], o.r1.z, o2); o3 = fmaf(S[7], o.r1.w, o3);
    float op = red8_dpp((o0 + o1) + (o2 + o3));
    if (q == 0) *po = op;
}

__global__ __launch_bounds__(64, 1) void wkv_kernel(
    const float* __restrict__ rt, const float* __restrict__ decay,
    const float* __restrict__ kt, const float* __restrict__ vt,
    const float* __restrict__ aarr, const float* __restrict__ barr,
    float* __restrict__ wkvt)
{
    int tid = threadIdx.x;
    int blk = blockIdx.x;              // 256 blocks: chunk*32 + bh (XCD-local)
    int chunk = blk >> 5, bh = blk & 31;
    int b = bh >> 4, h = bh & 15;
    int i = chunk * 8 + (tid >> 3);    // state row owned by this 8-lane group
    int q = tid & 7;                   // column-slice owner (8 cols)
    int jb = q * 8;
    size_t base = ((size_t)b * Tdim) * Cdim + (size_t)h * Ndim;
    const float* pa = aarr + base + jb;
    const float* pd = decay + base + jb;
    const float* pk = kt + base + jb;
    const float* pb = barr + base + jb;
    const float* pr = rt + base + jb;
    const float* pv = vt + base + i;
    float* po = wkvt + base + i;

    float S[8];
    #pragma unroll
    for (int j = 0; j < 8; ++j) S[j] = 0.f;

    Ops A, B, C, D;
    load_set(A, pa, pd, pk, pb, pr, pv);
    {
        size_t o1 = (size_t)1 * Cdim, o2 = (size_t)2 * Cdim, o3 = (size_t)3 * Cdim;
        load_set(B, pa + o1, pd + o1, pk + o1, pb + o1, pr + o1, pv + o1);
        load_set(C, pa + o2, pd + o2, pk + o2, pb + o2, pr + o2, pv + o2);
        load_set(D, pa + o3, pd + o3, pk + o3, pb + o3, pr + o3, pv + o3);
    }

    for (int t = 0; t < Tdim; t += 4) {
        wkv_wait33();
        wkv_compute(S, A, po + (size_t)t * Cdim, q);
        size_t o4 = (size_t)((t + 4 < Tdim) ? t + 4 : Tdim - 1) * Cdim;
        load_set(A, pa + o4, pd + o4, pk + o4, pb + o4, pr + o4, pv + o4);

        wkv_wait33();
        wkv_compute(S, B, po + (size_t)(t + 1) * Cdim, q);
        size_t o5 = (size_t)((t + 5 < Tdim) ? t + 5 : Tdim - 1) * Cdim;
        load_set(B, pa + o5, pd + o5, pk + o5, pb + o5, pr + o5, pv + o5);

        wkv_wait33();
        wkv_compute(S, C, po + (size_t)(t + 2) * Cdim, q);
        size_t o6 = (size_t)((t + 6 < Tdim) ? t + 6 : Tdim - 1) * Cdim;
        load_set(C, pa + o6, pd + o6, pk + o6, pb + o6, pr + o6, pv + o6);

        wkv_wait33();
        wkv_compute(S, D, po + (size_t)(t + 3) * Cdim, q);
        size_t o7 = (size_t)((t + 7 < Tdim) ? t + 7 : Tdim - 1) * Cdim;
        load_set(D, pa + o7, pd + o7, pk + o7, pb + o7, pr + o7, pv + o7);
    }
}

// ---------------------------------------------------------------------------
// E2: pt = GroupNorm(rt*wkvt)*ln_g + ln_b + ut; g16 = bf16(gt*pt)
// ---------------------------------------------------------------------------
__global__ __launch_bounds__(256) void e2_kernel(
    const float* __restrict__ rt, const float* __restrict__ wkvt,
    const float* __restrict__ ut, const __hip_bfloat16* __restrict__ gt16,
    const float* __restrict__ ln_g, const float* __restrict__ ln_b,
    __hip_bfloat16* __restrict__ g16)
{
    int gid = blockIdx.x * 4 + (threadIdx.x >> 6);
    int lane = threadIdx.x & 63;
    int h = gid % Hdim;
    size_t idx = (size_t)gid * 64 + lane;
    int c = h * 64 + lane;
    float x = rt[idx] * wkvt[idx];
    float mu = wsum64(x) * (1.f / 64.f);
    float d = x - mu;
    float var = wsum64(d * d) * (1.f / 64.f);
    float xn = d / sqrtf(var + EPS_GN);
    float pt = xn * ln_g[c] + ln_b[c] + ut[idx];
    float res = __bfloat162float(gt16[idx]) * pt;
    g16[idx] = __float2bfloat16(res);
}

// ---------------------------------------------------------------------------
extern "C" void kernel_launch(void* const* d_in, const int* in_sizes, int n_in,
                              void* d_out, int out_size, void* d_ws, size_t ws_size,
                              hipStream_t stream)
{
    (void)in_sizes; (void)n_in; (void)out_size; (void)ws_size;
    const float* xt      = (const float*)d_in[0];
    const float* v_first = (const float*)d_in[1];
    const float* tmix_r  = (const float*)d_in[2];
    const float* tmix_w  = (const float*)d_in[3];
    const float* tmix_k  = (const float*)d_in[4];
    const float* tmix_v  = (const float*)d_in[5];
    const float* tmix_a  = (const float*)d_in[6];
    const float* tmix_g  = (const float*)d_in[7];
    const float* w1 = (const float*)d_in[8];
    const float* w2 = (const float*)d_in[9];
    const float* w0 = (const float*)d_in[10];
    const float* a1 = (const float*)d_in[11];
    const float* a2 = (const float*)d_in[12];
    const float* a0 = (const float*)d_in[13];
    const float* v1 = (const float*)d_in[14];
    const float* v2 = (const float*)d_in[15];
    const float* v0 = (const float*)d_in[16];
    const float* g1 = (const float*)d_in[17];
    const float* g2 = (const float*)d_in[18];
    const float* k_k = (const float*)d_in[19];
    const float* k_a = (const float*)d_in[20];
    const float* r_k = (const float*)d_in[21];
    const float* W_r = (const float*)d_in[22];
    const float* W_k = (const float*)d_in[23];
    const float* W_v = (const float*)d_in[24];
    const float* W_o = (const float*)d_in[25];
    const float* ln_g = (const float*)d_in[26];
    const float* ln_b = (const float*)d_in[27];

    float* out = (float*)d_out;
    const size_t BTC = (size_t)Bdim * Tdim * Cdim;   // 2,097,152
    const int M = Bdim * Tdim;                        // 2048

    float* ws = (float*)d_ws;
    float* rt    = ws + 0 * BTC;
    float* kt    = ws + 1 * BTC;
    float* vraw  = ws + 2 * BTC;
    float* vt    = ws + 3 * BTC;
    float* decay = ws + 4 * BTC;
    float* aarr  = ws + 5 * BTC;
    float* barr  = ws + 6 * BTC;
    float* ut    = ws + 7 * BTC;
    float* wkv   = ws + 8 * BTC;
    __hip_bfloat16* bfa = (__hip_bfloat16*)(ws + 9 * BTC);
    __hip_bfloat16* at16 = bfa + 0 * BTC;
    __hip_bfloat16* gt16 = bfa + 1 * BTC;
    __hip_bfloat16* xr16 = bfa + 2 * BTC;
    __hip_bfloat16* xk16 = bfa + 3 * BTC;
    __hip_bfloat16* xv16 = bfa + 4 * BTC;   // reused as g16 after gemm3
    __hip_bfloat16* Wb   = bfa + 5 * BTC;   // 4*CCdim = 2*BTC bf16
    // Aliased scratch (dead before their slots' writers run):
    __hip_bfloat16* Aall = (__hip_bfloat16*)decay;           // 8MB (decay written later by gemm_lr2)
    __hip_bfloat16* Wlr1 = (__hip_bfloat16*)aarr;            // (aarr written later by e1)
    __hip_bfloat16* Wl2  = Wlr1 + (size_t)384 * 2048;
    __hip_bfloat16* hcat = Wl2 + (size_t)4096 * 288;
    __hip_bfloat16* g16 = xv16;

    // weight prep: big W -> bf16, Wlr1, Wl2 (one dispatch, 3 segments)
    prep_weights<<<6528, 256, 0, stream>>>(
        W_r, W_k, W_v, W_o, w1, a1, v1, g1, w2, a2, v2, g2,
        tmix_w, tmix_a, tmix_v, tmix_g, Wb, Wlr1, Wl2);

    // activation prep: 3 lerps -> bf16, Aall = [x | xprev] bf16
    prep_all<<<1024, 256, 0, stream>>>(xt, tmix_r, tmix_k, tmix_v,
                                       xr16, xk16, xv16, Aall);

    // low-rank chain as 2 MFMA GEMMs
    gemm_lr1<<<dim3(3, 16), 256, 0, stream>>>(Aall, Wlr1, hcat);
    gemm_lr2<<<dim3(32, 16), 256, 0, stream>>>(hcat, Wl2, w0, a0, v0,
                                               decay, at16, vt, gt16);

    // 3 big projections in one dispatch (384 blocks, full chip)
    dim3 gg3(Cdim / 128, M / 128, 3);
    gemm3_mfma<<<gg3, 256, 0, stream>>>(xr16, xk16, xv16, Wb, rt, kt, vraw);

    // E1
    e1_kernel<<<(Bdim * Tdim * Hdim) / 4, 256, 0, stream>>>(
        kt, at16, rt, vraw, vt, v_first, k_k, k_a, r_k,
        aarr, barr, ut, out + BTC);

    // WKV scan (8-way split, XCD-local order, all-DPP reduce, 4-deep pipeline)
    wkv_kernel<<<256, 64, 0, stream>>>(rt, decay, kt, vt, aarr, barr, wkv);

    // E2 (writes bf16 gated output)
    e2_kernel<<<(Bdim * Tdim * Hdim) / 4, 256, 0, stream>>>(
        rt, wkv, ut, gt16, ln_g, ln_b, g16);

    // output projection (bf16 MFMA)
    dim3 gg(Cdim / 128, M / 128);
    gemm_mfma<<<gg, 256, 0, stream>>>(g16, Wb + 3 * (size_t)CCdim, out, M, Cdim, Cdim);
}

// Round 13
// 332.959 us; speedup vs baseline: 1.2774x; 1.0524x over previous
//
#include <hip/hip_runtime.h>
#include <hip/hip_bf16.h>
#include <math.h>

#define Bdim 2
#define Tdim 1024
#define Cdim 1024
#define Hdim 16
#define Ndim 64
#define CCdim (Cdim * Cdim)
#define EPS_GN 0.00064f

typedef __bf16 bf8_t __attribute__((ext_vector_type(8)));
typedef float f32x4 __attribute__((ext_vector_type(4)));
typedef float f4 __attribute__((ext_vector_type(4)));

static __device__ __forceinline__ float sigf(float x) { return 1.f / (1.f + expf(-x)); }

static __device__ __forceinline__ float wsum64(float v) {
    #pragma unroll
    for (int m = 1; m < 64; m <<= 1) v += __shfl_xor(v, m);
    return v;
}

static __device__ __forceinline__ void gload_lds16(const void* g, void* l) {
    __builtin_amdgcn_global_load_lds(
        (const __attribute__((address_space(1))) void*)g,
        (__attribute__((address_space(3))) void*)l, 16, 0, 0);
}

// 16-lane sum, ALL-DPP: quad_perm xor1 (0xB1), xor2 (0x4E),
// row_half_mirror (0x141: 8-lane), row_mirror (0x140: 16-lane).
// R11/R12 lesson: shfl_xor ~35cyc (LDS pipe); DPP ~5-8cyc.
static __device__ __forceinline__ float red16_dpp(float x) {
    int s1 = __builtin_amdgcn_update_dpp(0, __builtin_bit_cast(int, x),
                                         0xB1, 0xF, 0xF, true);
    float y = x + __builtin_bit_cast(float, s1);
    int s2 = __builtin_amdgcn_update_dpp(0, __builtin_bit_cast(int, y),
                                         0x4E, 0xF, 0xF, true);
    float z = y + __builtin_bit_cast(float, s2);
    int s3 = __builtin_amdgcn_update_dpp(0, __builtin_bit_cast(int, z),
                                         0x141, 0xF, 0xF, true);
    float w = z + __builtin_bit_cast(float, s3);
    int s4 = __builtin_amdgcn_update_dpp(0, __builtin_bit_cast(int, w),
                                         0x140, 0xF, 0xF, true);
    return w + __builtin_bit_cast(float, s4);
}

// ---------------------------------------------------------------------------
// prep_weights: 3 segments in one dispatch (unchanged).
// ---------------------------------------------------------------------------
__global__ __launch_bounds__(256) void prep_weights(
    const float* __restrict__ W0, const float* __restrict__ W1,
    const float* __restrict__ W2, const float* __restrict__ W3,
    const float* __restrict__ w1, const float* __restrict__ a1,
    const float* __restrict__ v1, const float* __restrict__ g1,
    const float* __restrict__ w2, const float* __restrict__ a2,
    const float* __restrict__ v2, const float* __restrict__ g2,
    const float* __restrict__ mw, const float* __restrict__ ma,
    const float* __restrict__ mv, const float* __restrict__ mg,
    __hip_bfloat16* __restrict__ Wb, __hip_bfloat16* __restrict__ Wlr1,
    __hip_bfloat16* __restrict__ Wl2)
{
    int blk = blockIdx.x;
    int tid = threadIdx.x;
    if (blk < 2048) {
        int which = blk >> 9;
        const float* src = (which == 0) ? W0 : (which == 1) ? W1 : (which == 2) ? W2 : W3;
        size_t e8 = ((size_t)(blk & 511) * 256 + tid) * 8;
        float c[8];
        *(float4*)&c[0] = ((const float4*)(src + e8))[0];
        *(float4*)&c[4] = ((const float4*)(src + e8))[1];
        __hip_bfloat16 o[8];
        #pragma unroll
        for (int j = 0; j < 8; ++j) o[j] = __float2bfloat16(c[j]);
        __hip_bfloat16* dst = Wb + (size_t)which * CCdim + e8;
        ((ushort4*)dst)[0] = *(ushort4*)&o[0];
        ((ushort4*)dst)[1] = *(ushort4*)&o[4];
    } else if (blk < 2432) {
        int n = blk - 2048;                 // 0..383
        if (n < 288) {
            const float* M1; const float* mix; int D, nl;
            if (n < 64)       { M1 = w1; mix = mw; D = 64;  nl = n; }
            else if (n < 128) { M1 = a1; mix = ma; D = 64;  nl = n - 64; }
            else if (n < 160) { M1 = v1; mix = mv; D = 32;  nl = n - 128; }
            else              { M1 = g1; mix = mg; D = 128; nl = n - 160; }
            #pragma unroll
            for (int i = 0; i < 8; ++i) {
                int kp = tid + i * 256;     // 0..2047
                int k = kp & 1023, half = kp >> 10;
                float mx = mix[k];
                float val = M1[(size_t)k * D + nl] * (half ? mx : 1.f - mx);
                Wlr1[(size_t)n * 2048 + kp] = __float2bfloat16(val);
            }
        } else {
            #pragma unroll
            for (int i = 0; i < 8; ++i)
                Wlr1[(size_t)n * 2048 + tid + i * 256] = __float2bfloat16(0.f);
        }
    } else {
        int np = blk - 2432;                // 0..4095
        int path = np >> 10, nl = np & 1023;
        const float* M2; int off, D;
        if (path == 0)      { M2 = w2; off = 0;   D = 64; }
        else if (path == 1) { M2 = a2; off = 64;  D = 64; }
        else if (path == 2) { M2 = v2; off = 128; D = 32; }
        else                { M2 = g2; off = 160; D = 128; }
        for (int kp = tid; kp < 288; kp += 256) {
            int kl = kp - off;
            float val = (kl >= 0 && kl < D) ? M2[(size_t)kl * Cdim + nl] : 0.f;
            Wl2[(size_t)np * 288 + kp] = __float2bfloat16(val);
        }
    }
}

// ---------------------------------------------------------------------------
// prep_all: token-shift lerps (r,k,v) -> bf16 + Aall = [x | xprev] bf16.
// ---------------------------------------------------------------------------
__global__ __launch_bounds__(256) void prep_all(
    const float* __restrict__ xt,
    const float* __restrict__ mr, const float* __restrict__ mk, const float* __restrict__ mv,
    __hip_bfloat16* __restrict__ xr16, __hip_bfloat16* __restrict__ xk16,
    __hip_bfloat16* __restrict__ xv16, __hip_bfloat16* __restrict__ Aall)
{
    int idx8 = blockIdx.x * 256 + threadIdx.x;   // 0..262143
    int m = idx8 >> 7;
    int c8 = (idx8 & 127) * 8;
    int t = m & (Tdim - 1);
    const float* p = xt + (size_t)idx8 * 8;
    float cur[8], prv[8];
    *(float4*)&cur[0] = ((const float4*)p)[0];
    *(float4*)&cur[4] = ((const float4*)p)[1];
    if (t > 0) {
        *(float4*)&prv[0] = ((const float4*)(p - Cdim))[0];
        *(float4*)&prv[4] = ((const float4*)(p - Cdim))[1];
    } else {
        #pragma unroll
        for (int j = 0; j < 8; ++j) prv[j] = 0.f;
    }
    float mx[8];
    __hip_bfloat16 o[8];
    size_t ob = (size_t)idx8 * 8;

    *(float4*)&mx[0] = *(const float4*)(mr + c8);
    *(float4*)&mx[4] = *(const float4*)(mr + c8 + 4);
    #pragma unroll
    for (int j = 0; j < 8; ++j) o[j] = __float2bfloat16(cur[j] + (prv[j] - cur[j]) * mx[j]);
    ((ushort4*)(xr16 + ob))[0] = *(ushort4*)&o[0];
    ((ushort4*)(xr16 + ob))[1] = *(ushort4*)&o[4];

    *(float4*)&mx[0] = *(const float4*)(mk + c8);
    *(float4*)&mx[4] = *(const float4*)(mk + c8 + 4);
    #pragma unroll
    for (int j = 0; j < 8; ++j) o[j] = __float2bfloat16(cur[j] + (prv[j] - cur[j]) * mx[j]);
    ((ushort4*)(xk16 + ob))[0] = *(ushort4*)&o[0];
    ((ushort4*)(xk16 + ob))[1] = *(ushort4*)&o[4];

    *(float4*)&mx[0] = *(const float4*)(mv + c8);
    *(float4*)&mx[4] = *(const float4*)(mv + c8 + 4);
    #pragma unroll
    for (int j = 0; j < 8; ++j) o[j] = __float2bfloat16(cur[j] + (prv[j] - cur[j]) * mx[j]);
    ((ushort4*)(xv16 + ob))[0] = *(ushort4*)&o[0];
    ((ushort4*)(xv16 + ob))[1] = *(ushort4*)&o[4];

    size_t ab = (size_t)m * 2048 + c8;
    #pragma unroll
    for (int j = 0; j < 8; ++j) o[j] = __float2bfloat16(cur[j]);
    ((ushort4*)(Aall + ab))[0] = *(ushort4*)&o[0];
    ((ushort4*)(Aall + ab))[1] = *(ushort4*)&o[4];
    #pragma unroll
    for (int j = 0; j < 8; ++j) o[j] = __float2bfloat16(prv[j]);
    ((ushort4*)(Aall + ab + 1024))[0] = *(ushort4*)&o[0];
    ((ushort4*)(Aall + ab + 1024))[1] = *(ushort4*)&o[4];
}

// ---------------------------------------------------------------------------
// Triple bf16 MFMA GEMM (z = 0,1,2 selects A/W/C): 128x128 tile, BK=32.
// ---------------------------------------------------------------------------
__global__ __launch_bounds__(256) void gemm3_mfma(
    const __hip_bfloat16* __restrict__ A0, const __hip_bfloat16* __restrict__ A1,
    const __hip_bfloat16* __restrict__ A2, const __hip_bfloat16* __restrict__ Wbase,
    float* __restrict__ C0, float* __restrict__ C1, float* __restrict__ C2)
{
    const int N = Cdim, K = Cdim;
    __shared__ unsigned short At[128][32];
    __shared__ unsigned short Bt[128][32];
    int z = blockIdx.z;
    const __hip_bfloat16* A = (z == 0) ? A0 : (z == 1) ? A1 : A2;
    const __hip_bfloat16* Bw = Wbase + (size_t)z * CCdim;
    float* Cout = (z == 0) ? C0 : (z == 1) ? C1 : C2;
    int tid = threadIdx.x;
    int lane = tid & 63, wv = tid >> 6;
    int bm = blockIdx.y * 128, bn = blockIdx.x * 128;
    int wr = wv >> 1, wc = wv & 1;

    f32x4 acc[4][4];
    #pragma unroll
    for (int mi = 0; mi < 4; ++mi)
        #pragma unroll
        for (int ni = 0; ni < 4; ++ni)
            acc[mi][ni] = (f32x4){0.f, 0.f, 0.f, 0.f};

    int srow = wv * 16 + (lane >> 2);
    int scol = (lane & 3) * 8;
    const __hip_bfloat16* pa0 = A + (size_t)(bm + srow) * K + scol;
    const __hip_bfloat16* pa1 = A + (size_t)(bm + 64 + srow) * K + scol;
    const __hip_bfloat16* pb0 = Bw + (size_t)(bn + srow) * K + scol;
    const __hip_bfloat16* pb1 = Bw + (size_t)(bn + 64 + srow) * K + scol;
    char* At_b = (char*)&At[0][0] + wv * 1024;
    char* Bt_b = (char*)&Bt[0][0] + wv * 1024;

    for (int k0 = 0; k0 < K; k0 += 32) {
        gload_lds16(pa0 + k0, At_b);
        gload_lds16(pa1 + k0, At_b + 4096);
        gload_lds16(pb0 + k0, Bt_b);
        gload_lds16(pb1 + k0, Bt_b + 4096);
        __syncthreads();

        bf8_t af[4], bfr[4];
        #pragma unroll
        for (int mi = 0; mi < 4; ++mi)
            af[mi] = *(const bf8_t*)((const char*)&At[0][0] +
                     (wr * 64 + mi * 16 + (lane & 15)) * 64 + (lane >> 4) * 16);
        #pragma unroll
        for (int ni = 0; ni < 4; ++ni)
            bfr[ni] = *(const bf8_t*)((const char*)&Bt[0][0] +
                     (wc * 64 + ni * 16 + (lane & 15)) * 64 + (lane >> 4) * 16);
        #pragma unroll
        for (int mi = 0; mi < 4; ++mi)
            #pragma unroll
            for (int ni = 0; ni < 4; ++ni)
                acc[mi][ni] = __builtin_amdgcn_mfma_f32_16x16x32_bf16(
                    af[mi], bfr[ni], acc[mi][ni], 0, 0, 0);
        __syncthreads();
    }

    #pragma unroll
    for (int mi = 0; mi < 4; ++mi) {
        int r0 = bm + wr * 64 + mi * 16 + (lane >> 4) * 4;
        #pragma unroll
        for (int ni = 0; ni < 4; ++ni) {
            int c0 = bn + wc * 64 + ni * 16 + (lane & 15);
            #pragma unroll
            for (int j = 0; j < 4; ++j)
                Cout[(size_t)(r0 + j) * N + c0] = acc[mi][ni][j];
        }
    }
}

// ---------------------------------------------------------------------------
// Single bf16 MFMA GEMM (output projection).
// ---------------------------------------------------------------------------
__global__ __launch_bounds__(256) void gemm_mfma(
    const __hip_bfloat16* __restrict__ A, const __hip_bfloat16* __restrict__ Bw,
    float* __restrict__ Cout, int M, int N, int K)
{
    __shared__ unsigned short At[128][32];
    __shared__ unsigned short Bt[128][32];
    int tid = threadIdx.x;
    int lane = tid & 63, wv = tid >> 6;
    int bm = blockIdx.y * 128, bn = blockIdx.x * 128;
    int wr = wv >> 1, wc = wv & 1;

    f32x4 acc[4][4];
    #pragma unroll
    for (int mi = 0; mi < 4; ++mi)
        #pragma unroll
        for (int ni = 0; ni < 4; ++ni)
            acc[mi][ni] = (f32x4){0.f, 0.f, 0.f, 0.f};

    int srow = wv * 16 + (lane >> 2);
    int scol = (lane & 3) * 8;
    const __hip_bfloat16* pa0 = A + (size_t)(bm + srow) * K + scol;
    const __hip_bfloat16* pa1 = A + (size_t)(bm + 64 + srow) * K + scol;
    const __hip_bfloat16* pb0 = Bw + (size_t)(bn + srow) * K + scol;
    const __hip_bfloat16* pb1 = Bw + (size_t)(bn + 64 + srow) * K + scol;
    char* At_b = (char*)&At[0][0] + wv * 1024;
    char* Bt_b = (char*)&Bt[0][0] + wv * 1024;

    for (int k0 = 0; k0 < K; k0 += 32) {
        gload_lds16(pa0 + k0, At_b);
        gload_lds16(pa1 + k0, At_b + 4096);
        gload_lds16(pb0 + k0, Bt_b);
        gload_lds16(pb1 + k0, Bt_b + 4096);
        __syncthreads();

        bf8_t af[4], bfr[4];
        #pragma unroll
        for (int mi = 0; mi < 4; ++mi)
            af[mi] = *(const bf8_t*)((const char*)&At[0][0] +
                     (wr * 64 + mi * 16 + (lane & 15)) * 64 + (lane >> 4) * 16);
        #pragma unroll
        for (int ni = 0; ni < 4; ++ni)
            bfr[ni] = *(const bf8_t*)((const char*)&Bt[0][0] +
                     (wc * 64 + ni * 16 + (lane & 15)) * 64 + (lane >> 4) * 16);
        #pragma unroll
        for (int mi = 0; mi < 4; ++mi)
            #pragma unroll
            for (int ni = 0; ni < 4; ++ni)
                acc[mi][ni] = __builtin_amdgcn_mfma_f32_16x16x32_bf16(
                    af[mi], bfr[ni], acc[mi][ni], 0, 0, 0);
        __syncthreads();
    }

    #pragma unroll
    for (int mi = 0; mi < 4; ++mi) {
        int r0 = bm + wr * 64 + mi * 16 + (lane >> 4) * 4;
        #pragma unroll
        for (int ni = 0; ni < 4; ++ni) {
            int c0 = bn + wc * 64 + ni * 16 + (lane & 15);
            #pragma unroll
            for (int j = 0; j < 4; ++j)
                Cout[(size_t)(r0 + j) * N + c0] = acc[mi][ni][j];
        }
    }
}

// ---------------------------------------------------------------------------
// gemm_lr1: H[2048][288] = Aall @ Wlr1^T, bf16 out, per-range activation.
// ---------------------------------------------------------------------------
__global__ __launch_bounds__(256) void gemm_lr1(
    const __hip_bfloat16* __restrict__ A, const __hip_bfloat16* __restrict__ W,
    __hip_bfloat16* __restrict__ H)
{
    const int K = 2048;
    __shared__ unsigned short At[128][32];
    __shared__ unsigned short Bt[128][32];
    int tid = threadIdx.x;
    int lane = tid & 63, wv = tid >> 6;
    int bm = blockIdx.y * 128, bn = blockIdx.x * 128;
    int wr = wv >> 1, wc = wv & 1;

    f32x4 acc[4][4];
    #pragma unroll
    for (int mi = 0; mi < 4; ++mi)
        #pragma unroll
        for (int ni = 0; ni < 4; ++ni)
            acc[mi][ni] = (f32x4){0.f, 0.f, 0.f, 0.f};

    int srow = wv * 16 + (lane >> 2);
    int scol = (lane & 3) * 8;
    const __hip_bfloat16* pa0 = A + (size_t)(bm + srow) * K + scol;
    const __hip_bfloat16* pa1 = A + (size_t)(bm + 64 + srow) * K + scol;
    const __hip_bfloat16* pb0 = W + (size_t)(bn + srow) * K + scol;
    const __hip_bfloat16* pb1 = W + (size_t)(bn + 64 + srow) * K + scol;
    char* At_b = (char*)&At[0][0] + wv * 1024;
    char* Bt_b = (char*)&Bt[0][0] + wv * 1024;

    for (int k0 = 0; k0 < K; k0 += 32) {
        gload_lds16(pa0 + k0, At_b);
        gload_lds16(pa1 + k0, At_b + 4096);
        gload_lds16(pb0 + k0, Bt_b);
        gload_lds16(pb1 + k0, Bt_b + 4096);
        __syncthreads();

        bf8_t af[4], bfr[4];
        #pragma unroll
        for (int mi = 0; mi < 4; ++mi)
            af[mi] = *(const bf8_t*)((const char*)&At[0][0] +
                     (wr * 64 + mi * 16 + (lane & 15)) * 64 + (lane >> 4) * 16);
        #pragma unroll
        for (int ni = 0; ni < 4; ++ni)
            bfr[ni] = *(const bf8_t*)((const char*)&Bt[0][0] +
                     (wc * 64 + ni * 16 + (lane & 15)) * 64 + (lane >> 4) * 16);
        #pragma unroll
        for (int mi = 0; mi < 4; ++mi)
            #pragma unroll
            for (int ni = 0; ni < 4; ++ni)
                acc[mi][ni] = __builtin_amdgcn_mfma_f32_16x16x32_bf16(
                    af[mi], bfr[ni], acc[mi][ni], 0, 0, 0);
        __syncthreads();
    }

    #pragma unroll
    for (int mi = 0; mi < 4; ++mi) {
        int r0 = bm + wr * 64 + mi * 16 + (lane >> 4) * 4;
        #pragma unroll
        for (int ni = 0; ni < 4; ++ni) {
            int c0 = bn + wc * 64 + ni * 16 + (lane & 15);
            if (c0 < 288) {
                #pragma unroll
                for (int j = 0; j < 4; ++j) {
                    float v = acc[mi][ni][j];
                    if (c0 < 64) v = tanhf(v);
                    else if (c0 >= 160) v = sigf(v);
                    H[(size_t)(r0 + j) * 288 + c0] = __float2bfloat16(v);
                }
            }
        }
    }
}

// ---------------------------------------------------------------------------
// gemm_lr2: block-diag expansion, epilogue demux (unchanged).
// ---------------------------------------------------------------------------
__global__ __launch_bounds__(256) void gemm_lr2(
    const __hip_bfloat16* __restrict__ H, const __hip_bfloat16* __restrict__ W,
    const float* __restrict__ w0, const float* __restrict__ a0,
    const float* __restrict__ v0,
    float* __restrict__ decay, __hip_bfloat16* __restrict__ at16,
    float* __restrict__ vt, __hip_bfloat16* __restrict__ gt16)
{
    const int K = 288;
    __shared__ unsigned short At[128][32];
    __shared__ unsigned short Bt[128][32];
    int tid = threadIdx.x;
    int lane = tid & 63, wv = tid >> 6;
    int bm = blockIdx.y * 128, bn = blockIdx.x * 128;
    int wr = wv >> 1, wc = wv & 1;

    f32x4 acc[4][4];
    #pragma unroll
    for (int mi = 0; mi < 4; ++mi)
        #pragma unroll
        for (int ni = 0; ni < 4; ++ni)
            acc[mi][ni] = (f32x4){0.f, 0.f, 0.f, 0.f};

    int srow = wv * 16 + (lane >> 2);
    int scol = (lane & 3) * 8;
    const __hip_bfloat16* pa0 = H + (size_t)(bm + srow) * K + scol;
    const __hip_bfloat16* pa1 = H + (size_t)(bm + 64 + srow) * K + scol;
    const __hip_bfloat16* pb0 = W + (size_t)(bn + srow) * K + scol;
    const __hip_bfloat16* pb1 = W + (size_t)(bn + 64 + srow) * K + scol;
    char* At_b = (char*)&At[0][0] + wv * 1024;
    char* Bt_b = (char*)&Bt[0][0] + wv * 1024;

    for (int k0 = 0; k0 < K; k0 += 32) {
        gload_lds16(pa0 + k0, At_b);
        gload_lds16(pa1 + k0, At_b + 4096);
        gload_lds16(pb0 + k0, Bt_b);
        gload_lds16(pb1 + k0, Bt_b + 4096);
        __syncthreads();

        bf8_t af[4], bfr[4];
        #pragma unroll
        for (int mi = 0; mi < 4; ++mi)
            af[mi] = *(const bf8_t*)((const char*)&At[0][0] +
                     (wr * 64 + mi * 16 + (lane & 15)) * 64 + (lane >> 4) * 16);
        #pragma unroll
        for (int ni = 0; ni < 4; ++ni)
            bfr[ni] = *(const bf8_t*)((const char*)&Bt[0][0] +
                     (wc * 64 + ni * 16 + (lane & 15)) * 64 + (lane >> 4) * 16);
        #pragma unroll
        for (int mi = 0; mi < 4; ++mi)
            #pragma unroll
            for (int ni = 0; ni < 4; ++ni)
                acc[mi][ni] = __builtin_amdgcn_mfma_f32_16x16x32_bf16(
                    af[mi], bfr[ni], acc[mi][ni], 0, 0, 0);
        __syncthreads();
    }

    #pragma unroll
    for (int mi = 0; mi < 4; ++mi) {
        int r0 = bm + wr * 64 + mi * 16 + (lane >> 4) * 4;
        #pragma unroll
        for (int ni = 0; ni < 4; ++ni) {
            int np = bn + wc * 64 + ni * 16 + (lane & 15);
            int path = np >> 10, nl = np & 1023;
            #pragma unroll
            for (int j = 0; j < 4; ++j) {
                float v = acc[mi][ni][j];
                size_t oi = (size_t)(r0 + j) * Cdim + nl;
                if (path == 0)      decay[oi] = sigf(v + w0[nl]) * 0.60653065971263342f;
                else if (path == 1) at16[oi] = __float2bfloat16(sigf(v + a0[nl]));
                else if (path == 2) vt[oi] = sigf(v + v0[nl]);
                else                gt16[oi] = __float2bfloat16(v);
            }
        }
    }
}

// ---------------------------------------------------------------------------
// E1: kk-normalize -> aarr=-kkn, barr=kkn*at; ut; v_first passthrough.
// ---------------------------------------------------------------------------
__global__ __launch_bounds__(256) void e1_kernel(
    const float* __restrict__ kt, const __hip_bfloat16* __restrict__ at16,
    const float* __restrict__ rt, const float* __restrict__ vraw,
    const float* __restrict__ vt, const float* __restrict__ vfirst,
    const float* __restrict__ k_k, const float* __restrict__ k_a,
    const float* __restrict__ r_k,
    float* __restrict__ aarr, float* __restrict__ barr,
    float* __restrict__ ut, float* __restrict__ out2)
{
    int gid = blockIdx.x * 4 + (threadIdx.x >> 6);
    int lane = threadIdx.x & 63;
    int h = gid % Hdim;
    size_t idx = (size_t)gid * 64 + lane;
    int c = h * 64 + lane;
    float ktv = kt[idx];
    float atv = __bfloat162float(at16[idx]);
    float kk = ktv * k_k[c];
    float ss = wsum64(kk * kk);
    float norm = sqrtf(ss);
    float kkn = kk / fmaxf(norm, 1e-12f);
    aarr[idx] = -kkn;
    barr[idx] = kkn * atv;
    float kmix = ktv * (1.f + (atv - 1.f) * k_a[c]);
    float rv = rt[idx];
    float dot = wsum64(rv * kmix * r_k[c]);
    float vm = vraw[idx];
    float vf = vfirst[idx];
    vm = vm + (vf - vm) * vt[idx];
    ut[idx] = dot * vm;
    out2[idx] = vf;
}

// ---------------------------------------------------------------------------
// WKV scan v8: 16-way row-split, 4 rows x 16 lanes/row, all-DPP 16-lane
// reduce, XCD-local ordering, 4-deep asm-batched reg pipeline.
//  - 512 blocks x 64 thr = 2 blocks/CU (2 waves on different SIMDs = TLP;
//    blocks c and c+256 share a bh -> L1 reuse of operand stream).
//  - blk = chunk*32 + bh: all 16 chunks of a bh on the SAME XCD (mod-8).
//  - per set: 5 dwordx4 + 1 dword = 6 VMEM instr; per-lane VALU ~23/step.
//  - red16_dpp: quad xor1/xor2 + half_mirror + row_mirror, zero shfl.
//  - vmcnt(18): prologue 24 outstanding -> retires exactly set 0;
//    steady 25 (3 sets + stores) -> retires oldest set + oldest store.
// ---------------------------------------------------------------------------
struct Ops { f4 a, d, k, b, r; float vi; };

static __device__ __forceinline__ void load_set(
    Ops& s, const float* pa, const float* pd, const float* pk,
    const float* pb, const float* pr, const float* pv)
{
    asm volatile(
        "global_load_dwordx4 %0, %6, off\n\t"
        "global_load_dword   %5, %11, off\n\t"
        "global_load_dwordx4 %1, %7, off\n\t"
        "global_load_dwordx4 %2, %8, off\n\t"
        "global_load_dwordx4 %3, %9, off\n\t"
        "global_load_dwordx4 %4, %10, off"
        : "=&v"(s.a), "=&v"(s.d), "=&v"(s.k), "=&v"(s.b), "=&v"(s.r), "=&v"(s.vi)
        : "v"(pa), "v"(pd), "v"(pk), "v"(pb), "v"(pr), "v"(pv));
}

static __device__ __forceinline__ void wkv_wait18() {
    asm volatile("s_waitcnt vmcnt(18)" ::: "memory");
    __builtin_amdgcn_sched_barrier(0);
}

static __device__ __forceinline__ void wkv_compute(
    float S[4], const Ops& o, float* po, int q)
{
    float s0 = S[0] * o.a.x, s1 = S[1] * o.a.y;
    float s2 = S[2] * o.a.z, s3 = S[3] * o.a.w;
    float sp = red16_dpp((s0 + s1) + (s2 + s3));

    S[0] = fmaf(S[0], o.d.x, fmaf(sp, o.b.x, o.vi * o.k.x));
    S[1] = fmaf(S[1], o.d.y, fmaf(sp, o.b.y, o.vi * o.k.y));
    S[2] = fmaf(S[2], o.d.z, fmaf(sp, o.b.z, o.vi * o.k.z));
    S[3] = fmaf(S[3], o.d.w, fmaf(sp, o.b.w, o.vi * o.k.w));

    float o0 = S[0] * o.r.x, o1 = S[1] * o.r.y;
    float o2 = S[2] * o.r.z, o3 = S[3] * o.r.w;
    float op = red16_dpp((o0 + o1) + (o2 + o3));
    if (q == 0) *po = op;
}

__global__ __launch_bounds__(64, 1) void wkv_kernel(
    const float* __restrict__ rt, const float* __restrict__ decay,
    const float* __restrict__ kt, const float* __restrict__ vt,
    const float* __restrict__ aarr, const float* __restrict__ barr,
    float* __restrict__ wkvt)
{
    int tid = threadIdx.x;
    int blk = blockIdx.x;              // 512 blocks: chunk*32 + bh (XCD-local)
    int chunk = blk >> 5, bh = blk & 31;
    int b = bh >> 4, h = bh & 15;
    int i = chunk * 4 + (tid >> 4);    // state row owned by this 16-lane group
    int q = tid & 15;                  // column-slice owner (4 cols)
    int jb = q * 4;
    size_t base = ((size_t)b * Tdim) * Cdim + (size_t)h * Ndim;
    const float* pa = aarr + base + jb;
    const float* pd = decay + base + jb;
    const float* pk = kt + base + jb;
    const float* pb = barr + base + jb;
    const float* pr = rt + base + jb;
    const float* pv = vt + base + i;
    float* po = wkvt + base + i;

    float S[4];
    #pragma unroll
    for (int j = 0; j < 4; ++j) S[j] = 0.f;

    Ops A, B, C, D;
    load_set(A, pa, pd, pk, pb, pr, pv);
    {
        size_t o1 = (size_t)1 * Cdim, o2 = (size_t)2 * Cdim, o3 = (size_t)3 * Cdim;
        load_set(B, pa + o1, pd + o1, pk + o1, pb + o1, pr + o1, pv + o1);
        load_set(C, pa + o2, pd + o2, pk + o2, pb + o2, pr + o2, pv + o2);
        load_set(D, pa + o3, pd + o3, pk + o3, pb + o3, pr + o3, pv + o3);
    }

    for (int t = 0; t < Tdim; t += 4) {
        wkv_wait18();
        wkv_compute(S, A, po + (size_t)t * Cdim, q);
        size_t o4 = (size_t)((t + 4 < Tdim) ? t + 4 : Tdim - 1) * Cdim;
        load_set(A, pa + o4, pd + o4, pk + o4, pb + o4, pr + o4, pv + o4);

        wkv_wait18();
        wkv_compute(S, B, po + (size_t)(t + 1) * Cdim, q);
        size_t o5 = (size_t)((t + 5 < Tdim) ? t + 5 : Tdim - 1) * Cdim;
        load_set(B, pa + o5, pd + o5, pk + o5, pb + o5, pr + o5, pv + o5);

        wkv_wait18();
        wkv_compute(S, C, po + (size_t)(t + 2) * Cdim, q);
        size_t o6 = (size_t)((t + 6 < Tdim) ? t + 6 : Tdim - 1) * Cdim;
        load_set(C, pa + o6, pd + o6, pk + o6, pb + o6, pr + o6, pv + o6);

        wkv_wait18();
        wkv_compute(S, D, po + (size_t)(t + 3) * Cdim, q);
        size_t o7 = (size_t)((t + 7 < Tdim) ? t + 7 : Tdim - 1) * Cdim;
        load_set(D, pa + o7, pd + o7, pk + o7, pb + o7, pr + o7, pv + o7);
    }
}

// ---------------------------------------------------------------------------
// E2: pt = GroupNorm(rt*wkvt)*ln_g + ln_b + ut; g16 = bf16(gt*pt)
// ---------------------------------------------------------------------------
__global__ __launch_bounds__(256) void e2_kernel(
    const float* __restrict__ rt, const float* __restrict__ wkvt,
    const float* __restrict__ ut, const __hip_bfloat16* __restrict__ gt16,
    const float* __restrict__ ln_g, const float* __restrict__ ln_b,
    __hip_bfloat16* __restrict__ g16)
{
    int gid = blockIdx.x * 4 + (threadIdx.x >> 6);
    int lane = threadIdx.x & 63;
    int h = gid % Hdim;
    size_t idx = (size_t)gid * 64 + lane;
    int c = h * 64 + lane;
    float x = rt[idx] * wkvt[idx];
    float mu = wsum64(x) * (1.f / 64.f);
    float d = x - mu;
    float var = wsum64(d * d) * (1.f / 64.f);
    float xn = d / sqrtf(var + EPS_GN);
    float pt = xn * ln_g[c] + ln_b[c] + ut[idx];
    float res = __bfloat162float(gt16[idx]) * pt;
    g16[idx] = __float2bfloat16(res);
}

// ---------------------------------------------------------------------------
extern "C" void kernel_launch(void* const* d_in, const int* in_sizes, int n_in,
                              void* d_out, int out_size, void* d_ws, size_t ws_size,
                              hipStream_t stream)
{
    (void)in_sizes; (void)n_in; (void)out_size; (void)ws_size;
    const float* xt      = (const float*)d_in[0];
    const float* v_first = (const float*)d_in[1];
    const float* tmix_r  = (const float*)d_in[2];
    const float* tmix_w  = (const float*)d_in[3];
    const float* tmix_k  = (const float*)d_in[4];
    const float* tmix_v  = (const float*)d_in[5];
    const float* tmix_a  = (const float*)d_in[6];
    const float* tmix_g  = (const float*)d_in[7];
    const float* w1 = (const float*)d_in[8];
    const float* w2 = (const float*)d_in[9];
    const float* w0 = (const float*)d_in[10];
    const float* a1 = (const float*)d_in[11];
    const float* a2 = (const float*)d_in[12];
    const float* a0 = (const float*)d_in[13];
    const float* v1 = (const float*)d_in[14];
    const float* v2 = (const float*)d_in[15];
    const float* v0 = (const float*)d_in[16];
    const float* g1 = (const float*)d_in[17];
    const float* g2 = (const float*)d_in[18];
    const float* k_k = (const float*)d_in[19];
    const float* k_a = (const float*)d_in[20];
    const float* r_k = (const float*)d_in[21];
    const float* W_r = (const float*)d_in[22];
    const float* W_k = (const float*)d_in[23];
    const float* W_v = (const float*)d_in[24];
    const float* W_o = (const float*)d_in[25];
    const float* ln_g = (const float*)d_in[26];
    const float* ln_b = (const float*)d_in[27];

    float* out = (float*)d_out;
    const size_t BTC = (size_t)Bdim * Tdim * Cdim;   // 2,097,152
    const int M = Bdim * Tdim;                        // 2048

    float* ws = (float*)d_ws;
    float* rt    = ws + 0 * BTC;
    float* kt    = ws + 1 * BTC;
    float* vraw  = ws + 2 * BTC;
    float* vt    = ws + 3 * BTC;
    float* decay = ws + 4 * BTC;
    float* aarr  = ws + 5 * BTC;
    float* barr  = ws + 6 * BTC;
    float* ut    = ws + 7 * BTC;
    float* wkv   = ws + 8 * BTC;
    __hip_bfloat16* bfa = (__hip_bfloat16*)(ws + 9 * BTC);
    __hip_bfloat16* at16 = bfa + 0 * BTC;
    __hip_bfloat16* gt16 = bfa + 1 * BTC;
    __hip_bfloat16* xr16 = bfa + 2 * BTC;
    __hip_bfloat16* xk16 = bfa + 3 * BTC;
    __hip_bfloat16* xv16 = bfa + 4 * BTC;   // reused as g16 after gemm3
    __hip_bfloat16* Wb   = bfa + 5 * BTC;   // 4*CCdim = 2*BTC bf16
    // Aliased scratch (dead before their slots' writers run):
    __hip_bfloat16* Aall = (__hip_bfloat16*)decay;           // 8MB (decay written later by gemm_lr2)
    __hip_bfloat16* Wlr1 = (__hip_bfloat16*)aarr;            // (aarr written later by e1)
    __hip_bfloat16* Wl2  = Wlr1 + (size_t)384 * 2048;
    __hip_bfloat16* hcat = Wl2 + (size_t)4096 * 288;
    __hip_bfloat16* g16 = xv16;

    // weight prep: big W -> bf16, Wlr1, Wl2 (one dispatch, 3 segments)
    prep_weights<<<6528, 256, 0, stream>>>(
        W_r, W_k, W_v, W_o, w1, a1, v1, g1, w2, a2, v2, g2,
        tmix_w, tmix_a, tmix_v, tmix_g, Wb, Wlr1, Wl2);

    // activation prep: 3 lerps -> bf16, Aall = [x | xprev] bf16
    prep_all<<<1024, 256, 0, stream>>>(xt, tmix_r, tmix_k, tmix_v,
                                       xr16, xk16, xv16, Aall);

    // low-rank chain as 2 MFMA GEMMs
    gemm_lr1<<<dim3(3, 16), 256, 0, stream>>>(Aall, Wlr1, hcat);
    gemm_lr2<<<dim3(32, 16), 256, 0, stream>>>(hcat, Wl2, w0, a0, v0,
                                               decay, at16, vt, gt16);

    // 3 big projections in one dispatch (384 blocks, full chip)
    dim3 gg3(Cdim / 128, M / 128, 3);
    gemm3_mfma<<<gg3, 256, 0, stream>>>(xr16, xk16, xv16, Wb, rt, kt, vraw);

    // E1
    e1_kernel<<<(Bdim * Tdim * Hdim) / 4, 256, 0, stream>>>(
        kt, at16, rt, vraw, vt, v_first, k_k, k_a, r_k,
        aarr, barr, ut, out + BTC);

    // WKV scan (16-way XCD-local split, all-DPP reduce, 4-deep pipeline)
    wkv_kernel<<<512, 64, 0, stream>>>(rt, decay, kt, vt, aarr, barr, wkv);

    // E2 (writes bf16 gated output)
    e2_kernel<<<(Bdim * Tdim * Hdim) / 4, 256, 0, stream>>>(
        rt, wkv, ut, gt16, ln_g, ln_b, g16);

    // output projection (bf16 MFMA)
    dim3 gg(Cdim / 128, M / 128);
    gemm_mfma<<<gg, 256, 0, stream>>>(g16, Wb + 3 * (size_t)CCdim, out, M, Cdim, Cdim);
}

// Round 14
// 308.709 us; speedup vs baseline: 1.3777x; 1.0786x over previous
//
#include <hip/hip_runtime.h>
#include <hip/hip_bf16.h>
#include <math.h>

#define Bdim 2
#define Tdim 1024
#define Cdim 1024
#define Hdim 16
#define Ndim 64
#define CCdim (Cdim * Cdim)
#define EPS_GN 0.00064f

typedef __bf16 bf8_t __attribute__((ext_vector_type(8)));
typedef float f32x4 __attribute__((ext_vector_type(4)));
typedef float f4 __attribute__((ext_vector_type(4)));

static __device__ __forceinline__ float sigf(float x) { return 1.f / (1.f + expf(-x)); }

static __device__ __forceinline__ float wsum64(float v) {
    #pragma unroll
    for (int m = 1; m < 64; m <<= 1) v += __shfl_xor(v, m);
    return v;
}

static __device__ __forceinline__ void gload_lds16(const void* g, void* l) {
    __builtin_amdgcn_global_load_lds(
        (const __attribute__((address_space(1))) void*)g,
        (__attribute__((address_space(3))) void*)l, 16, 0, 0);
}

// 16-lane sum, ALL-DPP: quad_perm xor1 (0xB1), xor2 (0x4E),
// row_half_mirror (0x141), row_mirror (0x140). shfl_xor ~35cyc; DPP ~5-8.
static __device__ __forceinline__ float red16_dpp(float x) {
    int s1 = __builtin_amdgcn_update_dpp(0, __builtin_bit_cast(int, x),
                                         0xB1, 0xF, 0xF, true);
    float y = x + __builtin_bit_cast(float, s1);
    int s2 = __builtin_amdgcn_update_dpp(0, __builtin_bit_cast(int, y),
                                         0x4E, 0xF, 0xF, true);
    float z = y + __builtin_bit_cast(float, s2);
    int s3 = __builtin_amdgcn_update_dpp(0, __builtin_bit_cast(int, z),
                                         0x141, 0xF, 0xF, true);
    float w = z + __builtin_bit_cast(float, s3);
    int s4 = __builtin_amdgcn_update_dpp(0, __builtin_bit_cast(int, w),
                                         0x140, 0xF, 0xF, true);
    return w + __builtin_bit_cast(float, s4);
}

// ---------------------------------------------------------------------------
// prep_fused: weights (blk<6528, 3 segments) + activations (blk>=6528).
// ---------------------------------------------------------------------------
__global__ __launch_bounds__(256) void prep_fused(
    const float* __restrict__ W0, const float* __restrict__ W1,
    const float* __restrict__ W2, const float* __restrict__ W3,
    const float* __restrict__ w1, const float* __restrict__ a1,
    const float* __restrict__ v1, const float* __restrict__ g1,
    const float* __restrict__ w2, const float* __restrict__ a2,
    const float* __restrict__ v2, const float* __restrict__ g2,
    const float* __restrict__ mw, const float* __restrict__ ma,
    const float* __restrict__ mv, const float* __restrict__ mg,
    const float* __restrict__ xt,
    const float* __restrict__ mr, const float* __restrict__ mk,
    __hip_bfloat16* __restrict__ Wb, __hip_bfloat16* __restrict__ Wlr1,
    __hip_bfloat16* __restrict__ Wl2,
    __hip_bfloat16* __restrict__ xr16, __hip_bfloat16* __restrict__ xk16,
    __hip_bfloat16* __restrict__ xv16, __hip_bfloat16* __restrict__ Aall)
{
    int blk = blockIdx.x;
    int tid = threadIdx.x;
    if (blk < 2048) {
        int which = blk >> 9;
        const float* src = (which == 0) ? W0 : (which == 1) ? W1 : (which == 2) ? W2 : W3;
        size_t e8 = ((size_t)(blk & 511) * 256 + tid) * 8;
        float c[8];
        *(float4*)&c[0] = ((const float4*)(src + e8))[0];
        *(float4*)&c[4] = ((const float4*)(src + e8))[1];
        __hip_bfloat16 o[8];
        #pragma unroll
        for (int j = 0; j < 8; ++j) o[j] = __float2bfloat16(c[j]);
        __hip_bfloat16* dst = Wb + (size_t)which * CCdim + e8;
        ((ushort4*)dst)[0] = *(ushort4*)&o[0];
        ((ushort4*)dst)[1] = *(ushort4*)&o[4];
    } else if (blk < 2432) {
        int n = blk - 2048;                 // 0..383
        if (n < 288) {
            const float* M1; const float* mix; int D, nl;
            if (n < 64)       { M1 = w1; mix = mw; D = 64;  nl = n; }
            else if (n < 128) { M1 = a1; mix = ma; D = 64;  nl = n - 64; }
            else if (n < 160) { M1 = v1; mix = mv; D = 32;  nl = n - 128; }
            else              { M1 = g1; mix = mg; D = 128; nl = n - 160; }
            #pragma unroll
            for (int i = 0; i < 8; ++i) {
                int kp = tid + i * 256;     // 0..2047
                int k = kp & 1023, half = kp >> 10;
                float mx = mix[k];
                float val = M1[(size_t)k * D + nl] * (half ? mx : 1.f - mx);
                Wlr1[(size_t)n * 2048 + kp] = __float2bfloat16(val);
            }
        } else {
            #pragma unroll
            for (int i = 0; i < 8; ++i)
                Wlr1[(size_t)n * 2048 + tid + i * 256] = __float2bfloat16(0.f);
        }
    } else if (blk < 6528) {
        int np = blk - 2432;                // 0..4095
        int path = np >> 10, nl = np & 1023;
        const float* M2; int off, D;
        if (path == 0)      { M2 = w2; off = 0;   D = 64; }
        else if (path == 1) { M2 = a2; off = 64;  D = 64; }
        else if (path == 2) { M2 = v2; off = 128; D = 32; }
        else                { M2 = g2; off = 160; D = 128; }
        for (int kp = tid; kp < 288; kp += 256) {
            int kl = kp - off;
            float val = (kl >= 0 && kl < D) ? M2[(size_t)kl * Cdim + nl] : 0.f;
            Wl2[(size_t)np * 288 + kp] = __float2bfloat16(val);
        }
    } else {
        // activation prep: lerps (r,k,v) -> bf16 + Aall = [x | xprev]
        int idx8 = (blk - 6528) * 256 + tid;     // 0..262143
        int m = idx8 >> 7;
        int c8 = (idx8 & 127) * 8;
        int t = m & (Tdim - 1);
        const float* p = xt + (size_t)idx8 * 8;
        float cur[8], prv[8];
        *(float4*)&cur[0] = ((const float4*)p)[0];
        *(float4*)&cur[4] = ((const float4*)p)[1];
        if (t > 0) {
            *(float4*)&prv[0] = ((const float4*)(p - Cdim))[0];
            *(float4*)&prv[4] = ((const float4*)(p - Cdim))[1];
        } else {
            #pragma unroll
            for (int j = 0; j < 8; ++j) prv[j] = 0.f;
        }
        float mx[8];
        __hip_bfloat16 o[8];
        size_t ob = (size_t)idx8 * 8;

        *(float4*)&mx[0] = *(const float4*)(mr + c8);
        *(float4*)&mx[4] = *(const float4*)(mr + c8 + 4);
        #pragma unroll
        for (int j = 0; j < 8; ++j) o[j] = __float2bfloat16(cur[j] + (prv[j] - cur[j]) * mx[j]);
        ((ushort4*)(xr16 + ob))[0] = *(ushort4*)&o[0];
        ((ushort4*)(xr16 + ob))[1] = *(ushort4*)&o[4];

        *(float4*)&mx[0] = *(const float4*)(mk + c8);
        *(float4*)&mx[4] = *(const float4*)(mk + c8 + 4);
        #pragma unroll
        for (int j = 0; j < 8; ++j) o[j] = __float2bfloat16(cur[j] + (prv[j] - cur[j]) * mx[j]);
        ((ushort4*)(xk16 + ob))[0] = *(ushort4*)&o[0];
        ((ushort4*)(xk16 + ob))[1] = *(ushort4*)&o[4];

        *(float4*)&mx[0] = *(const float4*)(mv + c8);
        *(float4*)&mx[4] = *(const float4*)(mv + c8 + 4);
        #pragma unroll
        for (int j = 0; j < 8; ++j) o[j] = __float2bfloat16(cur[j] + (prv[j] - cur[j]) * mx[j]);
        ((ushort4*)(xv16 + ob))[0] = *(ushort4*)&o[0];
        ((ushort4*)(xv16 + ob))[1] = *(ushort4*)&o[4];

        size_t ab = (size_t)m * 2048 + c8;
        #pragma unroll
        for (int j = 0; j < 8; ++j) o[j] = __float2bfloat16(cur[j]);
        ((ushort4*)(Aall + ab))[0] = *(ushort4*)&o[0];
        ((ushort4*)(Aall + ab))[1] = *(ushort4*)&o[4];
        #pragma unroll
        for (int j = 0; j < 8; ++j) o[j] = __float2bfloat16(prv[j]);
        ((ushort4*)(Aall + ab + 1024))[0] = *(ushort4*)&o[0];
        ((ushort4*)(Aall + ab + 1024))[1] = *(ushort4*)&o[4];
    }
}

// ---------------------------------------------------------------------------
// gemm_fused: z=0 -> lr1 (K=2048, N=384 real 288, bf16+act out, x<3 only;
// dispatched FIRST so its 2x-longer blocks don't straggle);
// z=1..3 -> the three C x C projections (K=1024, f32 out).
// ---------------------------------------------------------------------------
__global__ __launch_bounds__(256) void gemm_fused(
    const __hip_bfloat16* __restrict__ A0, const __hip_bfloat16* __restrict__ A1,
    const __hip_bfloat16* __restrict__ A2, const __hip_bfloat16* __restrict__ Aall,
    const __hip_bfloat16* __restrict__ Wbase, const __hip_bfloat16* __restrict__ Wlr1,
    float* __restrict__ C0, float* __restrict__ C1, float* __restrict__ C2,
    __hip_bfloat16* __restrict__ H)
{
    __shared__ unsigned short At[128][32];
    __shared__ unsigned short Bt[128][32];
    int z = blockIdx.z;
    const __hip_bfloat16* A; const __hip_bfloat16* Bw;
    float* Cout = nullptr;
    int K;
    if (z == 0) {
        if (blockIdx.x >= 3) return;   // N=384: 3 column tiles
        A = Aall; Bw = Wlr1; K = 2048;
    } else {
        int zi = z - 1;
        A = (zi == 0) ? A0 : (zi == 1) ? A1 : A2;
        Bw = Wbase + (size_t)zi * CCdim;
        Cout = (zi == 0) ? C0 : (zi == 1) ? C1 : C2;
        K = Cdim;
    }
    int tid = threadIdx.x;
    int lane = tid & 63, wv = tid >> 6;
    int bm = blockIdx.y * 128, bn = blockIdx.x * 128;
    int wr = wv >> 1, wc = wv & 1;

    f32x4 acc[4][4];
    #pragma unroll
    for (int mi = 0; mi < 4; ++mi)
        #pragma unroll
        for (int ni = 0; ni < 4; ++ni)
            acc[mi][ni] = (f32x4){0.f, 0.f, 0.f, 0.f};

    int srow = wv * 16 + (lane >> 2);
    int scol = (lane & 3) * 8;
    const __hip_bfloat16* pa0 = A + (size_t)(bm + srow) * K + scol;
    const __hip_bfloat16* pa1 = A + (size_t)(bm + 64 + srow) * K + scol;
    const __hip_bfloat16* pb0 = Bw + (size_t)(bn + srow) * K + scol;
    const __hip_bfloat16* pb1 = Bw + (size_t)(bn + 64 + srow) * K + scol;
    char* At_b = (char*)&At[0][0] + wv * 1024;
    char* Bt_b = (char*)&Bt[0][0] + wv * 1024;

    for (int k0 = 0; k0 < K; k0 += 32) {
        gload_lds16(pa0 + k0, At_b);
        gload_lds16(pa1 + k0, At_b + 4096);
        gload_lds16(pb0 + k0, Bt_b);
        gload_lds16(pb1 + k0, Bt_b + 4096);
        __syncthreads();

        bf8_t af[4], bfr[4];
        #pragma unroll
        for (int mi = 0; mi < 4; ++mi)
            af[mi] = *(const bf8_t*)((const char*)&At[0][0] +
                     (wr * 64 + mi * 16 + (lane & 15)) * 64 + (lane >> 4) * 16);
        #pragma unroll
        for (int ni = 0; ni < 4; ++ni)
            bfr[ni] = *(const bf8_t*)((const char*)&Bt[0][0] +
                     (wc * 64 + ni * 16 + (lane & 15)) * 64 + (lane >> 4) * 16);
        #pragma unroll
        for (int mi = 0; mi < 4; ++mi)
            #pragma unroll
            for (int ni = 0; ni < 4; ++ni)
                acc[mi][ni] = __builtin_amdgcn_mfma_f32_16x16x32_bf16(
                    af[mi], bfr[ni], acc[mi][ni], 0, 0, 0);
        __syncthreads();
    }

    if (z == 0) {
        #pragma unroll
        for (int mi = 0; mi < 4; ++mi) {
            int r0 = bm + wr * 64 + mi * 16 + (lane >> 4) * 4;
            #pragma unroll
            for (int ni = 0; ni < 4; ++ni) {
                int c0 = bn + wc * 64 + ni * 16 + (lane & 15);
                if (c0 < 288) {
                    #pragma unroll
                    for (int j = 0; j < 4; ++j) {
                        float v = acc[mi][ni][j];
                        if (c0 < 64) v = tanhf(v);
                        else if (c0 >= 160) v = sigf(v);
                        H[(size_t)(r0 + j) * 288 + c0] = __float2bfloat16(v);
                    }
                }
            }
        }
    } else {
        #pragma unroll
        for (int mi = 0; mi < 4; ++mi) {
            int r0 = bm + wr * 64 + mi * 16 + (lane >> 4) * 4;
            #pragma unroll
            for (int ni = 0; ni < 4; ++ni) {
                int c0 = bn + wc * 64 + ni * 16 + (lane & 15);
                #pragma unroll
                for (int j = 0; j < 4; ++j)
                    Cout[(size_t)(r0 + j) * Cdim + c0] = acc[mi][ni][j];
            }
        }
    }
}

// ---------------------------------------------------------------------------
// Single bf16 MFMA GEMM (output projection).
// ---------------------------------------------------------------------------
__global__ __launch_bounds__(256) void gemm_mfma(
    const __hip_bfloat16* __restrict__ A, const __hip_bfloat16* __restrict__ Bw,
    float* __restrict__ Cout, int M, int N, int K)
{
    __shared__ unsigned short At[128][32];
    __shared__ unsigned short Bt[128][32];
    int tid = threadIdx.x;
    int lane = tid & 63, wv = tid >> 6;
    int bm = blockIdx.y * 128, bn = blockIdx.x * 128;
    int wr = wv >> 1, wc = wv & 1;

    f32x4 acc[4][4];
    #pragma unroll
    for (int mi = 0; mi < 4; ++mi)
        #pragma unroll
        for (int ni = 0; ni < 4; ++ni)
            acc[mi][ni] = (f32x4){0.f, 0.f, 0.f, 0.f};

    int srow = wv * 16 + (lane >> 2);
    int scol = (lane & 3) * 8;
    const __hip_bfloat16* pa0 = A + (size_t)(bm + srow) * K + scol;
    const __hip_bfloat16* pa1 = A + (size_t)(bm + 64 + srow) * K + scol;
    const __hip_bfloat16* pb0 = Bw + (size_t)(bn + srow) * K + scol;
    const __hip_bfloat16* pb1 = Bw + (size_t)(bn + 64 + srow) * K + scol;
    char* At_b = (char*)&At[0][0] + wv * 1024;
    char* Bt_b = (char*)&Bt[0][0] + wv * 1024;

    for (int k0 = 0; k0 < K; k0 += 32) {
        gload_lds16(pa0 + k0, At_b);
        gload_lds16(pa1 + k0, At_b + 4096);
        gload_lds16(pb0 + k0, Bt_b);
        gload_lds16(pb1 + k0, Bt_b + 4096);
        __syncthreads();

        bf8_t af[4], bfr[4];
        #pragma unroll
        for (int mi = 0; mi < 4; ++mi)
            af[mi] = *(const bf8_t*)((const char*)&At[0][0] +
                     (wr * 64 + mi * 16 + (lane & 15)) * 64 + (lane >> 4) * 16);
        #pragma unroll
        for (int ni = 0; ni < 4; ++ni)
            bfr[ni] = *(const bf8_t*)((const char*)&Bt[0][0] +
                     (wc * 64 + ni * 16 + (lane & 15)) * 64 + (lane >> 4) * 16);
        #pragma unroll
        for (int mi = 0; mi < 4; ++mi)
            #pragma unroll
            for (int ni = 0; ni < 4; ++ni)
                acc[mi][ni] = __builtin_amdgcn_mfma_f32_16x16x32_bf16(
                    af[mi], bfr[ni], acc[mi][ni], 0, 0, 0);
        __syncthreads();
    }

    #pragma unroll
    for (int mi = 0; mi < 4; ++mi) {
        int r0 = bm + wr * 64 + mi * 16 + (lane >> 4) * 4;
        #pragma unroll
        for (int ni = 0; ni < 4; ++ni) {
            int c0 = bn + wc * 64 + ni * 16 + (lane & 15);
            #pragma unroll
            for (int j = 0; j < 4; ++j)
                Cout[(size_t)(r0 + j) * N + c0] = acc[mi][ni][j];
        }
    }
}

// ---------------------------------------------------------------------------
// gemm_lr2: block-diag expansion, epilogue demux (unchanged).
// ---------------------------------------------------------------------------
__global__ __launch_bounds__(256) void gemm_lr2(
    const __hip_bfloat16* __restrict__ H, const __hip_bfloat16* __restrict__ W,
    const float* __restrict__ w0, const float* __restrict__ a0,
    const float* __restrict__ v0,
    float* __restrict__ decay, __hip_bfloat16* __restrict__ at16,
    float* __restrict__ vt, __hip_bfloat16* __restrict__ gt16)
{
    const int K = 288;
    __shared__ unsigned short At[128][32];
    __shared__ unsigned short Bt[128][32];
    int tid = threadIdx.x;
    int lane = tid & 63, wv = tid >> 6;
    int bm = blockIdx.y * 128, bn = blockIdx.x * 128;
    int wr = wv >> 1, wc = wv & 1;

    f32x4 acc[4][4];
    #pragma unroll
    for (int mi = 0; mi < 4; ++mi)
        #pragma unroll
        for (int ni = 0; ni < 4; ++ni)
            acc[mi][ni] = (f32x4){0.f, 0.f, 0.f, 0.f};

    int srow = wv * 16 + (lane >> 2);
    int scol = (lane & 3) * 8;
    const __hip_bfloat16* pa0 = H + (size_t)(bm + srow) * K + scol;
    const __hip_bfloat16* pa1 = H + (size_t)(bm + 64 + srow) * K + scol;
    const __hip_bfloat16* pb0 = W + (size_t)(bn + srow) * K + scol;
    const __hip_bfloat16* pb1 = W + (size_t)(bn + 64 + srow) * K + scol;
    char* At_b = (char*)&At[0][0] + wv * 1024;
    char* Bt_b = (char*)&Bt[0][0] + wv * 1024;

    for (int k0 = 0; k0 < K; k0 += 32) {
        gload_lds16(pa0 + k0, At_b);
        gload_lds16(pa1 + k0, At_b + 4096);
        gload_lds16(pb0 + k0, Bt_b);
        gload_lds16(pb1 + k0, Bt_b + 4096);
        __syncthreads();

        bf8_t af[4], bfr[4];
        #pragma unroll
        for (int mi = 0; mi < 4; ++mi)
            af[mi] = *(const bf8_t*)((const char*)&At[0][0] +
                     (wr * 64 + mi * 16 + (lane & 15)) * 64 + (lane >> 4) * 16);
        #pragma unroll
        for (int ni = 0; ni < 4; ++ni)
            bfr[ni] = *(const bf8_t*)((const char*)&Bt[0][0] +
                     (wc * 64 + ni * 16 + (lane & 15)) * 64 + (lane >> 4) * 16);
        #pragma unroll
        for (int mi = 0; mi < 4; ++mi)
            #pragma unroll
            for (int ni = 0; ni < 4; ++ni)
                acc[mi][ni] = __builtin_amdgcn_mfma_f32_16x16x32_bf16(
                    af[mi], bfr[ni], acc[mi][ni], 0, 0, 0);
        __syncthreads();
    }

    #pragma unroll
    for (int mi = 0; mi < 4; ++mi) {
        int r0 = bm + wr * 64 + mi * 16 + (lane >> 4) * 4;
        #pragma unroll
        for (int ni = 0; ni < 4; ++ni) {
            int np = bn + wc * 64 + ni * 16 + (lane & 15);
            int path = np >> 10, nl = np & 1023;
            #pragma unroll
            for (int j = 0; j < 4; ++j) {
                float v = acc[mi][ni][j];
                size_t oi = (size_t)(r0 + j) * Cdim + nl;
                if (path == 0)      decay[oi] = sigf(v + w0[nl]) * 0.60653065971263342f;
                else if (path == 1) at16[oi] = __float2bfloat16(sigf(v + a0[nl]));
                else if (path == 2) vt[oi] = sigf(v + v0[nl]);
                else                gt16[oi] = __float2bfloat16(v);
            }
        }
    }
}

// ---------------------------------------------------------------------------
// E1: kk-normalize -> aarr=-kkn, barr=kkn*at; ut; v_first passthrough.
// ---------------------------------------------------------------------------
__global__ __launch_bounds__(256) void e1_kernel(
    const float* __restrict__ kt, const __hip_bfloat16* __restrict__ at16,
    const float* __restrict__ rt, const float* __restrict__ vraw,
    const float* __restrict__ vt, const float* __restrict__ vfirst,
    const float* __restrict__ k_k, const float* __restrict__ k_a,
    const float* __restrict__ r_k,
    float* __restrict__ aarr, float* __restrict__ barr,
    float* __restrict__ ut, float* __restrict__ out2)
{
    int gid = blockIdx.x * 4 + (threadIdx.x >> 6);
    int lane = threadIdx.x & 63;
    int h = gid % Hdim;
    size_t idx = (size_t)gid * 64 + lane;
    int c = h * 64 + lane;
    float ktv = kt[idx];
    float atv = __bfloat162float(at16[idx]);
    float kk = ktv * k_k[c];
    float ss = wsum64(kk * kk);
    float norm = sqrtf(ss);
    float kkn = kk / fmaxf(norm, 1e-12f);
    aarr[idx] = -kkn;
    barr[idx] = kkn * atv;
    float kmix = ktv * (1.f + (atv - 1.f) * k_a[c]);
    float rv = rt[idx];
    float dot = wsum64(rv * kmix * r_k[c]);
    float vm = vraw[idx];
    float vf = vfirst[idx];
    vm = vm + (vf - vm) * vt[idx];
    ut[idx] = dot * vm;
    out2[idx] = vf;
}

// ---------------------------------------------------------------------------
// WKV scan v8 (unchanged from R13): 16-way row-split, 4 rows x 16 lanes,
// all-DPP reduce, XCD-local ordering, 4-deep asm-batched reg pipeline.
// ---------------------------------------------------------------------------
struct Ops { f4 a, d, k, b, r; float vi; };

static __device__ __forceinline__ void load_set(
    Ops& s, const float* pa, const float* pd, const float* pk,
    const float* pb, const float* pr, const float* pv)
{
    asm volatile(
        "global_load_dwordx4 %0, %6, off\n\t"
        "global_load_dword   %5, %11, off\n\t"
        "global_load_dwordx4 %1, %7, off\n\t"
        "global_load_dwordx4 %2, %8, off\n\t"
        "global_load_dwordx4 %3, %9, off\n\t"
        "global_load_dwordx4 %4, %10, off"
        : "=&v"(s.a), "=&v"(s.d), "=&v"(s.k), "=&v"(s.b), "=&v"(s.r), "=&v"(s.vi)
        : "v"(pa), "v"(pd), "v"(pk), "v"(pb), "v"(pr), "v"(pv));
}

static __device__ __forceinline__ void wkv_wait18() {
    asm volatile("s_waitcnt vmcnt(18)" ::: "memory");
    __builtin_amdgcn_sched_barrier(0);
}

static __device__ __forceinline__ void wkv_compute(
    float S[4], const Ops& o, float* po, int q)
{
    float s0 = S[0] * o.a.x, s1 = S[1] * o.a.y;
    float s2 = S[2] * o.a.z, s3 = S[3] * o.a.w;
    float sp = red16_dpp((s0 + s1) + (s2 + s3));

    S[0] = fmaf(S[0], o.d.x, fmaf(sp, o.b.x, o.vi * o.k.x));
    S[1] = fmaf(S[1], o.d.y, fmaf(sp, o.b.y, o.vi * o.k.y));
    S[2] = fmaf(S[2], o.d.z, fmaf(sp, o.b.z, o.vi * o.k.z));
    S[3] = fmaf(S[3], o.d.w, fmaf(sp, o.b.w, o.vi * o.k.w));

    float o0 = S[0] * o.r.x, o1 = S[1] * o.r.y;
    float o2 = S[2] * o.r.z, o3 = S[3] * o.r.w;
    float op = red16_dpp((o0 + o1) + (o2 + o3));
    if (q == 0) *po = op;
}

__global__ __launch_bounds__(64, 1) void wkv_kernel(
    const float* __restrict__ rt, const float* __restrict__ decay,
    const float* __restrict__ kt, const float* __restrict__ vt,
    const float* __restrict__ aarr, const float* __restrict__ barr,
    float* __restrict__ wkvt)
{
    int tid = threadIdx.x;
    int blk = blockIdx.x;              // 512 blocks: chunk*32 + bh (XCD-local)
    int chunk = blk >> 5, bh = blk & 31;
    int b = bh >> 4, h = bh & 15;
    int i = chunk * 4 + (tid >> 4);    // state row owned by this 16-lane group
    int q = tid & 15;                  // column-slice owner (4 cols)
    int jb = q * 4;
    size_t base = ((size_t)b * Tdim) * Cdim + (size_t)h * Ndim;
    const float* pa = aarr + base + jb;
    const float* pd = decay + base + jb;
    const float* pk = kt + base + jb;
    const float* pb = barr + base + jb;
    const float* pr = rt + base + jb;
    const float* pv = vt + base + i;
    float* po = wkvt + base + i;

    float S[4];
    #pragma unroll
    for (int j = 0; j < 4; ++j) S[j] = 0.f;

    Ops A, B, C, D;
    load_set(A, pa, pd, pk, pb, pr, pv);
    {
        size_t o1 = (size_t)1 * Cdim, o2 = (size_t)2 * Cdim, o3 = (size_t)3 * Cdim;
        load_set(B, pa + o1, pd + o1, pk + o1, pb + o1, pr + o1, pv + o1);
        load_set(C, pa + o2, pd + o2, pk + o2, pb + o2, pr + o2, pv + o2);
        load_set(D, pa + o3, pd + o3, pk + o3, pb + o3, pr + o3, pv + o3);
    }

    for (int t = 0; t < Tdim; t += 4) {
        wkv_wait18();
        wkv_compute(S, A, po + (size_t)t * Cdim, q);
        size_t o4 = (size_t)((t + 4 < Tdim) ? t + 4 : Tdim - 1) * Cdim;
        load_set(A, pa + o4, pd + o4, pk + o4, pb + o4, pr + o4, pv + o4);

        wkv_wait18();
        wkv_compute(S, B, po + (size_t)(t + 1) * Cdim, q);
        size_t o5 = (size_t)((t + 5 < Tdim) ? t + 5 : Tdim - 1) * Cdim;
        load_set(B, pa + o5, pd + o5, pk + o5, pb + o5, pr + o5, pv + o5);

        wkv_wait18();
        wkv_compute(S, C, po + (size_t)(t + 2) * Cdim, q);
        size_t o6 = (size_t)((t + 6 < Tdim) ? t + 6 : Tdim - 1) * Cdim;
        load_set(C, pa + o6, pd + o6, pk + o6, pb + o6, pr + o6, pv + o6);

        wkv_wait18();
        wkv_compute(S, D, po + (size_t)(t + 3) * Cdim, q);
        size_t o7 = (size_t)((t + 7 < Tdim) ? t + 7 : Tdim - 1) * Cdim;
        load_set(D, pa + o7, pd + o7, pk + o7, pb + o7, pr + o7, pv + o7);
    }
}

// ---------------------------------------------------------------------------
// E2: pt = GroupNorm(rt*wkvt)*ln_g + ln_b + ut; g16 = bf16(gt*pt)
// ---------------------------------------------------------------------------
__global__ __launch_bounds__(256) void e2_kernel(
    const float* __restrict__ rt, const float* __restrict__ wkvt,
    const float* __restrict__ ut, const __hip_bfloat16* __restrict__ gt16,
    const float* __restrict__ ln_g, const float* __restrict__ ln_b,
    __hip_bfloat16* __restrict__ g16)
{
    int gid = blockIdx.x * 4 + (threadIdx.x >> 6);
    int lane = threadIdx.x & 63;
    int h = gid % Hdim;
    size_t idx = (size_t)gid * 64 + lane;
    int c = h * 64 + lane;
    float x = rt[idx] * wkvt[idx];
    float mu = wsum64(x) * (1.f / 64.f);
    float d = x - mu;
    float var = wsum64(d * d) * (1.f / 64.f);
    float xn = d / sqrtf(var + EPS_GN);
    float pt = xn * ln_g[c] + ln_b[c] + ut[idx];
    float res = __bfloat162float(gt16[idx]) * pt;
    g16[idx] = __float2bfloat16(res);
}

// ---------------------------------------------------------------------------
extern "C" void kernel_launch(void* const* d_in, const int* in_sizes, int n_in,
                              void* d_out, int out_size, void* d_ws, size_t ws_size,
                              hipStream_t stream)
{
    (void)in_sizes; (void)n_in; (void)out_size; (void)ws_size;
    const float* xt      = (const float*)d_in[0];
    const float* v_first = (const float*)d_in[1];
    const float* tmix_r  = (const float*)d_in[2];
    const float* tmix_w  = (const float*)d_in[3];
    const float* tmix_k  = (const float*)d_in[4];
    const float* tmix_v  = (const float*)d_in[5];
    const float* tmix_a  = (const float*)d_in[6];
    const float* tmix_g  = (const float*)d_in[7];
    const float* w1 = (const float*)d_in[8];
    const float* w2 = (const float*)d_in[9];
    const float* w0 = (const float*)d_in[10];
    const float* a1 = (const float*)d_in[11];
    const float* a2 = (const float*)d_in[12];
    const float* a0 = (const float*)d_in[13];
    const float* v1 = (const float*)d_in[14];
    const float* v2 = (const float*)d_in[15];
    const float* v0 = (const float*)d_in[16];
    const float* g1 = (const float*)d_in[17];
    const float* g2 = (const float*)d_in[18];
    const float* k_k = (const float*)d_in[19];
    const float* k_a = (const float*)d_in[20];
    const float* r_k = (const float*)d_in[21];
    const float* W_r = (const float*)d_in[22];
    const float* W_k = (const float*)d_in[23];
    const float* W_v = (const float*)d_in[24];
    const float* W_o = (const float*)d_in[25];
    const float* ln_g = (const float*)d_in[26];
    const float* ln_b = (const float*)d_in[27];

    float* out = (float*)d_out;
    const size_t BTC = (size_t)Bdim * Tdim * Cdim;   // 2,097,152
    const int M = Bdim * Tdim;                        // 2048

    float* ws = (float*)d_ws;
    float* rt    = ws + 0 * BTC;
    float* kt    = ws + 1 * BTC;
    float* vraw  = ws + 2 * BTC;
    float* vt    = ws + 3 * BTC;
    float* decay = ws + 4 * BTC;
    float* aarr  = ws + 5 * BTC;
    float* barr  = ws + 6 * BTC;
    float* ut    = ws + 7 * BTC;
    float* wkv   = ws + 8 * BTC;
    __hip_bfloat16* bfa = (__hip_bfloat16*)(ws + 9 * BTC);
    __hip_bfloat16* at16 = bfa + 0 * BTC;
    __hip_bfloat16* gt16 = bfa + 1 * BTC;
    __hip_bfloat16* xr16 = bfa + 2 * BTC;
    __hip_bfloat16* xk16 = bfa + 3 * BTC;
    __hip_bfloat16* xv16 = bfa + 4 * BTC;   // reused as g16 after gemm
    __hip_bfloat16* Wb   = bfa + 5 * BTC;   // 4*CCdim = 2*BTC bf16
    // Aliased scratch (dead before their slots' writers run):
    __hip_bfloat16* Aall = (__hip_bfloat16*)decay;           // 8MB (decay written later by gemm_lr2)
    __hip_bfloat16* Wlr1 = (__hip_bfloat16*)aarr;            // (aarr written later by e1)
    __hip_bfloat16* Wl2  = Wlr1 + (size_t)384 * 2048;
    __hip_bfloat16* hcat = Wl2 + (size_t)4096 * 288;
    __hip_bfloat16* g16 = xv16;

    // prep: weights (bf16, Wlr1, Wl2) + activation lerps + Aall, one dispatch
    prep_fused<<<7552, 256, 0, stream>>>(
        W_r, W_k, W_v, W_o, w1, a1, v1, g1, w2, a2, v2, g2,
        tmix_w, tmix_a, tmix_v, tmix_g, xt, tmix_r, tmix_k,
        Wb, Wlr1, Wl2, xr16, xk16, xv16, Aall);

    // fused GEMM: z=0 lr1 (K=2048, long blocks first) + z=1..3 projections
    dim3 ggf(Cdim / 128, M / 128, 4);   // (8,16,4)
    gemm_fused<<<ggf, 256, 0, stream>>>(xr16, xk16, xv16, Aall, Wb, Wlr1,
                                        rt, kt, vraw, hcat);

    // lr2 expansion (block-diag) -> decay/at16/vt/gt16
    gemm_lr2<<<dim3(32, 16), 256, 0, stream>>>(hcat, Wl2, w0, a0, v0,
                                               decay, at16, vt, gt16);

    // E1
    e1_kernel<<<(Bdim * Tdim * Hdim) / 4, 256, 0, stream>>>(
        kt, at16, rt, vraw, vt, v_first, k_k, k_a, r_k,
        aarr, barr, ut, out + BTC);

    // WKV scan (16-way XCD-local split, all-DPP reduce, 4-deep pipeline)
    wkv_kernel<<<512, 64, 0, stream>>>(rt, decay, kt, vt, aarr, barr, wkv);

    // E2 (writes bf16 gated output)
    e2_kernel<<<(Bdim * Tdim * Hdim) / 4, 256, 0, stream>>>(
        rt, wkv, ut, gt16, ln_g, ln_b, g16);

    // output projection (bf16 MFMA)
    dim3 gg(Cdim / 128, M / 128);
    gemm_mfma<<<gg, 256, 0, stream>>>(g16, Wb + 3 * (size_t)CCdim, out, M, Cdim, Cdim);
}

// Round 16
// 289.834 us; speedup vs baseline: 1.4674x; 1.0651x over previous
//
#include <hip/hip_runtime.h>
#include <hip/hip_bf16.h>
#include <math.h>

#define Bdim 2
#define Tdim 1024
#define Cdim 1024
#define Hdim 16
#define Ndim 64
#define CCdim (Cdim * Cdim)
#define EPS_GN 0.00064f

typedef __bf16 bf8_t __attribute__((ext_vector_type(8)));
typedef float f32x4 __attribute__((ext_vector_type(4)));
typedef float f4 __attribute__((ext_vector_type(4)));

static __device__ __forceinline__ float sigf(float x) { return 1.f / (1.f + expf(-x)); }

static __device__ __forceinline__ float wsum64(float v) {
    #pragma unroll
    for (int m = 1; m < 64; m <<= 1) v += __shfl_xor(v, m);
    return v;
}

static __device__ __forceinline__ void gload_lds16(const void* g, void* l) {
    __builtin_amdgcn_global_load_lds(
        (const __attribute__((address_space(1))) void*)g,
        (__attribute__((address_space(3))) void*)l, 16, 0, 0);
}

// 16-lane sum, ALL-DPP: quad_perm xor1 (0xB1), xor2 (0x4E),
// row_half_mirror (0x141), row_mirror (0x140). shfl_xor ~35cyc; DPP ~5-8.
static __device__ __forceinline__ float red16_dpp(float x) {
    int s1 = __builtin_amdgcn_update_dpp(0, __builtin_bit_cast(int, x),
                                         0xB1, 0xF, 0xF, true);
    float y = x + __builtin_bit_cast(float, s1);
    int s2 = __builtin_amdgcn_update_dpp(0, __builtin_bit_cast(int, y),
                                         0x4E, 0xF, 0xF, true);
    float z = y + __builtin_bit_cast(float, s2);
    int s3 = __builtin_amdgcn_update_dpp(0, __builtin_bit_cast(int, z),
                                         0x141, 0xF, 0xF, true);
    float w = z + __builtin_bit_cast(float, s3);
    int s4 = __builtin_amdgcn_update_dpp(0, __builtin_bit_cast(int, w),
                                         0x140, 0xF, 0xF, true);
    return w + __builtin_bit_cast(float, s4);
}

// ---------------------------------------------------------------------------
// prep_fused: weights (blk<6528, 3 segments) + activations (blk>=6528).
// ---------------------------------------------------------------------------
__global__ __launch_bounds__(256) void prep_fused(
    const float* __restrict__ W0, const float* __restrict__ W1,
    const float* __restrict__ W2, const float* __restrict__ W3,
    const float* __restrict__ w1, const float* __restrict__ a1,
    const float* __restrict__ v1, const float* __restrict__ g1,
    const float* __restrict__ w2, const float* __restrict__ a2,
    const float* __restrict__ v2, const float* __restrict__ g2,
    const float* __restrict__ mw, const float* __restrict__ ma,
    const float* __restrict__ mv, const float* __restrict__ mg,
    const float* __restrict__ xt,
    const float* __restrict__ mr, const float* __restrict__ mk,
    __hip_bfloat16* __restrict__ Wb, __hip_bfloat16* __restrict__ Wlr1,
    __hip_bfloat16* __restrict__ Wl2,
    __hip_bfloat16* __restrict__ xr16, __hip_bfloat16* __restrict__ xk16,
    __hip_bfloat16* __restrict__ xv16, __hip_bfloat16* __restrict__ Aall)
{
    int blk = blockIdx.x;
    int tid = threadIdx.x;
    if (blk < 2048) {
        int which = blk >> 9;
        const float* src = (which == 0) ? W0 : (which == 1) ? W1 : (which == 2) ? W2 : W3;
        size_t e8 = ((size_t)(blk & 511) * 256 + tid) * 8;
        float c[8];
        *(float4*)&c[0] = ((const float4*)(src + e8))[0];
        *(float4*)&c[4] = ((const float4*)(src + e8))[1];
        __hip_bfloat16 o[8];
        #pragma unroll
        for (int j = 0; j < 8; ++j) o[j] = __float2bfloat16(c[j]);
        __hip_bfloat16* dst = Wb + (size_t)which * CCdim + e8;
        ((ushort4*)dst)[0] = *(ushort4*)&o[0];
        ((ushort4*)dst)[1] = *(ushort4*)&o[4];
    } else if (blk < 2432) {
        int n = blk - 2048;                 // 0..383
        if (n < 288) {
            const float* M1; const float* mix; int D, nl;
            if (n < 64)       { M1 = w1; mix = mw; D = 64;  nl = n; }
            else if (n < 128) { M1 = a1; mix = ma; D = 64;  nl = n - 64; }
            else if (n < 160) { M1 = v1; mix = mv; D = 32;  nl = n - 128; }
            else              { M1 = g1; mix = mg; D = 128; nl = n - 160; }
            #pragma unroll
            for (int i = 0; i < 8; ++i) {
                int kp = tid + i * 256;     // 0..2047
                int k = kp & 1023, half = kp >> 10;
                float mx = mix[k];
                float val = M1[(size_t)k * D + nl] * (half ? mx : 1.f - mx);
                Wlr1[(size_t)n * 2048 + kp] = __float2bfloat16(val);
            }
        } else {
            #pragma unroll
            for (int i = 0; i < 8; ++i)
                Wlr1[(size_t)n * 2048 + tid + i * 256] = __float2bfloat16(0.f);
        }
    } else if (blk < 6528) {
        int np = blk - 2432;                // 0..4095
        int path = np >> 10, nl = np & 1023;
        const float* M2; int off, D;
        if (path == 0)      { M2 = w2; off = 0;   D = 64; }
        else if (path == 1) { M2 = a2; off = 64;  D = 64; }
        else if (path == 2) { M2 = v2; off = 128; D = 32; }
        else                { M2 = g2; off = 160; D = 128; }
        for (int kp = tid; kp < 288; kp += 256) {
            int kl = kp - off;
            float val = (kl >= 0 && kl < D) ? M2[(size_t)kl * Cdim + nl] : 0.f;
            Wl2[(size_t)np * 288 + kp] = __float2bfloat16(val);
        }
    } else {
        // activation prep: lerps (r,k,v) -> bf16 + Aall = [x | xprev]
        int idx8 = (blk - 6528) * 256 + tid;     // 0..262143
        int m = idx8 >> 7;
        int c8 = (idx8 & 127) * 8;
        int t = m & (Tdim - 1);
        const float* p = xt + (size_t)idx8 * 8;
        float cur[8], prv[8];
        *(float4*)&cur[0] = ((const float4*)p)[0];
        *(float4*)&cur[4] = ((const float4*)p)[1];
        if (t > 0) {
            *(float4*)&prv[0] = ((const float4*)(p - Cdim))[0];
            *(float4*)&prv[4] = ((const float4*)(p - Cdim))[1];
        } else {
            #pragma unroll
            for (int j = 0; j < 8; ++j) prv[j] = 0.f;
        }
        float mx[8];
        __hip_bfloat16 o[8];
        size_t ob = (size_t)idx8 * 8;

        *(float4*)&mx[0] = *(const float4*)(mr + c8);
        *(float4*)&mx[4] = *(const float4*)(mr + c8 + 4);
        #pragma unroll
        for (int j = 0; j < 8; ++j) o[j] = __float2bfloat16(cur[j] + (prv[j] - cur[j]) * mx[j]);
        ((ushort4*)(xr16 + ob))[0] = *(ushort4*)&o[0];
        ((ushort4*)(xr16 + ob))[1] = *(ushort4*)&o[4];

        *(float4*)&mx[0] = *(const float4*)(mk + c8);
        *(float4*)&mx[4] = *(const float4*)(mk + c8 + 4);
        #pragma unroll
        for (int j = 0; j < 8; ++j) o[j] = __float2bfloat16(cur[j] + (prv[j] - cur[j]) * mx[j]);
        ((ushort4*)(xk16 + ob))[0] = *(ushort4*)&o[0];
        ((ushort4*)(xk16 + ob))[1] = *(ushort4*)&o[4];

        *(float4*)&mx[0] = *(const float4*)(mv + c8);
        *(float4*)&mx[4] = *(const float4*)(mv + c8 + 4);
        #pragma unroll
        for (int j = 0; j < 8; ++j) o[j] = __float2bfloat16(cur[j] + (prv[j] - cur[j]) * mx[j]);
        ((ushort4*)(xv16 + ob))[0] = *(ushort4*)&o[0];
        ((ushort4*)(xv16 + ob))[1] = *(ushort4*)&o[4];

        size_t ab = (size_t)m * 2048 + c8;
        #pragma unroll
        for (int j = 0; j < 8; ++j) o[j] = __float2bfloat16(cur[j]);
        ((ushort4*)(Aall + ab))[0] = *(ushort4*)&o[0];
        ((ushort4*)(Aall + ab))[1] = *(ushort4*)&o[4];
        #pragma unroll
        for (int j = 0; j < 8; ++j) o[j] = __float2bfloat16(prv[j]);
        ((ushort4*)(Aall + ab + 1024))[0] = *(ushort4*)&o[0];
        ((ushort4*)(Aall + ab + 1024))[1] = *(ushort4*)&o[4];
    }
}

// ---------------------------------------------------------------------------
// gemm_fused: z=0 -> lr1 (K=2048, x<3 only); z=1..3 -> C x C projections.
// ---------------------------------------------------------------------------
__global__ __launch_bounds__(256) void gemm_fused(
    const __hip_bfloat16* __restrict__ A0, const __hip_bfloat16* __restrict__ A1,
    const __hip_bfloat16* __restrict__ A2, const __hip_bfloat16* __restrict__ Aall,
    const __hip_bfloat16* __restrict__ Wbase, const __hip_bfloat16* __restrict__ Wlr1,
    float* __restrict__ C0, float* __restrict__ C1, float* __restrict__ C2,
    __hip_bfloat16* __restrict__ H)
{
    __shared__ unsigned short At[128][32];
    __shared__ unsigned short Bt[128][32];
    int z = blockIdx.z;
    const __hip_bfloat16* A; const __hip_bfloat16* Bw;
    float* Cout = nullptr;
    int K;
    if (z == 0) {
        if (blockIdx.x >= 3) return;   // N=384: 3 column tiles
        A = Aall; Bw = Wlr1; K = 2048;
    } else {
        int zi = z - 1;
        A = (zi == 0) ? A0 : (zi == 1) ? A1 : A2;
        Bw = Wbase + (size_t)zi * CCdim;
        Cout = (zi == 0) ? C0 : (zi == 1) ? C1 : C2;
        K = Cdim;
    }
    int tid = threadIdx.x;
    int lane = tid & 63, wv = tid >> 6;
    int bm = blockIdx.y * 128, bn = blockIdx.x * 128;
    int wr = wv >> 1, wc = wv & 1;

    f32x4 acc[4][4];
    #pragma unroll
    for (int mi = 0; mi < 4; ++mi)
        #pragma unroll
        for (int ni = 0; ni < 4; ++ni)
            acc[mi][ni] = (f32x4){0.f, 0.f, 0.f, 0.f};

    int srow = wv * 16 + (lane >> 2);
    int scol = (lane & 3) * 8;
    const __hip_bfloat16* pa0 = A + (size_t)(bm + srow) * K + scol;
    const __hip_bfloat16* pa1 = A + (size_t)(bm + 64 + srow) * K + scol;
    const __hip_bfloat16* pb0 = Bw + (size_t)(bn + srow) * K + scol;
    const __hip_bfloat16* pb1 = Bw + (size_t)(bn + 64 + srow) * K + scol;
    char* At_b = (char*)&At[0][0] + wv * 1024;
    char* Bt_b = (char*)&Bt[0][0] + wv * 1024;

    for (int k0 = 0; k0 < K; k0 += 32) {
        gload_lds16(pa0 + k0, At_b);
        gload_lds16(pa1 + k0, At_b + 4096);
        gload_lds16(pb0 + k0, Bt_b);
        gload_lds16(pb1 + k0, Bt_b + 4096);
        __syncthreads();

        bf8_t af[4], bfr[4];
        #pragma unroll
        for (int mi = 0; mi < 4; ++mi)
            af[mi] = *(const bf8_t*)((const char*)&At[0][0] +
                     (wr * 64 + mi * 16 + (lane & 15)) * 64 + (lane >> 4) * 16);
        #pragma unroll
        for (int ni = 0; ni < 4; ++ni)
            bfr[ni] = *(const bf8_t*)((const char*)&Bt[0][0] +
                     (wc * 64 + ni * 16 + (lane & 15)) * 64 + (lane >> 4) * 16);
        #pragma unroll
        for (int mi = 0; mi < 4; ++mi)
            #pragma unroll
            for (int ni = 0; ni < 4; ++ni)
                acc[mi][ni] = __builtin_amdgcn_mfma_f32_16x16x32_bf16(
                    af[mi], bfr[ni], acc[mi][ni], 0, 0, 0);
        __syncthreads();
    }

    if (z == 0) {
        #pragma unroll
        for (int mi = 0; mi < 4; ++mi) {
            int r0 = bm + wr * 64 + mi * 16 + (lane >> 4) * 4;
            #pragma unroll
            for (int ni = 0; ni < 4; ++ni) {
                int c0 = bn + wc * 64 + ni * 16 + (lane & 15);
                if (c0 < 288) {
                    #pragma unroll
                    for (int j = 0; j < 4; ++j) {
                        float v = acc[mi][ni][j];
                        if (c0 < 64) v = tanhf(v);
                        else if (c0 >= 160) v = sigf(v);
                        H[(size_t)(r0 + j) * 288 + c0] = __float2bfloat16(v);
                    }
                }
            }
        }
    } else {
        #pragma unroll
        for (int mi = 0; mi < 4; ++mi) {
            int r0 = bm + wr * 64 + mi * 16 + (lane >> 4) * 4;
            #pragma unroll
            for (int ni = 0; ni < 4; ++ni) {
                int c0 = bn + wc * 64 + ni * 16 + (lane & 15);
                #pragma unroll
                for (int j = 0; j < 4; ++j)
                    Cout[(size_t)(r0 + j) * Cdim + c0] = acc[mi][ni][j];
            }
        }
    }
}

// ---------------------------------------------------------------------------
// Single bf16 MFMA GEMM (output projection).
// ---------------------------------------------------------------------------
__global__ __launch_bounds__(256) void gemm_mfma(
    const __hip_bfloat16* __restrict__ A, const __hip_bfloat16* __restrict__ Bw,
    float* __restrict__ Cout, int M, int N, int K)
{
    __shared__ unsigned short At[128][32];
    __shared__ unsigned short Bt[128][32];
    int tid = threadIdx.x;
    int lane = tid & 63, wv = tid >> 6;
    int bm = blockIdx.y * 128, bn = blockIdx.x * 128;
    int wr = wv >> 1, wc = wv & 1;

    f32x4 acc[4][4];
    #pragma unroll
    for (int mi = 0; mi < 4; ++mi)
        #pragma unroll
        for (int ni = 0; ni < 4; ++ni)
            acc[mi][ni] = (f32x4){0.f, 0.f, 0.f, 0.f};

    int srow = wv * 16 + (lane >> 2);
    int scol = (lane & 3) * 8;
    const __hip_bfloat16* pa0 = A + (size_t)(bm + srow) * K + scol;
    const __hip_bfloat16* pa1 = A + (size_t)(bm + 64 + srow) * K + scol;
    const __hip_bfloat16* pb0 = Bw + (size_t)(bn + srow) * K + scol;
    const __hip_bfloat16* pb1 = Bw + (size_t)(bn + 64 + srow) * K + scol;
    char* At_b = (char*)&At[0][0] + wv * 1024;
    char* Bt_b = (char*)&Bt[0][0] + wv * 1024;

    for (int k0 = 0; k0 < K; k0 += 32) {
        gload_lds16(pa0 + k0, At_b);
        gload_lds16(pa1 + k0, At_b + 4096);
        gload_lds16(pb0 + k0, Bt_b);
        gload_lds16(pb1 + k0, Bt_b + 4096);
        __syncthreads();

        bf8_t af[4], bfr[4];
        #pragma unroll
        for (int mi = 0; mi < 4; ++mi)
            af[mi] = *(const bf8_t*)((const char*)&At[0][0] +
                     (wr * 64 + mi * 16 + (lane & 15)) * 64 + (lane >> 4) * 16);
        #pragma unroll
        for (int ni = 0; ni < 4; ++ni)
            bfr[ni] = *(const bf8_t*)((const char*)&Bt[0][0] +
                     (wc * 64 + ni * 16 + (lane & 15)) * 64 + (lane >> 4) * 16);
        #pragma unroll
        for (int mi = 0; mi < 4; ++mi)
            #pragma unroll
            for (int ni = 0; ni < 4; ++ni)
                acc[mi][ni] = __builtin_amdgcn_mfma_f32_16x16x32_bf16(
                    af[mi], bfr[ni], acc[mi][ni], 0, 0, 0);
        __syncthreads();
    }

    #pragma unroll
    for (int mi = 0; mi < 4; ++mi) {
        int r0 = bm + wr * 64 + mi * 16 + (lane >> 4) * 4;
        #pragma unroll
        for (int ni = 0; ni < 4; ++ni) {
            int c0 = bn + wc * 64 + ni * 16 + (lane & 15);
            #pragma unroll
            for (int j = 0; j < 4; ++j)
                Cout[(size_t)(r0 + j) * N + c0] = acc[mi][ni][j];
        }
    }
}

// ---------------------------------------------------------------------------
// gemm_lr2: block-diag expansion, epilogue demux (unchanged).
// ---------------------------------------------------------------------------
__global__ __launch_bounds__(256) void gemm_lr2(
    const __hip_bfloat16* __restrict__ H, const __hip_bfloat16* __restrict__ W,
    const float* __restrict__ w0, const float* __restrict__ a0,
    const float* __restrict__ v0,
    float* __restrict__ decay, __hip_bfloat16* __restrict__ at16,
    float* __restrict__ vt, __hip_bfloat16* __restrict__ gt16)
{
    const int K = 288;
    __shared__ unsigned short At[128][32];
    __shared__ unsigned short Bt[128][32];
    int tid = threadIdx.x;
    int lane = tid & 63, wv = tid >> 6;
    int bm = blockIdx.y * 128, bn = blockIdx.x * 128;
    int wr = wv >> 1, wc = wv & 1;

    f32x4 acc[4][4];
    #pragma unroll
    for (int mi = 0; mi < 4; ++mi)
        #pragma unroll
        for (int ni = 0; ni < 4; ++ni)
            acc[mi][ni] = (f32x4){0.f, 0.f, 0.f, 0.f};

    int srow = wv * 16 + (lane >> 2);
    int scol = (lane & 3) * 8;
    const __hip_bfloat16* pa0 = H + (size_t)(bm + srow) * K + scol;
    const __hip_bfloat16* pa1 = H + (size_t)(bm + 64 + srow) * K + scol;
    const __hip_bfloat16* pb0 = W + (size_t)(bn + srow) * K + scol;
    const __hip_bfloat16* pb1 = W + (size_t)(bn + 64 + srow) * K + scol;
    char* At_b = (char*)&At[0][0] + wv * 1024;
    char* Bt_b = (char*)&Bt[0][0] + wv * 1024;

    for (int k0 = 0; k0 < K; k0 += 32) {
        gload_lds16(pa0 + k0, At_b);
        gload_lds16(pa1 + k0, At_b + 4096);
        gload_lds16(pb0 + k0, Bt_b);
        gload_lds16(pb1 + k0, Bt_b + 4096);
        __syncthreads();

        bf8_t af[4], bfr[4];
        #pragma unroll
        for (int mi = 0; mi < 4; ++mi)
            af[mi] = *(const bf8_t*)((const char*)&At[0][0] +
                     (wr * 64 + mi * 16 + (lane & 15)) * 64 + (lane >> 4) * 16);
        #pragma unroll
        for (int ni = 0; ni < 4; ++ni)
            bfr[ni] = *(const bf8_t*)((const char*)&Bt[0][0] +
                     (wc * 64 + ni * 16 + (lane & 15)) * 64 + (lane >> 4) * 16);
        #pragma unroll
        for (int mi = 0; mi < 4; ++mi)
            #pragma unroll
            for (int ni = 0; ni < 4; ++ni)
                acc[mi][ni] = __builtin_amdgcn_mfma_f32_16x16x32_bf16(
                    af[mi], bfr[ni], acc[mi][ni], 0, 0, 0);
        __syncthreads();
    }

    #pragma unroll
    for (int mi = 0; mi < 4; ++mi) {
        int r0 = bm + wr * 64 + mi * 16 + (lane >> 4) * 4;
        #pragma unroll
        for (int ni = 0; ni < 4; ++ni) {
            int np = bn + wc * 64 + ni * 16 + (lane & 15);
            int path = np >> 10, nl = np & 1023;
            #pragma unroll
            for (int j = 0; j < 4; ++j) {
                float v = acc[mi][ni][j];
                size_t oi = (size_t)(r0 + j) * Cdim + nl;
                if (path == 0)      decay[oi] = sigf(v + w0[nl]) * 0.60653065971263342f;
                else if (path == 1) at16[oi] = __float2bfloat16(sigf(v + a0[nl]));
                else if (path == 2) vt[oi] = sigf(v + v0[nl]);
                else                gt16[oi] = __float2bfloat16(v);
            }
        }
    }
}

// ---------------------------------------------------------------------------
// E1: kk-normalize -> aarr=-kkn, barr=kkn*at; ut; v_first passthrough.
// ---------------------------------------------------------------------------
__global__ __launch_bounds__(256) void e1_kernel(
    const float* __restrict__ kt, const __hip_bfloat16* __restrict__ at16,
    const float* __restrict__ rt, const float* __restrict__ vraw,
    const float* __restrict__ vt, const float* __restrict__ vfirst,
    const float* __restrict__ k_k, const float* __restrict__ k_a,
    const float* __restrict__ r_k,
    float* __restrict__ aarr, float* __restrict__ barr,
    float* __restrict__ ut, float* __restrict__ out2)
{
    int gid = blockIdx.x * 4 + (threadIdx.x >> 6);
    int lane = threadIdx.x & 63;
    int h = gid % Hdim;
    size_t idx = (size_t)gid * 64 + lane;
    int c = h * 64 + lane;
    float ktv = kt[idx];
    float atv = __bfloat162float(at16[idx]);
    float kk = ktv * k_k[c];
    float ss = wsum64(kk * kk);
    float norm = sqrtf(ss);
    float kkn = kk / fmaxf(norm, 1e-12f);
    aarr[idx] = -kkn;
    barr[idx] = kkn * atv;
    float kmix = ktv * (1.f + (atv - 1.f) * k_a[c]);
    float rv = rt[idx];
    float dot = wsum64(rv * kmix * r_k[c]);
    float vm = vraw[idx];
    float vf = vfirst[idx];
    vm = vm + (vf - vm) * vt[idx];
    ut[idx] = dot * vm;
    out2[idx] = vf;
}

// ---------------------------------------------------------------------------
// WKV scan v10 = R13 v8 + STORE-AWARE counted waits (LDS staging reverted
// after R15 crash; this is the minimal-delta test of the same theory).
// R14 insight: global_store increments vmcnt on CDNA, so uniform vmcnt(18)
// forced each step to wait on a ~200cyc store round-trip. Store-aware
// counts: steady state, ops newer than set-X's loads = 3 stores + 18 loads
// -> vmcnt(21) retires X's loads while all stores stay in flight (~3
// macro-steps deep). First macro-iter peeled with exact waits {18,19,20,21}
// (queue holds 24 loads, then stores accumulate one per sub-step).
// ---------------------------------------------------------------------------
struct Ops { f4 a, d, k, b, r; float vi; };

static __device__ __forceinline__ void load_set(
    Ops& s, const float* pa, const float* pd, const float* pk,
    const float* pb, const float* pr, const float* pv)
{
    asm volatile(
        "global_load_dwordx4 %0, %6, off\n\t"
        "global_load_dword   %5, %11, off\n\t"
        "global_load_dwordx4 %1, %7, off\n\t"
        "global_load_dwordx4 %2, %8, off\n\t"
        "global_load_dwordx4 %3, %9, off\n\t"
        "global_load_dwordx4 %4, %10, off"
        : "=&v"(s.a), "=&v"(s.d), "=&v"(s.k), "=&v"(s.b), "=&v"(s.r), "=&v"(s.vi)
        : "v"(pa), "v"(pd), "v"(pk), "v"(pb), "v"(pr), "v"(pv));
}

static __device__ __forceinline__ void wkv_wait18() {
    asm volatile("s_waitcnt vmcnt(18)" ::: "memory");
    __builtin_amdgcn_sched_barrier(0);
}
static __device__ __forceinline__ void wkv_wait19() {
    asm volatile("s_waitcnt vmcnt(19)" ::: "memory");
    __builtin_amdgcn_sched_barrier(0);
}
static __device__ __forceinline__ void wkv_wait20() {
    asm volatile("s_waitcnt vmcnt(20)" ::: "memory");
    __builtin_amdgcn_sched_barrier(0);
}
static __device__ __forceinline__ void wkv_wait21() {
    asm volatile("s_waitcnt vmcnt(21)" ::: "memory");
    __builtin_amdgcn_sched_barrier(0);
}

static __device__ __forceinline__ void wkv_compute(
    float S[4], const Ops& o, float* po, int q)
{
    float s0 = S[0] * o.a.x, s1 = S[1] * o.a.y;
    float s2 = S[2] * o.a.z, s3 = S[3] * o.a.w;
    float sp = red16_dpp((s0 + s1) + (s2 + s3));

    S[0] = fmaf(S[0], o.d.x, fmaf(sp, o.b.x, o.vi * o.k.x));
    S[1] = fmaf(S[1], o.d.y, fmaf(sp, o.b.y, o.vi * o.k.y));
    S[2] = fmaf(S[2], o.d.z, fmaf(sp, o.b.z, o.vi * o.k.z));
    S[3] = fmaf(S[3], o.d.w, fmaf(sp, o.b.w, o.vi * o.k.w));

    float o0 = S[0] * o.r.x, o1 = S[1] * o.r.y;
    float o2 = S[2] * o.r.z, o3 = S[3] * o.r.w;
    float op = red16_dpp((o0 + o1) + (o2 + o3));
    if (q == 0) *po = op;
}

__global__ __launch_bounds__(64, 1) void wkv_kernel(
    const float* __restrict__ rt, const float* __restrict__ decay,
    const float* __restrict__ kt, const float* __restrict__ vt,
    const float* __restrict__ aarr, const float* __restrict__ barr,
    float* __restrict__ wkvt)
{
    int tid = threadIdx.x;
    int blk = blockIdx.x;              // 512 blocks: chunk*32 + bh (XCD-local)
    int chunk = blk >> 5, bh = blk & 31;
    int b = bh >> 4, h = bh & 15;
    int i = chunk * 4 + (tid >> 4);    // state row owned by this 16-lane group
    int q = tid & 15;                  // column-slice owner (4 cols)
    int jb = q * 4;
    size_t base = ((size_t)b * Tdim) * Cdim + (size_t)h * Ndim;
    const float* pa = aarr + base + jb;
    const float* pd = decay + base + jb;
    const float* pk = kt + base + jb;
    const float* pb = barr + base + jb;
    const float* pr = rt + base + jb;
    const float* pv = vt + base + i;
    float* po = wkvt + base + i;

    float S[4];
    #pragma unroll
    for (int j = 0; j < 4; ++j) S[j] = 0.f;

    Ops A, B, C, D;
    load_set(A, pa, pd, pk, pb, pr, pv);
    {
        size_t o1 = (size_t)1 * Cdim, o2 = (size_t)2 * Cdim, o3 = (size_t)3 * Cdim;
        load_set(B, pa + o1, pd + o1, pk + o1, pb + o1, pr + o1, pv + o1);
        load_set(C, pa + o2, pd + o2, pk + o2, pb + o2, pr + o2, pv + o2);
        load_set(D, pa + o3, pd + o3, pk + o3, pb + o3, pr + o3, pv + o3);
    }

    // peeled first macro-iter: no stores in queue yet -> exact waits 18..21
    {
        wkv_wait18();
        wkv_compute(S, A, po, q);
        size_t o4 = (size_t)4 * Cdim;
        load_set(A, pa + o4, pd + o4, pk + o4, pb + o4, pr + o4, pv + o4);

        wkv_wait19();
        wkv_compute(S, B, po + (size_t)1 * Cdim, q);
        size_t o5 = (size_t)5 * Cdim;
        load_set(B, pa + o5, pd + o5, pk + o5, pb + o5, pr + o5, pv + o5);

        wkv_wait20();
        wkv_compute(S, C, po + (size_t)2 * Cdim, q);
        size_t o6 = (size_t)6 * Cdim;
        load_set(C, pa + o6, pd + o6, pk + o6, pb + o6, pr + o6, pv + o6);

        wkv_wait21();
        wkv_compute(S, D, po + (size_t)3 * Cdim, q);
        size_t o7 = (size_t)7 * Cdim;
        load_set(D, pa + o7, pd + o7, pk + o7, pb + o7, pr + o7, pv + o7);
    }

    for (int t = 4; t < Tdim; t += 4) {
        wkv_wait21();
        wkv_compute(S, A, po + (size_t)t * Cdim, q);
        size_t o4 = (size_t)((t + 4 < Tdim) ? t + 4 : Tdim - 1) * Cdim;
        load_set(A, pa + o4, pd + o4, pk + o4, pb + o4, pr + o4, pv + o4);

        wkv_wait21();
        wkv_compute(S, B, po + (size_t)(t + 1) * Cdim, q);
        size_t o5 = (size_t)((t + 5 < Tdim) ? t + 5 : Tdim - 1) * Cdim;
        load_set(B, pa + o5, pd + o5, pk + o5, pb + o5, pr + o5, pv + o5);

        wkv_wait21();
        wkv_compute(S, C, po + (size_t)(t + 2) * Cdim, q);
        size_t o6 = (size_t)((t + 6 < Tdim) ? t + 6 : Tdim - 1) * Cdim;
        load_set(C, pa + o6, pd + o6, pk + o6, pb + o6, pr + o6, pv + o6);

        wkv_wait21();
        wkv_compute(S, D, po + (size_t)(t + 3) * Cdim, q);
        size_t o7 = (size_t)((t + 7 < Tdim) ? t + 7 : Tdim - 1) * Cdim;
        load_set(D, pa + o7, pd + o7, pk + o7, pb + o7, pr + o7, pv + o7);
    }
}

// ---------------------------------------------------------------------------
// E2: pt = GroupNorm(rt*wkvt)*ln_g + ln_b + ut; g16 = bf16(gt*pt)
// ---------------------------------------------------------------------------
__global__ __launch_bounds__(256) void e2_kernel(
    const float* __restrict__ rt, const float* __restrict__ wkvt,
    const float* __restrict__ ut, const __hip_bfloat16* __restrict__ gt16,
    const float* __restrict__ ln_g, const float* __restrict__ ln_b,
    __hip_bfloat16* __restrict__ g16)
{
    int gid = blockIdx.x * 4 + (threadIdx.x >> 6);
    int lane = threadIdx.x & 63;
    int h = gid % Hdim;
    size_t idx = (size_t)gid * 64 + lane;
    int c = h * 64 + lane;
    float x = rt[idx] * wkvt[idx];
    float mu = wsum64(x) * (1.f / 64.f);
    float d = x - mu;
    float var = wsum64(d * d) * (1.f / 64.f);
    float xn = d / sqrtf(var + EPS_GN);
    float pt = xn * ln_g[c] + ln_b[c] + ut[idx];
    float res = __bfloat162float(gt16[idx]) * pt;
    g16[idx] = __float2bfloat16(res);
}

// ---------------------------------------------------------------------------
extern "C" void kernel_launch(void* const* d_in, const int* in_sizes, int n_in,
                              void* d_out, int out_size, void* d_ws, size_t ws_size,
                              hipStream_t stream)
{
    (void)in_sizes; (void)n_in; (void)out_size; (void)ws_size;
    const float* xt      = (const float*)d_in[0];
    const float* v_first = (const float*)d_in[1];
    const float* tmix_r  = (const float*)d_in[2];
    const float* tmix_w  = (const float*)d_in[3];
    const float* tmix_k  = (const float*)d_in[4];
    const float* tmix_v  = (const float*)d_in[5];
    const float* tmix_a  = (const float*)d_in[6];
    const float* tmix_g  = (const float*)d_in[7];
    const float* w1 = (const float*)d_in[8];
    const float* w2 = (const float*)d_in[9];
    const float* w0 = (const float*)d_in[10];
    const float* a1 = (const float*)d_in[11];
    const float* a2 = (const float*)d_in[12];
    const float* a0 = (const float*)d_in[13];
    const float* v1 = (const float*)d_in[14];
    const float* v2 = (const float*)d_in[15];
    const float* v0 = (const float*)d_in[16];
    const float* g1 = (const float*)d_in[17];
    const float* g2 = (const float*)d_in[18];
    const float* k_k = (const float*)d_in[19];
    const float* k_a = (const float*)d_in[20];
    const float* r_k = (const float*)d_in[21];
    const float* W_r = (const float*)d_in[22];
    const float* W_k = (const float*)d_in[23];
    const float* W_v = (const float*)d_in[24];
    const float* W_o = (const float*)d_in[25];
    const float* ln_g = (const float*)d_in[26];
    const float* ln_b = (const float*)d_in[27];

    float* out = (float*)d_out;
    const size_t BTC = (size_t)Bdim * Tdim * Cdim;   // 2,097,152
    const int M = Bdim * Tdim;                        // 2048

    float* ws = (float*)d_ws;
    float* rt    = ws + 0 * BTC;
    float* kt    = ws + 1 * BTC;
    float* vraw  = ws + 2 * BTC;
    float* vt    = ws + 3 * BTC;
    float* decay = ws + 4 * BTC;
    float* aarr  = ws + 5 * BTC;
    float* barr  = ws + 6 * BTC;
    float* ut    = ws + 7 * BTC;
    float* wkv   = ws + 8 * BTC;
    __hip_bfloat16* bfa = (__hip_bfloat16*)(ws + 9 * BTC);
    __hip_bfloat16* at16 = bfa + 0 * BTC;
    __hip_bfloat16* gt16 = bfa + 1 * BTC;
    __hip_bfloat16* xr16 = bfa + 2 * BTC;
    __hip_bfloat16* xk16 = bfa + 3 * BTC;
    __hip_bfloat16* xv16 = bfa + 4 * BTC;   // reused as g16 after gemm
    __hip_bfloat16* Wb   = bfa + 5 * BTC;   // 4*CCdim = 2*BTC bf16
    // Aliased scratch (dead before their slots' writers run):
    __hip_bfloat16* Aall = (__hip_bfloat16*)decay;           // 8MB (decay written later by gemm_lr2)
    __hip_bfloat16* Wlr1 = (__hip_bfloat16*)aarr;            // (aarr written later by e1)
    __hip_bfloat16* Wl2  = Wlr1 + (size_t)384 * 2048;
    __hip_bfloat16* hcat = Wl2 + (size_t)4096 * 288;
    __hip_bfloat16* g16 = xv16;

    // prep: weights (bf16, Wlr1, Wl2) + activation lerps + Aall, one dispatch
    prep_fused<<<7552, 256, 0, stream>>>(
        W_r, W_k, W_v, W_o, w1, a1, v1, g1, w2, a2, v2, g2,
        tmix_w, tmix_a, tmix_v, tmix_g, xt, tmix_r, tmix_k,
        Wb, Wlr1, Wl2, xr16, xk16, xv16, Aall);

    // fused GEMM: z=0 lr1 (K=2048, long blocks first) + z=1..3 projections
    dim3 ggf(Cdim / 128, M / 128, 4);   // (8,16,4)
    gemm_fused<<<ggf, 256, 0, stream>>>(xr16, xk16, xv16, Aall, Wb, Wlr1,
                                        rt, kt, vraw, hcat);

    // lr2 expansion (block-diag) -> decay/at16/vt/gt16
    gemm_lr2<<<dim3(32, 16), 256, 0, stream>>>(hcat, Wl2, w0, a0, v0,
                                               decay, at16, vt, gt16);

    // E1
    e1_kernel<<<(Bdim * Tdim * Hdim) / 4, 256, 0, stream>>>(
        kt, at16, rt, vraw, vt, v_first, k_k, k_a, r_k,
        aarr, barr, ut, out + BTC);

    // WKV scan (16-way XCD-local split, all-DPP reduce, store-aware waits)
    wkv_kernel<<<512, 64, 0, stream>>>(rt, decay, kt, vt, aarr, barr, wkv);

    // E2 (writes bf16 gated output)
    e2_kernel<<<(Bdim * Tdim * Hdim) / 4, 256, 0, stream>>>(
        rt, wkv, ut, gt16, ln_g, ln_b, g16);

    // output projection (bf16 MFMA)
    dim3 gg(Cdim / 128, M / 128);
    gemm_mfma<<<gg, 256, 0, stream>>>(g16, Wb + 3 * (size_t)CCdim, out, M, Cdim, Cdim);
}

// Round 18
// 281.090 us; speedup vs baseline: 1.5131x; 1.0311x over previous
//
#include <hip/hip_runtime.h>
#include <hip/hip_bf16.h>
#include <math.h>

#define Bdim 2
#define Tdim 1024
#define Cdim 1024
#define Hdim 16
#define Ndim 64
#define CCdim (Cdim * Cdim)
#define EPS_GN 0.00064f

typedef __bf16 bf8_t __attribute__((ext_vector_type(8)));
typedef float f32x4 __attribute__((ext_vector_type(4)));
typedef float f4 __attribute__((ext_vector_type(4)));

static __device__ __forceinline__ float sigf(float x) { return 1.f / (1.f + expf(-x)); }

static __device__ __forceinline__ float wsum64(float v) {
    #pragma unroll
    for (int m = 1; m < 64; m <<= 1) v += __shfl_xor(v, m);
    return v;
}

static __device__ __forceinline__ void gload_lds16(const void* g, void* l) {
    __builtin_amdgcn_global_load_lds(
        (const __attribute__((address_space(1))) void*)g,
        (__attribute__((address_space(3))) void*)l, 16, 0, 0);
}

// 16-lane sum, ALL-DPP: quad_perm xor1 (0xB1), xor2 (0x4E),
// row_half_mirror (0x141), row_mirror (0x140). shfl_xor ~35cyc; DPP ~5-8.
static __device__ __forceinline__ float red16_dpp(float x) {
    int s1 = __builtin_amdgcn_update_dpp(0, __builtin_bit_cast(int, x),
                                         0xB1, 0xF, 0xF, true);
    float y = x + __builtin_bit_cast(float, s1);
    int s2 = __builtin_amdgcn_update_dpp(0, __builtin_bit_cast(int, y),
                                         0x4E, 0xF, 0xF, true);
    float z = y + __builtin_bit_cast(float, s2);
    int s3 = __builtin_amdgcn_update_dpp(0, __builtin_bit_cast(int, z),
                                         0x141, 0xF, 0xF, true);
    float w = z + __builtin_bit_cast(float, s3);
    int s4 = __builtin_amdgcn_update_dpp(0, __builtin_bit_cast(int, w),
                                         0x140, 0xF, 0xF, true);
    return w + __builtin_bit_cast(float, s4);
}

// ---------------------------------------------------------------------------
// prep_fused: weights (blk<6528) + activations (6528..7551) + v_first copy
// (7552..8575; independent passthrough moved out of mid-chain e1).
// ---------------------------------------------------------------------------
__global__ __launch_bounds__(256) void prep_fused(
    const float* __restrict__ W0, const float* __restrict__ W1,
    const float* __restrict__ W2, const float* __restrict__ W3,
    const float* __restrict__ w1, const float* __restrict__ a1,
    const float* __restrict__ v1, const float* __restrict__ g1,
    const float* __restrict__ w2, const float* __restrict__ a2,
    const float* __restrict__ v2, const float* __restrict__ g2,
    const float* __restrict__ mw, const float* __restrict__ ma,
    const float* __restrict__ mv, const float* __restrict__ mg,
    const float* __restrict__ xt,
    const float* __restrict__ mr, const float* __restrict__ mk,
    const float* __restrict__ vfirst,
    __hip_bfloat16* __restrict__ Wb, __hip_bfloat16* __restrict__ Wlr1,
    __hip_bfloat16* __restrict__ Wl2,
    __hip_bfloat16* __restrict__ xr16, __hip_bfloat16* __restrict__ xk16,
    __hip_bfloat16* __restrict__ xv16, __hip_bfloat16* __restrict__ Aall,
    float* __restrict__ out2)
{
    int blk = blockIdx.x;
    int tid = threadIdx.x;
    if (blk < 2048) {
        int which = blk >> 9;
        const float* src = (which == 0) ? W0 : (which == 1) ? W1 : (which == 2) ? W2 : W3;
        size_t e8 = ((size_t)(blk & 511) * 256 + tid) * 8;
        float c[8];
        *(float4*)&c[0] = ((const float4*)(src + e8))[0];
        *(float4*)&c[4] = ((const float4*)(src + e8))[1];
        __hip_bfloat16 o[8];
        #pragma unroll
        for (int j = 0; j < 8; ++j) o[j] = __float2bfloat16(c[j]);
        __hip_bfloat16* dst = Wb + (size_t)which * CCdim + e8;
        ((ushort4*)dst)[0] = *(ushort4*)&o[0];
        ((ushort4*)dst)[1] = *(ushort4*)&o[4];
    } else if (blk < 2432) {
        int n = blk - 2048;                 // 0..383
        if (n < 288) {
            const float* M1; const float* mix; int D, nl;
            if (n < 64)       { M1 = w1; mix = mw; D = 64;  nl = n; }
            else if (n < 128) { M1 = a1; mix = ma; D = 64;  nl = n - 64; }
            else if (n < 160) { M1 = v1; mix = mv; D = 32;  nl = n - 128; }
            else              { M1 = g1; mix = mg; D = 128; nl = n - 160; }
            #pragma unroll
            for (int i = 0; i < 8; ++i) {
                int kp = tid + i * 256;     // 0..2047
                int k = kp & 1023, half = kp >> 10;
                float mx = mix[k];
                float val = M1[(size_t)k * D + nl] * (half ? mx : 1.f - mx);
                Wlr1[(size_t)n * 2048 + kp] = __float2bfloat16(val);
            }
        } else {
            #pragma unroll
            for (int i = 0; i < 8; ++i)
                Wlr1[(size_t)n * 2048 + tid + i * 256] = __float2bfloat16(0.f);
        }
    } else if (blk < 6528) {
        int np = blk - 2432;                // 0..4095
        int path = np >> 10, nl = np & 1023;
        const float* M2; int off, D;
        if (path == 0)      { M2 = w2; off = 0;   D = 64; }
        else if (path == 1) { M2 = a2; off = 64;  D = 64; }
        else if (path == 2) { M2 = v2; off = 128; D = 32; }
        else                { M2 = g2; off = 160; D = 128; }
        for (int kp = tid; kp < 288; kp += 256) {
            int kl = kp - off;
            float val = (kl >= 0 && kl < D) ? M2[(size_t)kl * Cdim + nl] : 0.f;
            Wl2[(size_t)np * 288 + kp] = __float2bfloat16(val);
        }
    } else if (blk < 7552) {
        // activation prep: lerps (r,k,v) -> bf16 + Aall = [x | xprev]
        int idx8 = (blk - 6528) * 256 + tid;     // 0..262143
        int m = idx8 >> 7;
        int c8 = (idx8 & 127) * 8;
        int t = m & (Tdim - 1);
        const float* p = xt + (size_t)idx8 * 8;
        float cur[8], prv[8];
        *(float4*)&cur[0] = ((const float4*)p)[0];
        *(float4*)&cur[4] = ((const float4*)p)[1];
        if (t > 0) {
            *(float4*)&prv[0] = ((const float4*)(p - Cdim))[0];
            *(float4*)&prv[4] = ((const float4*)(p - Cdim))[1];
        } else {
            #pragma unroll
            for (int j = 0; j < 8; ++j) prv[j] = 0.f;
        }
        float mx[8];
        __hip_bfloat16 o[8];
        size_t ob = (size_t)idx8 * 8;

        *(float4*)&mx[0] = *(const float4*)(mr + c8);
        *(float4*)&mx[4] = *(const float4*)(mr + c8 + 4);
        #pragma unroll
        for (int j = 0; j < 8; ++j) o[j] = __float2bfloat16(cur[j] + (prv[j] - cur[j]) * mx[j]);
        ((ushort4*)(xr16 + ob))[0] = *(ushort4*)&o[0];
        ((ushort4*)(xr16 + ob))[1] = *(ushort4*)&o[4];

        *(float4*)&mx[0] = *(const float4*)(mk + c8);
        *(float4*)&mx[4] = *(const float4*)(mk + c8 + 4);
        #pragma unroll
        for (int j = 0; j < 8; ++j) o[j] = __float2bfloat16(cur[j] + (prv[j] - cur[j]) * mx[j]);
        ((ushort4*)(xk16 + ob))[0] = *(ushort4*)&o[0];
        ((ushort4*)(xk16 + ob))[1] = *(ushort4*)&o[4];

        *(float4*)&mx[0] = *(const float4*)(mv + c8);
        *(float4*)&mx[4] = *(const float4*)(mv + c8 + 4);
        #pragma unroll
        for (int j = 0; j < 8; ++j) o[j] = __float2bfloat16(cur[j] + (prv[j] - cur[j]) * mx[j]);
        ((ushort4*)(xv16 + ob))[0] = *(ushort4*)&o[0];
        ((ushort4*)(xv16 + ob))[1] = *(ushort4*)&o[4];

        size_t ab = (size_t)m * 2048 + c8;
        #pragma unroll
        for (int j = 0; j < 8; ++j) o[j] = __float2bfloat16(cur[j]);
        ((ushort4*)(Aall + ab))[0] = *(ushort4*)&o[0];
        ((ushort4*)(Aall + ab))[1] = *(ushort4*)&o[4];
        #pragma unroll
        for (int j = 0; j < 8; ++j) o[j] = __float2bfloat16(prv[j]);
        ((ushort4*)(Aall + ab + 1024))[0] = *(ushort4*)&o[0];
        ((ushort4*)(Aall + ab + 1024))[1] = *(ushort4*)&o[4];
    } else {
        // v_first passthrough -> out[BTC:]
        size_t e8 = ((size_t)(blk - 7552) * 256 + tid) * 8;
        float4 v0 = ((const float4*)(vfirst + e8))[0];
        float4 v1v = ((const float4*)(vfirst + e8))[1];
        ((float4*)(out2 + e8))[0] = v0;
        ((float4*)(out2 + e8))[1] = v1v;
    }
}

// ---------------------------------------------------------------------------
// gemm_fused: z=0 -> lr1 (K=2048, x<3 only); z=1..3 -> C x C projections.
// ---------------------------------------------------------------------------
__global__ __launch_bounds__(256) void gemm_fused(
    const __hip_bfloat16* __restrict__ A0, const __hip_bfloat16* __restrict__ A1,
    const __hip_bfloat16* __restrict__ A2, const __hip_bfloat16* __restrict__ Aall,
    const __hip_bfloat16* __restrict__ Wbase, const __hip_bfloat16* __restrict__ Wlr1,
    float* __restrict__ C0, float* __restrict__ C1, float* __restrict__ C2,
    __hip_bfloat16* __restrict__ H)
{
    __shared__ unsigned short At[128][32];
    __shared__ unsigned short Bt[128][32];
    int z = blockIdx.z;
    const __hip_bfloat16* A; const __hip_bfloat16* Bw;
    float* Cout = nullptr;
    int K;
    if (z == 0) {
        if (blockIdx.x >= 3) return;   // N=384: 3 column tiles
        A = Aall; Bw = Wlr1; K = 2048;
    } else {
        int zi = z - 1;
        A = (zi == 0) ? A0 : (zi == 1) ? A1 : A2;
        Bw = Wbase + (size_t)zi * CCdim;
        Cout = (zi == 0) ? C0 : (zi == 1) ? C1 : C2;
        K = Cdim;
    }
    int tid = threadIdx.x;
    int lane = tid & 63, wv = tid >> 6;
    int bm = blockIdx.y * 128, bn = blockIdx.x * 128;
    int wr = wv >> 1, wc = wv & 1;

    f32x4 acc[4][4];
    #pragma unroll
    for (int mi = 0; mi < 4; ++mi)
        #pragma unroll
        for (int ni = 0; ni < 4; ++ni)
            acc[mi][ni] = (f32x4){0.f, 0.f, 0.f, 0.f};

    int srow = wv * 16 + (lane >> 2);
    int scol = (lane & 3) * 8;
    const __hip_bfloat16* pa0 = A + (size_t)(bm + srow) * K + scol;
    const __hip_bfloat16* pa1 = A + (size_t)(bm + 64 + srow) * K + scol;
    const __hip_bfloat16* pb0 = Bw + (size_t)(bn + srow) * K + scol;
    const __hip_bfloat16* pb1 = Bw + (size_t)(bn + 64 + srow) * K + scol;
    char* At_b = (char*)&At[0][0] + wv * 1024;
    char* Bt_b = (char*)&Bt[0][0] + wv * 1024;

    for (int k0 = 0; k0 < K; k0 += 32) {
        gload_lds16(pa0 + k0, At_b);
        gload_lds16(pa1 + k0, At_b + 4096);
        gload_lds16(pb0 + k0, Bt_b);
        gload_lds16(pb1 + k0, Bt_b + 4096);
        __syncthreads();

        bf8_t af[4], bfr[4];
        #pragma unroll
        for (int mi = 0; mi < 4; ++mi)
            af[mi] = *(const bf8_t*)((const char*)&At[0][0] +
                     (wr * 64 + mi * 16 + (lane & 15)) * 64 + (lane >> 4) * 16);
        #pragma unroll
        for (int ni = 0; ni < 4; ++ni)
            bfr[ni] = *(const bf8_t*)((const char*)&Bt[0][0] +
                     (wc * 64 + ni * 16 + (lane & 15)) * 64 + (lane >> 4) * 16);
        #pragma unroll
        for (int mi = 0; mi < 4; ++mi)
            #pragma unroll
            for (int ni = 0; ni < 4; ++ni)
                acc[mi][ni] = __builtin_amdgcn_mfma_f32_16x16x32_bf16(
                    af[mi], bfr[ni], acc[mi][ni], 0, 0, 0);
        __syncthreads();
    }

    if (z == 0) {
        #pragma unroll
        for (int mi = 0; mi < 4; ++mi) {
            int r0 = bm + wr * 64 + mi * 16 + (lane >> 4) * 4;
            #pragma unroll
            for (int ni = 0; ni < 4; ++ni) {
                int c0 = bn + wc * 64 + ni * 16 + (lane & 15);
                if (c0 < 288) {
                    #pragma unroll
                    for (int j = 0; j < 4; ++j) {
                        float v = acc[mi][ni][j];
                        if (c0 < 64) v = tanhf(v);
                        else if (c0 >= 160) v = sigf(v);
                        H[(size_t)(r0 + j) * 288 + c0] = __float2bfloat16(v);
                    }
                }
            }
        }
    } else {
        #pragma unroll
        for (int mi = 0; mi < 4; ++mi) {
            int r0 = bm + wr * 64 + mi * 16 + (lane >> 4) * 4;
            #pragma unroll
            for (int ni = 0; ni < 4; ++ni) {
                int c0 = bn + wc * 64 + ni * 16 + (lane & 15);
                #pragma unroll
                for (int j = 0; j < 4; ++j)
                    Cout[(size_t)(r0 + j) * Cdim + c0] = acc[mi][ni][j];
            }
        }
    }
}

// ---------------------------------------------------------------------------
// gemm_o64: output projection with 128x64 tiles -> grid (16,16) = 256
// blocks = full chip (was 128 blocks / half chip). 4 waves 2x2; wave does
// 64x32 via acc[4][2]; 3 staging loads/lane; 8 MFMA per k-step.
// ---------------------------------------------------------------------------
__global__ __launch_bounds__(256) void gemm_o64(
    const __hip_bfloat16* __restrict__ A, const __hip_bfloat16* __restrict__ Bw,
    float* __restrict__ Cout)
{
    const int K = Cdim, N = Cdim;
    __shared__ unsigned short At[128][32];
    __shared__ unsigned short Bt[64][32];
    int tid = threadIdx.x;
    int lane = tid & 63, wv = tid >> 6;
    int bm = blockIdx.y * 128, bn = blockIdx.x * 64;
    int wr = wv >> 1, wc = wv & 1;

    f32x4 acc[4][2];
    #pragma unroll
    for (int mi = 0; mi < 4; ++mi)
        #pragma unroll
        for (int ni = 0; ni < 2; ++ni)
            acc[mi][ni] = (f32x4){0.f, 0.f, 0.f, 0.f};

    int srow = wv * 16 + (lane >> 2);   // 0..63
    int scol = (lane & 3) * 8;
    const __hip_bfloat16* pa0 = A + (size_t)(bm + srow) * K + scol;
    const __hip_bfloat16* pa1 = A + (size_t)(bm + 64 + srow) * K + scol;
    const __hip_bfloat16* pb0 = Bw + (size_t)(bn + srow) * K + scol;
    char* At_b = (char*)&At[0][0] + wv * 1024;
    char* Bt_b = (char*)&Bt[0][0] + wv * 1024;

    for (int k0 = 0; k0 < K; k0 += 32) {
        gload_lds16(pa0 + k0, At_b);
        gload_lds16(pa1 + k0, At_b + 4096);
        gload_lds16(pb0 + k0, Bt_b);
        __syncthreads();

        bf8_t af[4], bfr[2];
        #pragma unroll
        for (int mi = 0; mi < 4; ++mi)
            af[mi] = *(const bf8_t*)((const char*)&At[0][0] +
                     (wr * 64 + mi * 16 + (lane & 15)) * 64 + (lane >> 4) * 16);
        #pragma unroll
        for (int ni = 0; ni < 2; ++ni)
            bfr[ni] = *(const bf8_t*)((const char*)&Bt[0][0] +
                     (wc * 32 + ni * 16 + (lane & 15)) * 64 + (lane >> 4) * 16);
        #pragma unroll
        for (int mi = 0; mi < 4; ++mi)
            #pragma unroll
            for (int ni = 0; ni < 2; ++ni)
                acc[mi][ni] = __builtin_amdgcn_mfma_f32_16x16x32_bf16(
                    af[mi], bfr[ni], acc[mi][ni], 0, 0, 0);
        __syncthreads();
    }

    #pragma unroll
    for (int mi = 0; mi < 4; ++mi) {
        int r0 = bm + wr * 64 + mi * 16 + (lane >> 4) * 4;
        #pragma unroll
        for (int ni = 0; ni < 2; ++ni) {
            int c0 = bn + wc * 32 + ni * 16 + (lane & 15);
            #pragma unroll
            for (int j = 0; j < 4; ++j)
                Cout[(size_t)(r0 + j) * N + c0] = acc[mi][ni][j];
        }
    }
}

// ---------------------------------------------------------------------------
// gemm_lr2: block-diag expansion, epilogue demux (unchanged).
// ---------------------------------------------------------------------------
__global__ __launch_bounds__(256) void gemm_lr2(
    const __hip_bfloat16* __restrict__ H, const __hip_bfloat16* __restrict__ W,
    const float* __restrict__ w0, const float* __restrict__ a0,
    const float* __restrict__ v0,
    float* __restrict__ decay, __hip_bfloat16* __restrict__ at16,
    float* __restrict__ vt, __hip_bfloat16* __restrict__ gt16)
{
    const int K = 288;
    __shared__ unsigned short At[128][32];
    __shared__ unsigned short Bt[128][32];
    int tid = threadIdx.x;
    int lane = tid & 63, wv = tid >> 6;
    int bm = blockIdx.y * 128, bn = blockIdx.x * 128;
    int wr = wv >> 1, wc = wv & 1;

    f32x4 acc[4][4];
    #pragma unroll
    for (int mi = 0; mi < 4; ++mi)
        #pragma unroll
        for (int ni = 0; ni < 4; ++ni)
            acc[mi][ni] = (f32x4){0.f, 0.f, 0.f, 0.f};

    int srow = wv * 16 + (lane >> 2);
    int scol = (lane & 3) * 8;
    const __hip_bfloat16* pa0 = H + (size_t)(bm + srow) * K + scol;
    const __hip_bfloat16* pa1 = H + (size_t)(bm + 64 + srow) * K + scol;
    const __hip_bfloat16* pb0 = W + (size_t)(bn + srow) * K + scol;
    const __hip_bfloat16* pb1 = W + (size_t)(bn + 64 + srow) * K + scol;
    char* At_b = (char*)&At[0][0] + wv * 1024;
    char* Bt_b = (char*)&Bt[0][0] + wv * 1024;

    for (int k0 = 0; k0 < K; k0 += 32) {
        gload_lds16(pa0 + k0, At_b);
        gload_lds16(pa1 + k0, At_b + 4096);
        gload_lds16(pb0 + k0, Bt_b);
        gload_lds16(pb1 + k0, Bt_b + 4096);
        __syncthreads();

        bf8_t af[4], bfr[4];
        #pragma unroll
        for (int mi = 0; mi < 4; ++mi)
            af[mi] = *(const bf8_t*)((const char*)&At[0][0] +
                     (wr * 64 + mi * 16 + (lane & 15)) * 64 + (lane >> 4) * 16);
        #pragma unroll
        for (int ni = 0; ni < 4; ++ni)
            bfr[ni] = *(const bf8_t*)((const char*)&Bt[0][0] +
                     (wc * 64 + ni * 16 + (lane & 15)) * 64 + (lane >> 4) * 16);
        #pragma unroll
        for (int mi = 0; mi < 4; ++mi)
            #pragma unroll
            for (int ni = 0; ni < 4; ++ni)
                acc[mi][ni] = __builtin_amdgcn_mfma_f32_16x16x32_bf16(
                    af[mi], bfr[ni], acc[mi][ni], 0, 0, 0);
        __syncthreads();
    }

    #pragma unroll
    for (int mi = 0; mi < 4; ++mi) {
        int r0 = bm + wr * 64 + mi * 16 + (lane >> 4) * 4;
        #pragma unroll
        for (int ni = 0; ni < 4; ++ni) {
            int np = bn + wc * 64 + ni * 16 + (lane & 15);
            int path = np >> 10, nl = np & 1023;
            #pragma unroll
            for (int j = 0; j < 4; ++j) {
                float v = acc[mi][ni][j];
                size_t oi = (size_t)(r0 + j) * Cdim + nl;
                if (path == 0)      decay[oi] = sigf(v + w0[nl]) * 0.60653065971263342f;
                else if (path == 1) at16[oi] = __float2bfloat16(sigf(v + a0[nl]));
                else if (path == 2) vt[oi] = sigf(v + v0[nl]);
                else                gt16[oi] = __float2bfloat16(v);
            }
        }
    }
}

// ---------------------------------------------------------------------------
// E1: kk-normalize -> aarr=-kkn, barr=kkn*at; ut. (v_first copy moved to prep)
// ---------------------------------------------------------------------------
__global__ __launch_bounds__(256) void e1_kernel(
    const float* __restrict__ kt, const __hip_bfloat16* __restrict__ at16,
    const float* __restrict__ rt, const float* __restrict__ vraw,
    const float* __restrict__ vt, const float* __restrict__ vfirst,
    const float* __restrict__ k_k, const float* __restrict__ k_a,
    const float* __restrict__ r_k,
    float* __restrict__ aarr, float* __restrict__ barr,
    float* __restrict__ ut)
{
    int gid = blockIdx.x * 4 + (threadIdx.x >> 6);
    int lane = threadIdx.x & 63;
    int h = gid % Hdim;
    size_t idx = (size_t)gid * 64 + lane;
    int c = h * 64 + lane;
    float ktv = kt[idx];
    float atv = __bfloat162float(at16[idx]);
    float kk = ktv * k_k[c];
    float ss = wsum64(kk * kk);
    float norm = sqrtf(ss);
    float kkn = kk / fmaxf(norm, 1e-12f);
    aarr[idx] = -kkn;
    barr[idx] = kkn * atv;
    float kmix = ktv * (1.f + (atv - 1.f) * k_a[c]);
    float rv = rt[idx];
    float dot = wsum64(rv * kmix * r_k[c]);
    float vm = vraw[idx];
    float vf = vfirst[idx];
    vm = vm + (vf - vm) * vt[idx];
    ut[idx] = dot * vm;
}

// ---------------------------------------------------------------------------
// WKV scan v10 (EXACT R16 version — known-good): 16-way XCD-local split,
// all-DPP reduce, 4-deep asm pipeline, store-aware counted waits
// (peel 18..21, steady 21).
// ---------------------------------------------------------------------------
struct Ops { f4 a, d, k, b, r; float vi; };

static __device__ __forceinline__ void load_set(
    Ops& s, const float* pa, const float* pd, const float* pk,
    const float* pb, const float* pr, const float* pv)
{
    asm volatile(
        "global_load_dwordx4 %0, %6, off\n\t"
        "global_load_dword   %5, %11, off\n\t"
        "global_load_dwordx4 %1, %7, off\n\t"
        "global_load_dwordx4 %2, %8, off\n\t"
        "global_load_dwordx4 %3, %9, off\n\t"
        "global_load_dwordx4 %4, %10, off"
        : "=&v"(s.a), "=&v"(s.d), "=&v"(s.k), "=&v"(s.b), "=&v"(s.r), "=&v"(s.vi)
        : "v"(pa), "v"(pd), "v"(pk), "v"(pb), "v"(pr), "v"(pv));
}

static __device__ __forceinline__ void wkv_wait18() {
    asm volatile("s_waitcnt vmcnt(18)" ::: "memory");
    __builtin_amdgcn_sched_barrier(0);
}
static __device__ __forceinline__ void wkv_wait19() {
    asm volatile("s_waitcnt vmcnt(19)" ::: "memory");
    __builtin_amdgcn_sched_barrier(0);
}
static __device__ __forceinline__ void wkv_wait20() {
    asm volatile("s_waitcnt vmcnt(20)" ::: "memory");
    __builtin_amdgcn_sched_barrier(0);
}
static __device__ __forceinline__ void wkv_wait21() {
    asm volatile("s_waitcnt vmcnt(21)" ::: "memory");
    __builtin_amdgcn_sched_barrier(0);
}

static __device__ __forceinline__ void wkv_compute(
    float S[4], const Ops& o, float* po, int q)
{
    float s0 = S[0] * o.a.x, s1 = S[1] * o.a.y;
    float s2 = S[2] * o.a.z, s3 = S[3] * o.a.w;
    float sp = red16_dpp((s0 + s1) + (s2 + s3));

    S[0] = fmaf(S[0], o.d.x, fmaf(sp, o.b.x, o.vi * o.k.x));
    S[1] = fmaf(S[1], o.d.y, fmaf(sp, o.b.y, o.vi * o.k.y));
    S[2] = fmaf(S[2], o.d.z, fmaf(sp, o.b.z, o.vi * o.k.z));
    S[3] = fmaf(S[3], o.d.w, fmaf(sp, o.b.w, o.vi * o.k.w));

    float o0 = S[0] * o.r.x, o1 = S[1] * o.r.y;
    float o2 = S[2] * o.r.z, o3 = S[3] * o.r.w;
    float op = red16_dpp((o0 + o1) + (o2 + o3));
    if (q == 0) *po = op;
}

__global__ __launch_bounds__(64, 1) void wkv_kernel(
    const float* __restrict__ rt, const float* __restrict__ decay,
    const float* __restrict__ kt, const float* __restrict__ vt,
    const float* __restrict__ aarr, const float* __restrict__ barr,
    float* __restrict__ wkvt)
{
    int tid = threadIdx.x;
    int blk = blockIdx.x;              // 512 blocks: chunk*32 + bh (XCD-local)
    int chunk = blk >> 5, bh = blk & 31;
    int b = bh >> 4, h = bh & 15;
    int i = chunk * 4 + (tid >> 4);    // state row owned by this 16-lane group
    int q = tid & 15;                  // column-slice owner (4 cols)
    int jb = q * 4;
    size_t base = ((size_t)b * Tdim) * Cdim + (size_t)h * Ndim;
    const float* pa = aarr + base + jb;
    const float* pd = decay + base + jb;
    const float* pk = kt + base + jb;
    const float* pb = barr + base + jb;
    const float* pr = rt + base + jb;
    const float* pv = vt + base + i;
    float* po = wkvt + base + i;

    float S[4];
    #pragma unroll
    for (int j = 0; j < 4; ++j) S[j] = 0.f;

    Ops A, B, C, D;
    load_set(A, pa, pd, pk, pb, pr, pv);
    {
        size_t o1 = (size_t)1 * Cdim, o2 = (size_t)2 * Cdim, o3 = (size_t)3 * Cdim;
        load_set(B, pa + o1, pd + o1, pk + o1, pb + o1, pr + o1, pv + o1);
        load_set(C, pa + o2, pd + o2, pk + o2, pb + o2, pr + o2, pv + o2);
        load_set(D, pa + o3, pd + o3, pk + o3, pb + o3, pr + o3, pv + o3);
    }

    // peeled first macro-iter: no stores in queue yet -> exact waits 18..21
    {
        wkv_wait18();
        wkv_compute(S, A, po, q);
        size_t o4 = (size_t)4 * Cdim;
        load_set(A, pa + o4, pd + o4, pk + o4, pb + o4, pr + o4, pv + o4);

        wkv_wait19();
        wkv_compute(S, B, po + (size_t)1 * Cdim, q);
        size_t o5 = (size_t)5 * Cdim;
        load_set(B, pa + o5, pd + o5, pk + o5, pb + o5, pr + o5, pv + o5);

        wkv_wait20();
        wkv_compute(S, C, po + (size_t)2 * Cdim, q);
        size_t o6 = (size_t)6 * Cdim;
        load_set(C, pa + o6, pd + o6, pk + o6, pb + o6, pr + o6, pv + o6);

        wkv_wait21();
        wkv_compute(S, D, po + (size_t)3 * Cdim, q);
        size_t o7 = (size_t)7 * Cdim;
        load_set(D, pa + o7, pd + o7, pk + o7, pb + o7, pr + o7, pv + o7);
    }

    for (int t = 4; t < Tdim; t += 4) {
        wkv_wait21();
        wkv_compute(S, A, po + (size_t)t * Cdim, q);
        size_t o4 = (size_t)((t + 4 < Tdim) ? t + 4 : Tdim - 1) * Cdim;
        load_set(A, pa + o4, pd + o4, pk + o4, pb + o4, pr + o4, pv + o4);

        wkv_wait21();
        wkv_compute(S, B, po + (size_t)(t + 1) * Cdim, q);
        size_t o5 = (size_t)((t + 5 < Tdim) ? t + 5 : Tdim - 1) * Cdim;
        load_set(B, pa + o5, pd + o5, pk + o5, pb + o5, pr + o5, pv + o5);

        wkv_wait21();
        wkv_compute(S, C, po + (size_t)(t + 2) * Cdim, q);
        size_t o6 = (size_t)((t + 6 < Tdim) ? t + 6 : Tdim - 1) * Cdim;
        load_set(C, pa + o6, pd + o6, pk + o6, pb + o6, pr + o6, pv + o6);

        wkv_wait21();
        wkv_compute(S, D, po + (size_t)(t + 3) * Cdim, q);
        size_t o7 = (size_t)((t + 7 < Tdim) ? t + 7 : Tdim - 1) * Cdim;
        load_set(D, pa + o7, pd + o7, pk + o7, pb + o7, pr + o7, pv + o7);
    }
}

// ---------------------------------------------------------------------------
// E2: pt = GroupNorm(rt*wkvt)*ln_g + ln_b + ut; g16 = bf16(gt*pt)
// ---------------------------------------------------------------------------
__global__ __launch_bounds__(256) void e2_kernel(
    const float* __restrict__ rt, const float* __restrict__ wkvt,
    const float* __restrict__ ut, const __hip_bfloat16* __restrict__ gt16,
    const float* __restrict__ ln_g, const float* __restrict__ ln_b,
    __hip_bfloat16* __restrict__ g16)
{
    int gid = blockIdx.x * 4 + (threadIdx.x >> 6);
    int lane = threadIdx.x & 63;
    int h = gid % Hdim;
    size_t idx = (size_t)gid * 64 + lane;
    int c = h * 64 + lane;
    float x = rt[idx] * wkvt[idx];
    float mu = wsum64(x) * (1.f / 64.f);
    float d = x - mu;
    float var = wsum64(d * d) * (1.f / 64.f);
    float xn = d / sqrtf(var + EPS_GN);
    float pt = xn * ln_g[c] + ln_b[c] + ut[idx];
    float res = __bfloat162float(gt16[idx]) * pt;
    g16[idx] = __float2bfloat16(res);
}

// ---------------------------------------------------------------------------
extern "C" void kernel_launch(void* const* d_in, const int* in_sizes, int n_in,
                              void* d_out, int out_size, void* d_ws, size_t ws_size,
                              hipStream_t stream)
{
    (void)in_sizes; (void)n_in; (void)out_size; (void)ws_size;
    const float* xt      = (const float*)d_in[0];
    const float* v_first = (const float*)d_in[1];
    const float* tmix_r  = (const float*)d_in[2];
    const float* tmix_w  = (const float*)d_in[3];
    const float* tmix_k  = (const float*)d_in[4];
    const float* tmix_v  = (const float*)d_in[5];
    const float* tmix_a  = (const float*)d_in[6];
    const float* tmix_g  = (const float*)d_in[7];
    const float* w1 = (const float*)d_in[8];
    const float* w2 = (const float*)d_in[9];
    const float* w0 = (const float*)d_in[10];
    const float* a1 = (const float*)d_in[11];
    const float* a2 = (const float*)d_in[12];
    const float* a0 = (const float*)d_in[13];
    const float* v1 = (const float*)d_in[14];
    const float* v2 = (const float*)d_in[15];
    const float* v0 = (const float*)d_in[16];
    const float* g1 = (const float*)d_in[17];
    const float* g2 = (const float*)d_in[18];
    const float* k_k = (const float*)d_in[19];
    const float* k_a = (const float*)d_in[20];
    const float* r_k = (const float*)d_in[21];
    const float* W_r = (const float*)d_in[22];
    const float* W_k = (const float*)d_in[23];
    const float* W_v = (const float*)d_in[24];
    const float* W_o = (const float*)d_in[25];
    const float* ln_g = (const float*)d_in[26];
    const float* ln_b = (const float*)d_in[27];

    float* out = (float*)d_out;
    const size_t BTC = (size_t)Bdim * Tdim * Cdim;   // 2,097,152
    const int M = Bdim * Tdim;                        // 2048

    float* ws = (float*)d_ws;
    float* rt    = ws + 0 * BTC;
    float* kt    = ws + 1 * BTC;
    float* vraw  = ws + 2 * BTC;
    float* vt    = ws + 3 * BTC;
    float* decay = ws + 4 * BTC;
    float* aarr  = ws + 5 * BTC;
    float* barr  = ws + 6 * BTC;
    float* ut    = ws + 7 * BTC;
    float* wkv   = ws + 8 * BTC;
    __hip_bfloat16* bfa = (__hip_bfloat16*)(ws + 9 * BTC);
    __hip_bfloat16* at16 = bfa + 0 * BTC;
    __hip_bfloat16* gt16 = bfa + 1 * BTC;
    __hip_bfloat16* xr16 = bfa + 2 * BTC;
    __hip_bfloat16* xk16 = bfa + 3 * BTC;
    __hip_bfloat16* xv16 = bfa + 4 * BTC;   // reused as g16 after gemm
    __hip_bfloat16* Wb   = bfa + 5 * BTC;   // 4*CCdim = 2*BTC bf16
    // Aliased scratch (dead before their slots' writers run):
    __hip_bfloat16* Aall = (__hip_bfloat16*)decay;           // 8MB (decay written later by gemm_lr2)
    __hip_bfloat16* Wlr1 = (__hip_bfloat16*)aarr;            // (aarr written later by e1)
    __hip_bfloat16* Wl2  = Wlr1 + (size_t)384 * 2048;
    __hip_bfloat16* hcat = Wl2 + (size_t)4096 * 288;
    __hip_bfloat16* g16 = xv16;

    // prep: weights + activation lerps + Aall + v_first copy, one dispatch
    prep_fused<<<8576, 256, 0, stream>>>(
        W_r, W_k, W_v, W_o, w1, a1, v1, g1, w2, a2, v2, g2,
        tmix_w, tmix_a, tmix_v, tmix_g, xt, tmix_r, tmix_k, v_first,
        Wb, Wlr1, Wl2, xr16, xk16, xv16, Aall, out + BTC);

    // fused GEMM: z=0 lr1 (K=2048, long blocks first) + z=1..3 projections
    dim3 ggf(Cdim / 128, M / 128, 4);   // (8,16,4)
    gemm_fused<<<ggf, 256, 0, stream>>>(xr16, xk16, xv16, Aall, Wb, Wlr1,
                                        rt, kt, vraw, hcat);

    // lr2 expansion (block-diag) -> decay/at16/vt/gt16
    gemm_lr2<<<dim3(32, 16), 256, 0, stream>>>(hcat, Wl2, w0, a0, v0,
                                               decay, at16, vt, gt16);

    // E1
    e1_kernel<<<(Bdim * Tdim * Hdim) / 4, 256, 0, stream>>>(
        kt, at16, rt, vraw, vt, v_first, k_k, k_a, r_k,
        aarr, barr, ut);

    // WKV scan (R16 known-good version)
    wkv_kernel<<<512, 64, 0, stream>>>(rt, decay, kt, vt, aarr, barr, wkv);

    // E2 (writes bf16 gated output)
    e2_kernel<<<(Bdim * Tdim * Hdim) / 4, 256, 0, stream>>>(
        rt, wkv, ut, gt16, ln_g, ln_b, g16);

    // output projection (full-chip 128x64 tiles)
    gemm_o64<<<dim3(Cdim / 64, M / 128), 256, 0, stream>>>(
        g16, Wb + 3 * (size_t)CCdim, out);
}

// Round 19
// 275.490 us; speedup vs baseline: 1.5438x; 1.0203x over previous
//
#include <hip/hip_runtime.h>
#include <hip/hip_bf16.h>
#include <math.h>

#define Bdim 2
#define Tdim 1024
#define Cdim 1024
#define Hdim 16
#define Ndim 64
#define CCdim (Cdim * Cdim)
#define EPS_GN 0.00064f

typedef __bf16 bf8_t __attribute__((ext_vector_type(8)));
typedef float f32x4 __attribute__((ext_vector_type(4)));
typedef float f4 __attribute__((ext_vector_type(4)));

static __device__ __forceinline__ float sigf(float x) { return 1.f / (1.f + expf(-x)); }

static __device__ __forceinline__ float wsum64(float v) {
    #pragma unroll
    for (int m = 1; m < 64; m <<= 1) v += __shfl_xor(v, m);
    return v;
}

static __device__ __forceinline__ void gload_lds16(const void* g, void* l) {
    __builtin_amdgcn_global_load_lds(
        (const __attribute__((address_space(1))) void*)g,
        (__attribute__((address_space(3))) void*)l, 16, 0, 0);
}

// 16-lane sum, ALL-DPP: quad_perm xor1 (0xB1), xor2 (0x4E),
// row_half_mirror (0x141), row_mirror (0x140). shfl_xor ~35cyc; DPP ~5-8.
static __device__ __forceinline__ float red16_dpp(float x) {
    int s1 = __builtin_amdgcn_update_dpp(0, __builtin_bit_cast(int, x),
                                         0xB1, 0xF, 0xF, true);
    float y = x + __builtin_bit_cast(float, s1);
    int s2 = __builtin_amdgcn_update_dpp(0, __builtin_bit_cast(int, y),
                                         0x4E, 0xF, 0xF, true);
    float z = y + __builtin_bit_cast(float, s2);
    int s3 = __builtin_amdgcn_update_dpp(0, __builtin_bit_cast(int, z),
                                         0x141, 0xF, 0xF, true);
    float w = z + __builtin_bit_cast(float, s3);
    int s4 = __builtin_amdgcn_update_dpp(0, __builtin_bit_cast(int, w),
                                         0x140, 0xF, 0xF, true);
    return w + __builtin_bit_cast(float, s4);
}

// ---------------------------------------------------------------------------
// prep_fused: weights (blk<6528) + activations (6528..7551) + v_first copy
// (7552..8575). Wl2 now stored COMPACT per path: [1024][D], offsets
// {0, 65536, 131072, 163840} (D = 64,64,32,128).
// ---------------------------------------------------------------------------
__global__ __launch_bounds__(256) void prep_fused(
    const float* __restrict__ W0, const float* __restrict__ W1,
    const float* __restrict__ W2, const float* __restrict__ W3,
    const float* __restrict__ w1, const float* __restrict__ a1,
    const float* __restrict__ v1, const float* __restrict__ g1,
    const float* __restrict__ w2, const float* __restrict__ a2,
    const float* __restrict__ v2, const float* __restrict__ g2,
    const float* __restrict__ mw, const float* __restrict__ ma,
    const float* __restrict__ mv, const float* __restrict__ mg,
    const float* __restrict__ xt,
    const float* __restrict__ mr, const float* __restrict__ mk,
    const float* __restrict__ vfirst,
    __hip_bfloat16* __restrict__ Wb, __hip_bfloat16* __restrict__ Wlr1,
    __hip_bfloat16* __restrict__ Wl2,
    __hip_bfloat16* __restrict__ xr16, __hip_bfloat16* __restrict__ xk16,
    __hip_bfloat16* __restrict__ xv16, __hip_bfloat16* __restrict__ Aall,
    float* __restrict__ out2)
{
    int blk = blockIdx.x;
    int tid = threadIdx.x;
    if (blk < 2048) {
        int which = blk >> 9;
        const float* src = (which == 0) ? W0 : (which == 1) ? W1 : (which == 2) ? W2 : W3;
        size_t e8 = ((size_t)(blk & 511) * 256 + tid) * 8;
        float c[8];
        *(float4*)&c[0] = ((const float4*)(src + e8))[0];
        *(float4*)&c[4] = ((const float4*)(src + e8))[1];
        __hip_bfloat16 o[8];
        #pragma unroll
        for (int j = 0; j < 8; ++j) o[j] = __float2bfloat16(c[j]);
        __hip_bfloat16* dst = Wb + (size_t)which * CCdim + e8;
        ((ushort4*)dst)[0] = *(ushort4*)&o[0];
        ((ushort4*)dst)[1] = *(ushort4*)&o[4];
    } else if (blk < 2432) {
        int n = blk - 2048;                 // 0..383
        if (n < 288) {
            const float* M1; const float* mix; int D, nl;
            if (n < 64)       { M1 = w1; mix = mw; D = 64;  nl = n; }
            else if (n < 128) { M1 = a1; mix = ma; D = 64;  nl = n - 64; }
            else if (n < 160) { M1 = v1; mix = mv; D = 32;  nl = n - 128; }
            else              { M1 = g1; mix = mg; D = 128; nl = n - 160; }
            #pragma unroll
            for (int i = 0; i < 8; ++i) {
                int kp = tid + i * 256;     // 0..2047
                int k = kp & 1023, half = kp >> 10;
                float mx = mix[k];
                float val = M1[(size_t)k * D + nl] * (half ? mx : 1.f - mx);
                Wlr1[(size_t)n * 2048 + kp] = __float2bfloat16(val);
            }
        } else {
            #pragma unroll
            for (int i = 0; i < 8; ++i)
                Wlr1[(size_t)n * 2048 + tid + i * 256] = __float2bfloat16(0.f);
        }
    } else if (blk < 6528) {
        int np = blk - 2432;                // 0..4095
        int path = np >> 10, nl = np & 1023;
        const float* M2; int D; size_t woff;
        if (path == 0)      { M2 = w2; D = 64;  woff = 0; }
        else if (path == 1) { M2 = a2; D = 64;  woff = 65536; }
        else if (path == 2) { M2 = v2; D = 32;  woff = 131072; }
        else                { M2 = g2; D = 128; woff = 163840; }
        for (int kl = tid; kl < D; kl += 256)
            Wl2[woff + (size_t)nl * D + kl] =
                __float2bfloat16(M2[(size_t)kl * Cdim + nl]);
    } else if (blk < 7552) {
        // activation prep: lerps (r,k,v) -> bf16 + Aall = [x | xprev]
        int idx8 = (blk - 6528) * 256 + tid;     // 0..262143
        int m = idx8 >> 7;
        int c8 = (idx8 & 127) * 8;
        int t = m & (Tdim - 1);
        const float* p = xt + (size_t)idx8 * 8;
        float cur[8], prv[8];
        *(float4*)&cur[0] = ((const float4*)p)[0];
        *(float4*)&cur[4] = ((const float4*)p)[1];
        if (t > 0) {
            *(float4*)&prv[0] = ((const float4*)(p - Cdim))[0];
            *(float4*)&prv[4] = ((const float4*)(p - Cdim))[1];
        } else {
            #pragma unroll
            for (int j = 0; j < 8; ++j) prv[j] = 0.f;
        }
        float mx[8];
        __hip_bfloat16 o[8];
        size_t ob = (size_t)idx8 * 8;

        *(float4*)&mx[0] = *(const float4*)(mr + c8);
        *(float4*)&mx[4] = *(const float4*)(mr + c8 + 4);
        #pragma unroll
        for (int j = 0; j < 8; ++j) o[j] = __float2bfloat16(cur[j] + (prv[j] - cur[j]) * mx[j]);
        ((ushort4*)(xr16 + ob))[0] = *(ushort4*)&o[0];
        ((ushort4*)(xr16 + ob))[1] = *(ushort4*)&o[4];

        *(float4*)&mx[0] = *(const float4*)(mk + c8);
        *(float4*)&mx[4] = *(const float4*)(mk + c8 + 4);
        #pragma unroll
        for (int j = 0; j < 8; ++j) o[j] = __float2bfloat16(cur[j] + (prv[j] - cur[j]) * mx[j]);
        ((ushort4*)(xk16 + ob))[0] = *(ushort4*)&o[0];
        ((ushort4*)(xk16 + ob))[1] = *(ushort4*)&o[4];

        *(float4*)&mx[0] = *(const float4*)(mv + c8);
        *(float4*)&mx[4] = *(const float4*)(mv + c8 + 4);
        #pragma unroll
        for (int j = 0; j < 8; ++j) o[j] = __float2bfloat16(cur[j] + (prv[j] - cur[j]) * mx[j]);
        ((ushort4*)(xv16 + ob))[0] = *(ushort4*)&o[0];
        ((ushort4*)(xv16 + ob))[1] = *(ushort4*)&o[4];

        size_t ab = (size_t)m * 2048 + c8;
        #pragma unroll
        for (int j = 0; j < 8; ++j) o[j] = __float2bfloat16(cur[j]);
        ((ushort4*)(Aall + ab))[0] = *(ushort4*)&o[0];
        ((ushort4*)(Aall + ab))[1] = *(ushort4*)&o[4];
        #pragma unroll
        for (int j = 0; j < 8; ++j) o[j] = __float2bfloat16(prv[j]);
        ((ushort4*)(Aall + ab + 1024))[0] = *(ushort4*)&o[0];
        ((ushort4*)(Aall + ab + 1024))[1] = *(ushort4*)&o[4];
    } else {
        // v_first passthrough -> out[BTC:]
        size_t e8 = ((size_t)(blk - 7552) * 256 + tid) * 8;
        float4 v0 = ((const float4*)(vfirst + e8))[0];
        float4 v1v = ((const float4*)(vfirst + e8))[1];
        ((float4*)(out2 + e8))[0] = v0;
        ((float4*)(out2 + e8))[1] = v1v;
    }
}

// ---------------------------------------------------------------------------
// gemm_fused: z=0 -> lr1 (K=2048, x<3 only); z=1..3 -> C x C projections.
// ---------------------------------------------------------------------------
__global__ __launch_bounds__(256) void gemm_fused(
    const __hip_bfloat16* __restrict__ A0, const __hip_bfloat16* __restrict__ A1,
    const __hip_bfloat16* __restrict__ A2, const __hip_bfloat16* __restrict__ Aall,
    const __hip_bfloat16* __restrict__ Wbase, const __hip_bfloat16* __restrict__ Wlr1,
    float* __restrict__ C0, float* __restrict__ C1, float* __restrict__ C2,
    __hip_bfloat16* __restrict__ H)
{
    __shared__ unsigned short At[128][32];
    __shared__ unsigned short Bt[128][32];
    int z = blockIdx.z;
    const __hip_bfloat16* A; const __hip_bfloat16* Bw;
    float* Cout = nullptr;
    int K;
    if (z == 0) {
        if (blockIdx.x >= 3) return;   // N=384: 3 column tiles
        A = Aall; Bw = Wlr1; K = 2048;
    } else {
        int zi = z - 1;
        A = (zi == 0) ? A0 : (zi == 1) ? A1 : A2;
        Bw = Wbase + (size_t)zi * CCdim;
        Cout = (zi == 0) ? C0 : (zi == 1) ? C1 : C2;
        K = Cdim;
    }
    int tid = threadIdx.x;
    int lane = tid & 63, wv = tid >> 6;
    int bm = blockIdx.y * 128, bn = blockIdx.x * 128;
    int wr = wv >> 1, wc = wv & 1;

    f32x4 acc[4][4];
    #pragma unroll
    for (int mi = 0; mi < 4; ++mi)
        #pragma unroll
        for (int ni = 0; ni < 4; ++ni)
            acc[mi][ni] = (f32x4){0.f, 0.f, 0.f, 0.f};

    int srow = wv * 16 + (lane >> 2);
    int scol = (lane & 3) * 8;
    const __hip_bfloat16* pa0 = A + (size_t)(bm + srow) * K + scol;
    const __hip_bfloat16* pa1 = A + (size_t)(bm + 64 + srow) * K + scol;
    const __hip_bfloat16* pb0 = Bw + (size_t)(bn + srow) * K + scol;
    const __hip_bfloat16* pb1 = Bw + (size_t)(bn + 64 + srow) * K + scol;
    char* At_b = (char*)&At[0][0] + wv * 1024;
    char* Bt_b = (char*)&Bt[0][0] + wv * 1024;

    for (int k0 = 0; k0 < K; k0 += 32) {
        gload_lds16(pa0 + k0, At_b);
        gload_lds16(pa1 + k0, At_b + 4096);
        gload_lds16(pb0 + k0, Bt_b);
        gload_lds16(pb1 + k0, Bt_b + 4096);
        __syncthreads();

        bf8_t af[4], bfr[4];
        #pragma unroll
        for (int mi = 0; mi < 4; ++mi)
            af[mi] = *(const bf8_t*)((const char*)&At[0][0] +
                     (wr * 64 + mi * 16 + (lane & 15)) * 64 + (lane >> 4) * 16);
        #pragma unroll
        for (int ni = 0; ni < 4; ++ni)
            bfr[ni] = *(const bf8_t*)((const char*)&Bt[0][0] +
                     (wc * 64 + ni * 16 + (lane & 15)) * 64 + (lane >> 4) * 16);
        #pragma unroll
        for (int mi = 0; mi < 4; ++mi)
            #pragma unroll
            for (int ni = 0; ni < 4; ++ni)
                acc[mi][ni] = __builtin_amdgcn_mfma_f32_16x16x32_bf16(
                    af[mi], bfr[ni], acc[mi][ni], 0, 0, 0);
        __syncthreads();
    }

    if (z == 0) {
        #pragma unroll
        for (int mi = 0; mi < 4; ++mi) {
            int r0 = bm + wr * 64 + mi * 16 + (lane >> 4) * 4;
            #pragma unroll
            for (int ni = 0; ni < 4; ++ni) {
                int c0 = bn + wc * 64 + ni * 16 + (lane & 15);
                if (c0 < 288) {
                    #pragma unroll
                    for (int j = 0; j < 4; ++j) {
                        float v = acc[mi][ni][j];
                        if (c0 < 64) v = tanhf(v);
                        else if (c0 >= 160) v = sigf(v);
                        H[(size_t)(r0 + j) * 288 + c0] = __float2bfloat16(v);
                    }
                }
            }
        }
    } else {
        #pragma unroll
        for (int mi = 0; mi < 4; ++mi) {
            int r0 = bm + wr * 64 + mi * 16 + (lane >> 4) * 4;
            #pragma unroll
            for (int ni = 0; ni < 4; ++ni) {
                int c0 = bn + wc * 64 + ni * 16 + (lane & 15);
                #pragma unroll
                for (int j = 0; j < 4; ++j)
                    Cout[(size_t)(r0 + j) * Cdim + c0] = acc[mi][ni][j];
            }
        }
    }
}

// ---------------------------------------------------------------------------
// gemm_o64: output projection with 128x64 tiles -> grid (16,16) = 256
// blocks = full chip. 4 waves 2x2; wave does 64x32 via acc[4][2].
// ---------------------------------------------------------------------------
__global__ __launch_bounds__(256) void gemm_o64(
    const __hip_bfloat16* __restrict__ A, const __hip_bfloat16* __restrict__ Bw,
    float* __restrict__ Cout)
{
    const int K = Cdim, N = Cdim;
    __shared__ unsigned short At[128][32];
    __shared__ unsigned short Bt[64][32];
    int tid = threadIdx.x;
    int lane = tid & 63, wv = tid >> 6;
    int bm = blockIdx.y * 128, bn = blockIdx.x * 64;
    int wr = wv >> 1, wc = wv & 1;

    f32x4 acc[4][2];
    #pragma unroll
    for (int mi = 0; mi < 4; ++mi)
        #pragma unroll
        for (int ni = 0; ni < 2; ++ni)
            acc[mi][ni] = (f32x4){0.f, 0.f, 0.f, 0.f};

    int srow = wv * 16 + (lane >> 2);   // 0..63
    int scol = (lane & 3) * 8;
    const __hip_bfloat16* pa0 = A + (size_t)(bm + srow) * K + scol;
    const __hip_bfloat16* pa1 = A + (size_t)(bm + 64 + srow) * K + scol;
    const __hip_bfloat16* pb0 = Bw + (size_t)(bn + srow) * K + scol;
    char* At_b = (char*)&At[0][0] + wv * 1024;
    char* Bt_b = (char*)&Bt[0][0] + wv * 1024;

    for (int k0 = 0; k0 < K; k0 += 32) {
        gload_lds16(pa0 + k0, At_b);
        gload_lds16(pa1 + k0, At_b + 4096);
        gload_lds16(pb0 + k0, Bt_b);
        __syncthreads();

        bf8_t af[4], bfr[2];
        #pragma unroll
        for (int mi = 0; mi < 4; ++mi)
            af[mi] = *(const bf8_t*)((const char*)&At[0][0] +
                     (wr * 64 + mi * 16 + (lane & 15)) * 64 + (lane >> 4) * 16);
        #pragma unroll
        for (int ni = 0; ni < 2; ++ni)
            bfr[ni] = *(const bf8_t*)((const char*)&Bt[0][0] +
                     (wc * 32 + ni * 16 + (lane & 15)) * 64 + (lane >> 4) * 16);
        #pragma unroll
        for (int mi = 0; mi < 4; ++mi)
            #pragma unroll
            for (int ni = 0; ni < 2; ++ni)
                acc[mi][ni] = __builtin_amdgcn_mfma_f32_16x16x32_bf16(
                    af[mi], bfr[ni], acc[mi][ni], 0, 0, 0);
        __syncthreads();
    }

    #pragma unroll
    for (int mi = 0; mi < 4; ++mi) {
        int r0 = bm + wr * 64 + mi * 16 + (lane >> 4) * 4;
        #pragma unroll
        for (int ni = 0; ni < 2; ++ni) {
            int c0 = bn + wc * 32 + ni * 16 + (lane & 15);
            #pragma unroll
            for (int j = 0; j < 4; ++j)
                Cout[(size_t)(r0 + j) * N + c0] = acc[mi][ni][j];
        }
    }
}

// ---------------------------------------------------------------------------
// gemm_lr2: per-path z-grid GEMM with TRUE K (R19: was K=288 block-diag
// with 75% zero flops). z=path, K=D in {64,64,32,128}; A = hcat column
// slice (lda 288); W compact [1024][D]. Epilogue bias+act+demux per path.
// grid (8,16,4).
// ---------------------------------------------------------------------------
__global__ __launch_bounds__(256) void gemm_lr2(
    const __hip_bfloat16* __restrict__ H, const __hip_bfloat16* __restrict__ Wl2,
    const float* __restrict__ w0, const float* __restrict__ a0,
    const float* __restrict__ v0,
    float* __restrict__ decay, __hip_bfloat16* __restrict__ at16,
    float* __restrict__ vt, __hip_bfloat16* __restrict__ gt16)
{
    __shared__ unsigned short At[128][32];
    __shared__ unsigned short Bt[128][32];
    int z = blockIdx.z;
    int D, aoff; size_t woff;
    if (z == 0)      { D = 64;  aoff = 0;   woff = 0; }
    else if (z == 1) { D = 64;  aoff = 64;  woff = 65536; }
    else if (z == 2) { D = 32;  aoff = 128; woff = 131072; }
    else             { D = 128; aoff = 160; woff = 163840; }
    const __hip_bfloat16* W = Wl2 + woff;
    int tid = threadIdx.x;
    int lane = tid & 63, wv = tid >> 6;
    int bm = blockIdx.y * 128, bn = blockIdx.x * 128;
    int wr = wv >> 1, wc = wv & 1;

    f32x4 acc[4][4];
    #pragma unroll
    for (int mi = 0; mi < 4; ++mi)
        #pragma unroll
        for (int ni = 0; ni < 4; ++ni)
            acc[mi][ni] = (f32x4){0.f, 0.f, 0.f, 0.f};

    int srow = wv * 16 + (lane >> 2);
    int scol = (lane & 3) * 8;
    const __hip_bfloat16* pa0 = H + (size_t)(bm + srow) * 288 + aoff + scol;
    const __hip_bfloat16* pa1 = H + (size_t)(bm + 64 + srow) * 288 + aoff + scol;
    const __hip_bfloat16* pb0 = W + (size_t)(bn + srow) * D + scol;
    const __hip_bfloat16* pb1 = W + (size_t)(bn + 64 + srow) * D + scol;
    char* At_b = (char*)&At[0][0] + wv * 1024;
    char* Bt_b = (char*)&Bt[0][0] + wv * 1024;

    for (int k0 = 0; k0 < D; k0 += 32) {
        if (k0 + scol < D) {
            gload_lds16(pa0 + k0, At_b);
            gload_lds16(pa1 + k0, At_b + 4096);
            gload_lds16(pb0 + k0, Bt_b);
            gload_lds16(pb1 + k0, Bt_b + 4096);
        }
        __syncthreads();

        bf8_t af[4], bfr[4];
        #pragma unroll
        for (int mi = 0; mi < 4; ++mi)
            af[mi] = *(const bf8_t*)((const char*)&At[0][0] +
                     (wr * 64 + mi * 16 + (lane & 15)) * 64 + (lane >> 4) * 16);
        #pragma unroll
        for (int ni = 0; ni < 4; ++ni)
            bfr[ni] = *(const bf8_t*)((const char*)&Bt[0][0] +
                     (wc * 64 + ni * 16 + (lane & 15)) * 64 + (lane >> 4) * 16);
        #pragma unroll
        for (int mi = 0; mi < 4; ++mi)
            #pragma unroll
            for (int ni = 0; ni < 4; ++ni)
                acc[mi][ni] = __builtin_amdgcn_mfma_f32_16x16x32_bf16(
                    af[mi], bfr[ni], acc[mi][ni], 0, 0, 0);
        __syncthreads();
    }

    #pragma unroll
    for (int mi = 0; mi < 4; ++mi) {
        int r0 = bm + wr * 64 + mi * 16 + (lane >> 4) * 4;
        #pragma unroll
        for (int ni = 0; ni < 4; ++ni) {
            int nl = bn + wc * 64 + ni * 16 + (lane & 15);
            #pragma unroll
            for (int j = 0; j < 4; ++j) {
                float v = acc[mi][ni][j];
                size_t oi = (size_t)(r0 + j) * Cdim + nl;
                if (z == 0)      decay[oi] = sigf(v + w0[nl]) * 0.60653065971263342f;
                else if (z == 1) at16[oi] = __float2bfloat16(sigf(v + a0[nl]));
                else if (z == 2) vt[oi] = sigf(v + v0[nl]);
                else             gt16[oi] = __float2bfloat16(v);
            }
        }
    }
}

// ---------------------------------------------------------------------------
// E1: kk-normalize -> aarr=-kkn, barr=kkn*at; ut. (v_first copy in prep)
// ---------------------------------------------------------------------------
__global__ __launch_bounds__(256) void e1_kernel(
    const float* __restrict__ kt, const __hip_bfloat16* __restrict__ at16,
    const float* __restrict__ rt, const float* __restrict__ vraw,
    const float* __restrict__ vt, const float* __restrict__ vfirst,
    const float* __restrict__ k_k, const float* __restrict__ k_a,
    const float* __restrict__ r_k,
    float* __restrict__ aarr, float* __restrict__ barr,
    float* __restrict__ ut)
{
    int gid = blockIdx.x * 4 + (threadIdx.x >> 6);
    int lane = threadIdx.x & 63;
    int h = gid % Hdim;
    size_t idx = (size_t)gid * 64 + lane;
    int c = h * 64 + lane;
    float ktv = kt[idx];
    float atv = __bfloat162float(at16[idx]);
    float kk = ktv * k_k[c];
    float ss = wsum64(kk * kk);
    float norm = sqrtf(ss);
    float kkn = kk / fmaxf(norm, 1e-12f);
    aarr[idx] = -kkn;
    barr[idx] = kkn * atv;
    float kmix = ktv * (1.f + (atv - 1.f) * k_a[c]);
    float rv = rt[idx];
    float dot = wsum64(rv * kmix * r_k[c]);
    float vm = vraw[idx];
    float vf = vfirst[idx];
    vm = vm + (vf - vm) * vt[idx];
    ut[idx] = dot * vm;
}

// ---------------------------------------------------------------------------
// WKV scan v10 (EXACT R16 version — known-good, FROZEN): 16-way XCD-local
// split, all-DPP reduce, 4-deep asm pipeline, store-aware counted waits.
// ---------------------------------------------------------------------------
struct Ops { f4 a, d, k, b, r; float vi; };

static __device__ __forceinline__ void load_set(
    Ops& s, const float* pa, const float* pd, const float* pk,
    const float* pb, const float* pr, const float* pv)
{
    asm volatile(
        "global_load_dwordx4 %0, %6, off\n\t"
        "global_load_dword   %5, %11, off\n\t"
        "global_load_dwordx4 %1, %7, off\n\t"
        "global_load_dwordx4 %2, %8, off\n\t"
        "global_load_dwordx4 %3, %9, off\n\t"
        "global_load_dwordx4 %4, %10, off"
        : "=&v"(s.a), "=&v"(s.d), "=&v"(s.k), "=&v"(s.b), "=&v"(s.r), "=&v"(s.vi)
        : "v"(pa), "v"(pd), "v"(pk), "v"(pb), "v"(pr), "v"(pv));
}

static __device__ __forceinline__ void wkv_wait18() {
    asm volatile("s_waitcnt vmcnt(18)" ::: "memory");
    __builtin_amdgcn_sched_barrier(0);
}
static __device__ __forceinline__ void wkv_wait19() {
    asm volatile("s_waitcnt vmcnt(19)" ::: "memory");
    __builtin_amdgcn_sched_barrier(0);
}
static __device__ __forceinline__ void wkv_wait20() {
    asm volatile("s_waitcnt vmcnt(20)" ::: "memory");
    __builtin_amdgcn_sched_barrier(0);
}
static __device__ __forceinline__ void wkv_wait21() {
    asm volatile("s_waitcnt vmcnt(21)" ::: "memory");
    __builtin_amdgcn_sched_barrier(0);
}

static __device__ __forceinline__ void wkv_compute(
    float S[4], const Ops& o, float* po, int q)
{
    float s0 = S[0] * o.a.x, s1 = S[1] * o.a.y;
    float s2 = S[2] * o.a.z, s3 = S[3] * o.a.w;
    float sp = red16_dpp((s0 + s1) + (s2 + s3));

    S[0] = fmaf(S[0], o.d.x, fmaf(sp, o.b.x, o.vi * o.k.x));
    S[1] = fmaf(S[1], o.d.y, fmaf(sp, o.b.y, o.vi * o.k.y));
    S[2] = fmaf(S[2], o.d.z, fmaf(sp, o.b.z, o.vi * o.k.z));
    S[3] = fmaf(S[3], o.d.w, fmaf(sp, o.b.w, o.vi * o.k.w));

    float o0 = S[0] * o.r.x, o1 = S[1] * o.r.y;
    float o2 = S[2] * o.r.z, o3 = S[3] * o.r.w;
    float op = red16_dpp((o0 + o1) + (o2 + o3));
    if (q == 0) *po = op;
}

__global__ __launch_bounds__(64, 1) void wkv_kernel(
    const float* __restrict__ rt, const float* __restrict__ decay,
    const float* __restrict__ kt, const float* __restrict__ vt,
    const float* __restrict__ aarr, const float* __restrict__ barr,
    float* __restrict__ wkvt)
{
    int tid = threadIdx.x;
    int blk = blockIdx.x;              // 512 blocks: chunk*32 + bh (XCD-local)
    int chunk = blk >> 5, bh = blk & 31;
    int b = bh >> 4, h = bh & 15;
    int i = chunk * 4 + (tid >> 4);    // state row owned by this 16-lane group
    int q = tid & 15;                  // column-slice owner (4 cols)
    int jb = q * 4;
    size_t base = ((size_t)b * Tdim) * Cdim + (size_t)h * Ndim;
    const float* pa = aarr + base + jb;
    const float* pd = decay + base + jb;
    const float* pk = kt + base + jb;
    const float* pb = barr + base + jb;
    const float* pr = rt + base + jb;
    const float* pv = vt + base + i;
    float* po = wkvt + base + i;

    float S[4];
    #pragma unroll
    for (int j = 0; j < 4; ++j) S[j] = 0.f;

    Ops A, B, C, D;
    load_set(A, pa, pd, pk, pb, pr, pv);
    {
        size_t o1 = (size_t)1 * Cdim, o2 = (size_t)2 * Cdim, o3 = (size_t)3 * Cdim;
        load_set(B, pa + o1, pd + o1, pk + o1, pb + o1, pr + o1, pv + o1);
        load_set(C, pa + o2, pd + o2, pk + o2, pb + o2, pr + o2, pv + o2);
        load_set(D, pa + o3, pd + o3, pk + o3, pb + o3, pr + o3, pv + o3);
    }

    // peeled first macro-iter: no stores in queue yet -> exact waits 18..21
    {
        wkv_wait18();
        wkv_compute(S, A, po, q);
        size_t o4 = (size_t)4 * Cdim;
        load_set(A, pa + o4, pd + o4, pk + o4, pb + o4, pr + o4, pv + o4);

        wkv_wait19();
        wkv_compute(S, B, po + (size_t)1 * Cdim, q);
        size_t o5 = (size_t)5 * Cdim;
        load_set(B, pa + o5, pd + o5, pk + o5, pb + o5, pr + o5, pv + o5);

        wkv_wait20();
        wkv_compute(S, C, po + (size_t)2 * Cdim, q);
        size_t o6 = (size_t)6 * Cdim;
        load_set(C, pa + o6, pd + o6, pk + o6, pb + o6, pr + o6, pv + o6);

        wkv_wait21();
        wkv_compute(S, D, po + (size_t)3 * Cdim, q);
        size_t o7 = (size_t)7 * Cdim;
        load_set(D, pa + o7, pd + o7, pk + o7, pb + o7, pr + o7, pv + o7);
    }

    for (int t = 4; t < Tdim; t += 4) {
        wkv_wait21();
        wkv_compute(S, A, po + (size_t)t * Cdim, q);
        size_t o4 = (size_t)((t + 4 < Tdim) ? t + 4 : Tdim - 1) * Cdim;
        load_set(A, pa + o4, pd + o4, pk + o4, pb + o4, pr + o4, pv + o4);

        wkv_wait21();
        wkv_compute(S, B, po + (size_t)(t + 1) * Cdim, q);
        size_t o5 = (size_t)((t + 5 < Tdim) ? t + 5 : Tdim - 1) * Cdim;
        load_set(B, pa + o5, pd + o5, pk + o5, pb + o5, pr + o5, pv + o5);

        wkv_wait21();
        wkv_compute(S, C, po + (size_t)(t + 2) * Cdim, q);
        size_t o6 = (size_t)((t + 6 < Tdim) ? t + 6 : Tdim - 1) * Cdim;
        load_set(C, pa + o6, pd + o6, pk + o6, pb + o6, pr + o6, pv + o6);

        wkv_wait21();
        wkv_compute(S, D, po + (size_t)(t + 3) * Cdim, q);
        size_t o7 = (size_t)((t + 7 < Tdim) ? t + 7 : Tdim - 1) * Cdim;
        load_set(D, pa + o7, pd + o7, pk + o7, pb + o7, pr + o7, pv + o7);
    }
}

// ---------------------------------------------------------------------------
// E2: pt = GroupNorm(rt*wkvt)*ln_g + ln_b + ut; g16 = bf16(gt*pt)
// ---------------------------------------------------------------------------
__global__ __launch_bounds__(256) void e2_kernel(
    const float* __restrict__ rt, const float* __restrict__ wkvt,
    const float* __restrict__ ut, const __hip_bfloat16* __restrict__ gt16,
    const float* __restrict__ ln_g, const float* __restrict__ ln_b,
    __hip_bfloat16* __restrict__ g16)
{
    int gid = blockIdx.x * 4 + (threadIdx.x >> 6);
    int lane = threadIdx.x & 63;
    int h = gid % Hdim;
    size_t idx = (size_t)gid * 64 + lane;
    int c = h * 64 + lane;
    float x = rt[idx] * wkvt[idx];
    float mu = wsum64(x) * (1.f / 64.f);
    float d = x - mu;
    float var = wsum64(d * d) * (1.f / 64.f);
    float xn = d / sqrtf(var + EPS_GN);
    float pt = xn * ln_g[c] + ln_b[c] + ut[idx];
    float res = __bfloat162float(gt16[idx]) * pt;
    g16[idx] = __float2bfloat16(res);
}

// ---------------------------------------------------------------------------
extern "C" void kernel_launch(void* const* d_in, const int* in_sizes, int n_in,
                              void* d_out, int out_size, void* d_ws, size_t ws_size,
                              hipStream_t stream)
{
    (void)in_sizes; (void)n_in; (void)out_size; (void)ws_size;
    const float* xt      = (const float*)d_in[0];
    const float* v_first = (const float*)d_in[1];
    const float* tmix_r  = (const float*)d_in[2];
    const float* tmix_w  = (const float*)d_in[3];
    const float* tmix_k  = (const float*)d_in[4];
    const float* tmix_v  = (const float*)d_in[5];
    const float* tmix_a  = (const float*)d_in[6];
    const float* tmix_g  = (const float*)d_in[7];
    const float* w1 = (const float*)d_in[8];
    const float* w2 = (const float*)d_in[9];
    const float* w0 = (const float*)d_in[10];
    const float* a1 = (const float*)d_in[11];
    const float* a2 = (const float*)d_in[12];
    const float* a0 = (const float*)d_in[13];
    const float* v1 = (const float*)d_in[14];
    const float* v2 = (const float*)d_in[15];
    const float* v0 = (const float*)d_in[16];
    const float* g1 = (const float*)d_in[17];
    const float* g2 = (const float*)d_in[18];
    const float* k_k = (const float*)d_in[19];
    const float* k_a = (const float*)d_in[20];
    const float* r_k = (const float*)d_in[21];
    const float* W_r = (const float*)d_in[22];
    const float* W_k = (const float*)d_in[23];
    const float* W_v = (const float*)d_in[24];
    const float* W_o = (const float*)d_in[25];
    const float* ln_g = (const float*)d_in[26];
    const float* ln_b = (const float*)d_in[27];

    float* out = (float*)d_out;
    const size_t BTC = (size_t)Bdim * Tdim * Cdim;   // 2,097,152
    const int M = Bdim * Tdim;                        // 2048

    float* ws = (float*)d_ws;
    float* rt    = ws + 0 * BTC;
    float* kt    = ws + 1 * BTC;
    float* vraw  = ws + 2 * BTC;
    float* vt    = ws + 3 * BTC;
    float* decay = ws + 4 * BTC;
    float* aarr  = ws + 5 * BTC;
    float* barr  = ws + 6 * BTC;
    float* ut    = ws + 7 * BTC;
    float* wkv   = ws + 8 * BTC;
    __hip_bfloat16* bfa = (__hip_bfloat16*)(ws + 9 * BTC);
    __hip_bfloat16* at16 = bfa + 0 * BTC;
    __hip_bfloat16* gt16 = bfa + 1 * BTC;
    __hip_bfloat16* xr16 = bfa + 2 * BTC;
    __hip_bfloat16* xk16 = bfa + 3 * BTC;
    __hip_bfloat16* xv16 = bfa + 4 * BTC;   // reused as g16 after gemm
    __hip_bfloat16* Wb   = bfa + 5 * BTC;   // 4*CCdim = 2*BTC bf16
    // Aliased scratch (dead before their slots' writers run):
    __hip_bfloat16* Aall = (__hip_bfloat16*)decay;           // 8MB (decay written later by gemm_lr2)
    __hip_bfloat16* Wlr1 = (__hip_bfloat16*)aarr;            // (aarr written later by e1)
    __hip_bfloat16* Wl2  = Wlr1 + (size_t)384 * 2048;        // compact per-path, 294912 bf16
    __hip_bfloat16* hcat = Wl2 + (size_t)1024 * 288;
    __hip_bfloat16* g16 = xv16;

    // prep: weights + activation lerps + Aall + v_first copy, one dispatch
    prep_fused<<<8576, 256, 0, stream>>>(
        W_r, W_k, W_v, W_o, w1, a1, v1, g1, w2, a2, v2, g2,
        tmix_w, tmix_a, tmix_v, tmix_g, xt, tmix_r, tmix_k, v_first,
        Wb, Wlr1, Wl2, xr16, xk16, xv16, Aall, out + BTC);

    // fused GEMM: z=0 lr1 (K=2048, long blocks first) + z=1..3 projections
    dim3 ggf(Cdim / 128, M / 128, 4);   // (8,16,4)
    gemm_fused<<<ggf, 256, 0, stream>>>(xr16, xk16, xv16, Aall, Wb, Wlr1,
                                        rt, kt, vraw, hcat);

    // lr2 expansion: per-path true-K GEMM (z-grid)
    gemm_lr2<<<dim3(8, 16, 4), 256, 0, stream>>>(hcat, Wl2, w0, a0, v0,
                                                 decay, at16, vt, gt16);

    // E1
    e1_kernel<<<(Bdim * Tdim * Hdim) / 4, 256, 0, stream>>>(
        kt, at16, rt, vraw, vt, v_first, k_k, k_a, r_k,
        aarr, barr, ut);

    // WKV scan (R16 known-good version, frozen)
    wkv_kernel<<<512, 64, 0, stream>>>(rt, decay, kt, vt, aarr, barr, wkv);

    // E2 (writes bf16 gated output)
    e2_kernel<<<(Bdim * Tdim * Hdim) / 4, 256, 0, stream>>>(
        rt, wkv, ut, gt16, ln_g, ln_b, g16);

    // output projection (full-chip 128x64 tiles)
    gemm_o64<<<dim3(Cdim / 64, M / 128), 256, 0, stream>>>(
        g16, Wb + 3 * (size_t)CCdim, out);
}